// Round 1
// baseline (1733.810 us; speedup 1.0000x reference)
//
#include <hip/hip_runtime.h>

#define KD 1024   // D
#define KI 2048   // I
#define KB 2      // B
#define KS 1024   // S
#define KC 64     // C (chunk len)
#define KN 16     // N chunks
#define KEPS 1e-6f

__device__ __forceinline__ float sigf(float x){ return 1.0f/(1.0f+__expf(-x)); }
__device__ __forceinline__ float siluf(float x){ return x*sigf(x); }
__device__ __forceinline__ float dsiluf(float x){ float s=sigf(x); return s*(1.0f+x*(1.0f-s)); }

// ---------------- gates: alpha/theta/eta per chunk ----------------
__global__ __launch_bounds__(256) void gates_kernel(
    const float* __restrict__ x, const float* __restrict__ aw,
    const float* __restrict__ tw, const float* __restrict__ ew,
    float* __restrict__ alpha, float* __restrict__ theta, float* __restrict__ eta)
{
  const int bn = blockIdx.x;  // 0..31
  const float4* xc = (const float4*)(x + (size_t)bn * (KC*KD));
  const float4* a4 = (const float4*)aw;
  const float4* t4 = (const float4*)tw;
  const float4* e4 = (const float4*)ew;
  float da=0.f, dt=0.f, de=0.f;
  for (int i = threadIdx.x; i < (KC*KD)/4; i += 256) {
    float4 xv = xc[i], av = a4[i], tv = t4[i], ev = e4[i];
    da += xv.x*av.x + xv.y*av.y + xv.z*av.z + xv.w*av.w;
    dt += xv.x*tv.x + xv.y*tv.y + xv.z*tv.z + xv.w*tv.w;
    de += xv.x*ev.x + xv.y*ev.y + xv.z*ev.z + xv.w*ev.w;
  }
  __shared__ float sA[256], sT[256], sE[256];
  sA[threadIdx.x]=da; sT[threadIdx.x]=dt; sE[threadIdx.x]=de;
  __syncthreads();
  for (int s=128;s>0;s>>=1){
    if ((int)threadIdx.x < s){
      sA[threadIdx.x]+=sA[threadIdx.x+s];
      sT[threadIdx.x]+=sT[threadIdx.x+s];
      sE[threadIdx.x]+=sE[threadIdx.x+s];
    }
    __syncthreads();
  }
  if (threadIdx.x==0){
    alpha[bn] = sigf(sA[0]);
    theta[bn] = sigf(sT[0]) * 0.01f;
    eta[bn]   = sigf(sE[0]);
  }
}

// ---------------- scan coefficients (closed form of the two assoc scans) ----
// S_t = eta_t*S_{t-1} - g_t (S_{-1}=0);  M_t = (1-alpha_t)*M_{t-1} + S_t (M_{-1}=w)
// ns = sum_j cs[j]*g_j with cs[j] = -prod_{l>j} eta_l
// nw = Pw*w + sum_j cm[j]*g_j with cm[j] = -sum_{t>=j} A(t)*E(j,t),
//   A(t)=prod_{l>t}(1-alpha_l), E(j,t)=prod_{l=j+1..t} eta_l, Pw=prod(1-alpha)
__global__ void scan_coef_kernel(const float* __restrict__ alpha, const float* __restrict__ eta,
                                 float* __restrict__ cm, float* __restrict__ cs, float* __restrict__ Pw)
{
  const int b = threadIdx.x;
  if (b >= KB) return;
  float al[KN], et[KN];
  for (int n=0;n<KN;n++){ al[n]=alpha[b*KN+n]; et[n]=eta[b*KN+n]; }
  float prodE = 1.f;
  for (int j=KN-1;j>=0;j--){ cs[b*KN+j] = -prodE; prodE *= et[j]; }
  float A[KN]; A[KN-1]=1.f;
  for (int t=KN-2;t>=0;t--) A[t] = A[t+1]*(1.f-al[t+1]);
  for (int j=0;j<KN;j++){
    float inner=0.f, E=1.f;
    for (int t=j;t<KN;t++){ inner += A[t]*E; if (t+1<KN) E *= et[t+1]; }
    cm[b*KN+j] = -inner;
  }
  float pw=1.f;
  for (int n=0;n<KN;n++) pw *= (1.f-al[n]);
  Pw[b]=pw;
}

// ---------------- generic fp32 tiled GEMM: C[M,Nn] = A[M,K] * op(B) -------
// TRANSB=1: B is [Nn,K] row-major (C = A*B^T).  TRANSB=0: B is [K,Nn].
// EPI: 0 none, 1 silu, 2 write pre-act to C2 + silu to C, 3 multiply by dsilu(Aux)
// bstride: per-batch weight stride (elements); batch = m0/1024 (S rows/batch)
template<int TRANSB, int EPI>
__global__ __launch_bounds__(256) void gemm_kernel(
    const float* __restrict__ A, const float* __restrict__ Bm,
    float* __restrict__ C, float* __restrict__ C2, const float* __restrict__ Aux,
    int Nn, int K, long bstride)
{
  const int n0 = blockIdx.x * 64;
  const int m0 = blockIdx.y * 64;
  const float* Bp = Bm + (size_t)(m0 >> 10) * (size_t)bstride;
  __shared__ float As[16][68];
  __shared__ float Bs[16][68];
  const int tid = threadIdx.x;
  const int tx = tid & 15, ty = tid >> 4;
  const int mload = tid >> 2, kq = (tid & 3) << 2;
  const int krow = tid >> 4, nq = (tid & 15) << 2;
  float acc[4][4] = {};
  for (int k0 = 0; k0 < K; k0 += 16) {
    float4 av = *(const float4*)(A + (size_t)(m0 + mload) * K + k0 + kq);
    As[kq+0][mload]=av.x; As[kq+1][mload]=av.y; As[kq+2][mload]=av.z; As[kq+3][mload]=av.w;
    if (TRANSB) {
      float4 bv = *(const float4*)(Bp + (size_t)(n0 + mload) * K + k0 + kq);
      Bs[kq+0][mload]=bv.x; Bs[kq+1][mload]=bv.y; Bs[kq+2][mload]=bv.z; Bs[kq+3][mload]=bv.w;
    } else {
      float4 bv = *(const float4*)(Bp + (size_t)(k0 + krow) * Nn + n0 + nq);
      Bs[krow][nq+0]=bv.x; Bs[krow][nq+1]=bv.y; Bs[krow][nq+2]=bv.z; Bs[krow][nq+3]=bv.w;
    }
    __syncthreads();
    #pragma unroll
    for (int kk = 0; kk < 16; ++kk) {
      float a0=As[kk][ty*4+0], a1=As[kk][ty*4+1], a2=As[kk][ty*4+2], a3=As[kk][ty*4+3];
      float b0=Bs[kk][tx*4+0], b1=Bs[kk][tx*4+1], b2=Bs[kk][tx*4+2], b3=Bs[kk][tx*4+3];
      acc[0][0]+=a0*b0; acc[0][1]+=a0*b1; acc[0][2]+=a0*b2; acc[0][3]+=a0*b3;
      acc[1][0]+=a1*b0; acc[1][1]+=a1*b1; acc[1][2]+=a1*b2; acc[1][3]+=a1*b3;
      acc[2][0]+=a2*b0; acc[2][1]+=a2*b1; acc[2][2]+=a2*b2; acc[2][3]+=a2*b3;
      acc[3][0]+=a3*b0; acc[3][1]+=a3*b1; acc[3][2]+=a3*b2; acc[3][3]+=a3*b3;
    }
    __syncthreads();
  }
  #pragma unroll
  for (int i=0;i<4;i++){
    #pragma unroll
    for (int j=0;j<4;j++){
      const int m = m0 + ty*4 + i, n = n0 + tx*4 + j;
      const size_t idx = (size_t)m * Nn + n;
      float v = acc[i][j];
      if (EPI==0) C[idx]=v;
      else if (EPI==1) C[idx]=siluf(v);
      else if (EPI==2){ C2[idx]=v; C[idx]=siluf(v); }
      else { C[idx]=v*dsiluf(Aux[idx]); }
    }
  }
}

// ---------------- row-wise RMSNorm in place (one wave per row) -------------
__global__ __launch_bounds__(256) void rms_rows_kernel(float* __restrict__ v, const float* __restrict__ w)
{
  const int row = blockIdx.x * 4 + (threadIdx.x >> 6);
  const int lane = threadIdx.x & 63;
  float* p = v + (size_t)row * KD;
  float vals[16]; float ss = 0.f;
  #pragma unroll
  for (int l=0;l<16;l++){ vals[l] = p[lane + (l<<6)]; ss += vals[l]*vals[l]; }
  #pragma unroll
  for (int o=32;o>0;o>>=1) ss += __shfl_xor(ss, o, 64);
  const float inv = rsqrtf(ss * (1.0f/KD) + KEPS);
  #pragma unroll
  for (int l=0;l<16;l++){ const int d = lane + (l<<6); p[d] = vals[l]*inv*w[d]; }
}

// ---------------- backward through rms+MSE: gy and gl per chunk ------------
__global__ __launch_bounds__(256) void rms_grad_kernel(
    const float* __restrict__ y, const float* __restrict__ kbuf, const float* __restrict__ vbuf,
    const float* __restrict__ lnw, const float* __restrict__ theta,
    float* __restrict__ gy, float* __restrict__ gl)
{
  const int bn = blockIdx.x;                    // chunk id b*KN+n
  const int wv = threadIdx.x >> 6, lane = threadIdx.x & 63;
  __shared__ float glacc[4][KD];
  float glp[16];
  #pragma unroll
  for (int l=0;l<16;l++) glp[l] = 0.f;
  const float th2 = theta[bn] * (2.0f / KD);
  for (int ci = 0; ci < 16; ++ci) {
    const int c = wv * 16 + ci;
    const size_t t = (size_t)bn * KC + c;
    const float* yr = y + t * KD;
    const float* kr = kbuf + t * KD;
    const float* vr = vbuf + t * KD;
    float yv[16]; float ss = 0.f;
    #pragma unroll
    for (int l=0;l<16;l++){ yv[l] = yr[lane + (l<<6)]; ss += yv[l]*yv[l]; }
    #pragma unroll
    for (int o2=32;o2>0;o2>>=1) ss += __shfl_xor(ss, o2, 64);
    const float inv = rsqrtf(ss * (1.0f/KD) + KEPS);
    float gzv[16]; float sdot = 0.f;
    #pragma unroll
    for (int l=0;l<16;l++){
      const int d = lane + (l<<6);
      const float lw = lnw[d];
      const float gz = th2 * (kr[d] + yv[l]*inv*lw - vr[d]);
      gzv[l] = gz;
      sdot += gz * lw * yv[l];
    }
    #pragma unroll
    for (int o2=32;o2>0;o2>>=1) sdot += __shfl_xor(sdot, o2, 64);
    const float c3 = inv*inv*inv * (1.0f/KD) * sdot;
    float* gyr = gy + t * KD;
    #pragma unroll
    for (int l=0;l<16;l++){
      const int d = lane + (l<<6);
      gyr[d] = inv * lnw[d] * gzv[l] - c3 * yv[l];
      glp[l] += gzv[l] * yv[l] * inv;
    }
  }
  #pragma unroll
  for (int l=0;l<16;l++) glacc[wv][lane + (l<<6)] = glp[l];
  __syncthreads();
  if (wv == 0) {
    #pragma unroll
    for (int l=0;l<16;l++){
      const int d = lane + (l<<6);
      gl[(size_t)bn * KD + d] = glacc[0][d]+glacc[1][d]+glacc[2][d]+glacc[3][d];
    }
  }
}

// ---------------- scan-weighted gradient accumulation ----------------------
// out[r,c] over b: P_n = A_n^T * B_n (K=64); outM = Pw*Winit + sum cm_n P_n; outS = sum cs_n P_n
__global__ __launch_bounds__(256) void wacc_kernel(
    const float* __restrict__ Amat, const float* __restrict__ Bmat,
    const float* __restrict__ Winit,
    const float* __restrict__ cm, const float* __restrict__ cs, const float* __restrict__ Pw,
    float* __restrict__ outM, float* __restrict__ outS,
    int R, int Ccols, int lda, int ldb)
{
  const int b = blockIdx.z;
  const int c0 = blockIdx.x * 64;
  const int r0 = blockIdx.y * 64;
  __shared__ float As[64][65];
  __shared__ float Bs[64][65];
  const int tid = threadIdx.x;
  const int tx = tid & 15, ty = tid >> 4;
  const int col = tid & 63, cr0 = tid >> 6;
  float accm[4][4] = {}, accs[4][4] = {};
  for (int n = 0; n < KN; ++n) {
    const float* Ab = Amat + (size_t)((b*KN + n) * KC) * lda;
    const float* Bb = Bmat + (size_t)((b*KN + n) * KC) * ldb;
    #pragma unroll
    for (int l = 0; l < 16; ++l) {
      const int c = cr0 + (l << 2);
      As[c][col] = Ab[(size_t)c * lda + r0 + col];
      Bs[c][col] = Bb[(size_t)c * ldb + c0 + col];
    }
    __syncthreads();
    float p[4][4] = {};
    for (int c = 0; c < KC; ++c) {
      float av[4], bv[4];
      #pragma unroll
      for (int i=0;i<4;i++) av[i] = As[c][ty*4+i];
      #pragma unroll
      for (int j=0;j<4;j++) bv[j] = Bs[c][tx*4+j];
      #pragma unroll
      for (int i=0;i<4;i++)
        #pragma unroll
        for (int j=0;j<4;j++) p[i][j] += av[i]*bv[j];
    }
    const float wm = cm[b*KN+n], wsc = cs[b*KN+n];
    #pragma unroll
    for (int i=0;i<4;i++)
      #pragma unroll
      for (int j=0;j<4;j++){ accm[i][j] += wm*p[i][j]; accs[i][j] += wsc*p[i][j]; }
    __syncthreads();
  }
  const float pw = Pw[b];
  #pragma unroll
  for (int i=0;i<4;i++){
    #pragma unroll
    for (int j=0;j<4;j++){
      const int r = r0 + ty*4+i, c = c0 + tx*4+j;
      const size_t w_idx = (size_t)r * Ccols + c;
      const size_t o_idx = ((size_t)b * R + r) * Ccols + c;
      outM[o_idx] = pw * Winit[w_idx] + accm[i][j];
      outS[o_idx] = accs[i][j];
    }
  }
}

// ---------------- nln / nsl from gl chunks ---------------------------------
__global__ void glcomb_kernel(const float* __restrict__ gl, const float* __restrict__ lnw,
                              const float* __restrict__ cm, const float* __restrict__ cs,
                              const float* __restrict__ Pw,
                              float* __restrict__ nln, float* __restrict__ nsl)
{
  const int idx = blockIdx.x*256 + threadIdx.x; // 0..KB*KD-1
  const int b = idx >> 10, d = idx & (KD-1);
  float am=0.f, as=0.f;
  for (int n=0;n<KN;n++){
    const float g = gl[(size_t)(b*KN+n)*KD + d];
    am += cm[b*KN+n]*g; as += cs[b*KN+n]*g;
  }
  nln[idx] = Pw[b]*lnw[d] + am;
  nsl[idx] = as;
}

// ---------------- final: out = q + rms(yq)*nln[b] --------------------------
__global__ __launch_bounds__(256) void final_out_kernel(
    const float* __restrict__ q, const float* __restrict__ yq, const float* __restrict__ nln,
    float* __restrict__ out)
{
  const int row = blockIdx.x * 4 + (threadIdx.x >> 6);
  const int lane = threadIdx.x & 63;
  const int b = row >> 10;
  const float* yr = yq + (size_t)row * KD;
  float yv[16]; float ss = 0.f;
  #pragma unroll
  for (int l=0;l<16;l++){ yv[l] = yr[lane + (l<<6)]; ss += yv[l]*yv[l]; }
  #pragma unroll
  for (int o=32;o>0;o>>=1) ss += __shfl_xor(ss, o, 64);
  const float inv = rsqrtf(ss * (1.0f/KD) + KEPS);
  #pragma unroll
  for (int l=0;l<16;l++){
    const int d = lane + (l<<6);
    out[(size_t)row*KD + d] = q[(size_t)row*KD + d] + yv[l]*inv*nln[b*KD + d];
  }
}

extern "C" void kernel_launch(void* const* d_in, const int* in_sizes, int n_in,
                              void* d_out, int out_size, void* d_ws, size_t ws_size,
                              hipStream_t stream)
{
  const float* x    = (const float*)d_in[0];
  const float* w1   = (const float*)d_in[1];
  const float* w2   = (const float*)d_in[2];
  const float* lnw  = (const float*)d_in[3];
  const float* wq   = (const float*)d_in[4];
  const float* wk   = (const float*)d_in[5];
  const float* wv   = (const float*)d_in[6];
  const float* qnw  = (const float*)d_in[7];
  const float* knw  = (const float*)d_in[8];
  const float* aw   = (const float*)d_in[9];
  const float* tw   = (const float*)d_in[10];
  const float* ew   = (const float*)d_in[11];

  float* out = (float*)d_out;
  float* nw1 = out + (size_t)KB*KS*KD;          // 2097152
  float* nw2 = nw1 + (size_t)KB*KI*KD;          // +4194304
  float* nln = nw2 + (size_t)KB*KD*KI;          // +4194304
  float* ns1 = nln + (size_t)KB*KD;             // +2048
  float* ns2 = ns1 + (size_t)KB*KI*KD;
  float* nsl = ns2 + (size_t)KB*KD*KI;

  float* ws = (float*)d_ws;
  size_t o = 0;
  float* kbuf = ws + o; o += (size_t)KB*KS*KD;
  float* vbuf = ws + o; o += (size_t)KB*KS*KD;
  float* qbuf = ws + o; o += (size_t)KB*KS*KD;
  float* abuf = ws + o; o += (size_t)KB*KS*KI;   // pre-act a; reused for hq
  float* hbuf = ws + o; o += (size_t)KB*KS*KI;
  float* ybuf = ws + o; o += (size_t)KB*KS*KD;   // y; reused for yq
  float* gybuf= ws + o; o += (size_t)KB*KS*KD;
  float* gabuf= ws + o; o += (size_t)KB*KS*KI;
  float* glbuf= ws + o; o += (size_t)KB*KN*KD;
  float* alpha= ws + o; o += 32;
  float* theta= ws + o; o += 32;
  float* eta  = ws + o; o += 32;
  float* csb  = ws + o; o += 32;
  float* cmb  = ws + o; o += 32;
  float* Pwb  = ws + o; o += 32;

  const int M = KB*KS;  // 2048 token rows
  dim3 blk(256);

  gates_kernel<<<KB*KN, blk, 0, stream>>>(x, aw, tw, ew, alpha, theta, eta);
  scan_coef_kernel<<<1, 64, 0, stream>>>(alpha, eta, cmb, csb, Pwb);

  // projections: k=silu(x wk^T), v=silu(x wv^T), q=silu(x wq^T)
  gemm_kernel<1,1><<<dim3(KD/64, M/64), blk, 0, stream>>>(x, wk, kbuf, nullptr, nullptr, KD, KD, 0);
  gemm_kernel<1,1><<<dim3(KD/64, M/64), blk, 0, stream>>>(x, wv, vbuf, nullptr, nullptr, KD, KD, 0);
  gemm_kernel<1,1><<<dim3(KD/64, M/64), blk, 0, stream>>>(x, wq, qbuf, nullptr, nullptr, KD, KD, 0);
  rms_rows_kernel<<<M/4, blk, 0, stream>>>(kbuf, knw);
  rms_rows_kernel<<<M/4, blk, 0, stream>>>(qbuf, qnw);

  // memory forward at initial weights: a = k w1^T (store), h = silu(a); y = h w2^T
  gemm_kernel<1,2><<<dim3(KI/64, M/64), blk, 0, stream>>>(kbuf, w1, hbuf, abuf, nullptr, KI, KD, 0);
  gemm_kernel<1,0><<<dim3(KD/64, M/64), blk, 0, stream>>>(hbuf, w2, ybuf, nullptr, nullptr, KD, KI, 0);

  // backward through rms+MSE
  rms_grad_kernel<<<KB*KN, blk, 0, stream>>>(ybuf, kbuf, vbuf, lnw, theta, gybuf, glbuf);
  // ga = (gy @ w2) * dsilu(a)   [NN GEMM]
  gemm_kernel<0,3><<<dim3(KI/64, M/64), blk, 0, stream>>>(gybuf, w2, gabuf, nullptr, abuf, KI, KD, 0);

  // scan-weighted gradient sums -> nw1/ns1 and nw2/ns2
  wacc_kernel<<<dim3(KD/64, KI/64, KB), blk, 0, stream>>>(gabuf, kbuf, w1, cmb, csb, Pwb,
                                                          nw1, ns1, KI, KD, KI, KD);
  wacc_kernel<<<dim3(KI/64, KD/64, KB), blk, 0, stream>>>(gybuf, hbuf, w2, cmb, csb, Pwb,
                                                          nw2, ns2, KD, KI, KD, KI);
  glcomb_kernel<<<(KB*KD)/256, blk, 0, stream>>>(glbuf, lnw, cmb, csb, Pwb, nln, nsl);

  // retrieval with updated per-batch weights: hq = silu(q nw1^T); yq = hq nw2^T
  gemm_kernel<1,1><<<dim3(KI/64, M/64), blk, 0, stream>>>(qbuf, nw1, abuf, nullptr, nullptr, KI, KD, (long)KI*KD);
  gemm_kernel<1,0><<<dim3(KD/64, M/64), blk, 0, stream>>>(abuf, nw2, ybuf, nullptr, nullptr, KD, KI, (long)KD*KI);
  final_out_kernel<<<M/4, blk, 0, stream>>>(qbuf, ybuf, nln, out);
}

// Round 2
// 580.399 us; speedup vs baseline: 2.9873x; 2.9873x over previous
//
#include <hip/hip_runtime.h>

#define KD 1024   // D
#define KI 2048   // I
#define KB 2      // B
#define KS 1024   // S
#define KC 64     // C (chunk len)
#define KN 16     // N chunks
#define KEPS 1e-6f

typedef __bf16 bf16x8 __attribute__((ext_vector_type(8)));
typedef float f32x4 __attribute__((ext_vector_type(4)));

__device__ __forceinline__ float sigf(float x){ return 1.0f/(1.0f+__expf(-x)); }
__device__ __forceinline__ float siluf(float x){ return x*sigf(x); }
__device__ __forceinline__ float dsiluf(float x){ float s=sigf(x); return s*(1.0f+x*(1.0f-s)); }

// ---------------- gates partial dots: 512 blocks, block-reduced ------------
__global__ __launch_bounds__(256) void gates_part_kernel(
    const float* __restrict__ x, const float* __restrict__ aw,
    const float* __restrict__ tw, const float* __restrict__ ew,
    float* __restrict__ part)   // part[g*512 + bn*16 + seg]
{
  const int seg = blockIdx.x, bn = blockIdx.y;
  const int base = seg*4096;
  float da=0.f, dt=0.f, de=0.f;
  #pragma unroll
  for (int i=0;i<4;i++){
    const int off = base + i*1024 + threadIdx.x*4;
    const float4 xv = *(const float4*)(x + (size_t)bn*65536 + off);
    const float4 av = *(const float4*)(aw + off);
    const float4 tv = *(const float4*)(tw + off);
    const float4 ev = *(const float4*)(ew + off);
    da += xv.x*av.x + xv.y*av.y + xv.z*av.z + xv.w*av.w;
    dt += xv.x*tv.x + xv.y*tv.y + xv.z*tv.z + xv.w*tv.w;
    de += xv.x*ev.x + xv.y*ev.y + xv.z*ev.z + xv.w*ev.w;
  }
  __shared__ float sA[256], sT[256], sE[256];
  sA[threadIdx.x]=da; sT[threadIdx.x]=dt; sE[threadIdx.x]=de;
  __syncthreads();
  for (int s=128;s>0;s>>=1){
    if ((int)threadIdx.x < s){
      sA[threadIdx.x]+=sA[threadIdx.x+s];
      sT[threadIdx.x]+=sT[threadIdx.x+s];
      sE[threadIdx.x]+=sE[threadIdx.x+s];
    }
    __syncthreads();
  }
  if (threadIdx.x==0){
    part[0*512 + bn*16 + seg] = sA[0];
    part[1*512 + bn*16 + seg] = sT[0];
    part[2*512 + bn*16 + seg] = sE[0];
  }
}

// ---------------- scan coefficients (closed form) --------------------------
__global__ void scan_coef_kernel(const float* __restrict__ part,
                                 float* __restrict__ cm, float* __restrict__ cs,
                                 float* __restrict__ Pw, float* __restrict__ theta)
{
  const int b = threadIdx.x;
  if (b >= KB) return;
  float al[KN], et[KN];
  for (int n=0;n<KN;n++){
    float sa=0.f, st=0.f, se=0.f;
    for (int s=0;s<16;s++){
      sa += part[0*512 + (b*KN+n)*16 + s];
      st += part[1*512 + (b*KN+n)*16 + s];
      se += part[2*512 + (b*KN+n)*16 + s];
    }
    al[n] = sigf(sa);
    theta[b*KN+n] = sigf(st)*0.01f;
    et[n] = sigf(se);
  }
  float prodE = 1.f;
  for (int j=KN-1;j>=0;j--){ cs[b*KN+j] = -prodE; prodE *= et[j]; }
  float A[KN]; A[KN-1]=1.f;
  for (int t=KN-2;t>=0;t--) A[t] = A[t+1]*(1.f-al[t+1]);
  for (int j=0;j<KN;j++){
    float inner=0.f, E=1.f;
    for (int t=j;t<KN;t++){ inner += A[t]*E; if (t+1<KN) E *= et[t+1]; }
    cm[b*KN+j] = -inner;
  }
  float pw=1.f;
  for (int n=0;n<KN;n++) pw *= (1.f-al[n]);
  Pw[b]=pw;
}

// ---------------- MFMA bf16 GEMM: C[M,N] = A[M,K] * B[N,K]^T ---------------
// fp32 sources, converted to bf16 at staging; fp32 accumulate.
// 128x128 tile, BK=64, 4 waves; LDS XOR-swizzle chunk^(row&7) -> 2-way reads.
// EPI: 0 none, 1 silu, 2 C2=preact + C=silu, 3 *= dsilu(Aux), 4 Pw[z]*Aux + acc
// b_bstride: B batch stride selected by m0>>10 (retrieval GEMMs)
// z_koff: per-z column offset into A and B rows (wacc GEMMs); out offset z*M*N
template<int EPI>
__global__ __launch_bounds__(256) void mfma_gemm(
    const float* __restrict__ A, const float* __restrict__ B,
    float* __restrict__ C, float* __restrict__ C2,
    const float* __restrict__ Aux, const float* __restrict__ Pw,
    int M, int Nn, int K, int lda, int ldb, long b_bstride, int z_koff)
{
  const int bz = blockIdx.z;
  const int n0 = blockIdx.x * 128;
  const int m0 = blockIdx.y * 128;
  const float* Ap = A + (size_t)z_koff * bz;
  const float* Bp = B + (size_t)z_koff * bz + (size_t)(m0 >> 10) * (size_t)b_bstride;
  __shared__ __bf16 As[128*64];
  __shared__ __bf16 Bs[128*64];
  const int tid = threadIdx.x;
  const int wv = tid >> 6, lane = tid & 63;
  const int wm = (wv >> 1) << 6, wn = (wv & 1) << 6;
  const int fr = lane & 15, fg = lane >> 4;
  const int sr = tid >> 3, sch = tid & 7;
  f32x4 acc[4][4] = {};
  for (int k0 = 0; k0 < K; k0 += 64) {
    #pragma unroll
    for (int i = 0; i < 4; ++i) {
      const int r = sr + i*32;
      const float* s = Ap + (size_t)(m0 + r) * lda + k0 + sch*8;
      const float4 f0 = *(const float4*)s;
      const float4 f1 = *(const float4*)(s+4);
      bf16x8 bv = { (__bf16)f0.x,(__bf16)f0.y,(__bf16)f0.z,(__bf16)f0.w,
                    (__bf16)f1.x,(__bf16)f1.y,(__bf16)f1.z,(__bf16)f1.w };
      *(bf16x8*)(As + r*64 + ((sch ^ (r & 7)) << 3)) = bv;
    }
    #pragma unroll
    for (int i = 0; i < 4; ++i) {
      const int r = sr + i*32;
      const float* s = Bp + (size_t)(n0 + r) * ldb + k0 + sch*8;
      const float4 f0 = *(const float4*)s;
      const float4 f1 = *(const float4*)(s+4);
      bf16x8 bv = { (__bf16)f0.x,(__bf16)f0.y,(__bf16)f0.z,(__bf16)f0.w,
                    (__bf16)f1.x,(__bf16)f1.y,(__bf16)f1.z,(__bf16)f1.w };
      *(bf16x8*)(Bs + r*64 + ((sch ^ (r & 7)) << 3)) = bv;
    }
    __syncthreads();
    #pragma unroll
    for (int ks = 0; ks < 2; ++ks) {
      bf16x8 af[4], bfr[4];
      #pragma unroll
      for (int mi = 0; mi < 4; ++mi) {
        const int r = wm + mi*16 + fr;
        af[mi] = *(const bf16x8*)(As + r*64 + (((ks*4+fg) ^ (r & 7)) << 3));
      }
      #pragma unroll
      for (int ni = 0; ni < 4; ++ni) {
        const int r = wn + ni*16 + fr;
        bfr[ni] = *(const bf16x8*)(Bs + r*64 + (((ks*4+fg) ^ (r & 7)) << 3));
      }
      #pragma unroll
      for (int mi = 0; mi < 4; ++mi)
        #pragma unroll
        for (int ni = 0; ni < 4; ++ni)
          acc[mi][ni] = __builtin_amdgcn_mfma_f32_16x16x32_bf16(af[mi], bfr[ni], acc[mi][ni], 0, 0, 0);
    }
    __syncthreads();
  }
  float* Cb = C + (size_t)bz * M * Nn;
  #pragma unroll
  for (int mi = 0; mi < 4; ++mi) {
    #pragma unroll
    for (int ni = 0; ni < 4; ++ni) {
      #pragma unroll
      for (int j = 0; j < 4; ++j) {
        const int m = m0 + wm + mi*16 + fg*4 + j;
        const int n = n0 + wn + ni*16 + fr;
        const size_t idx = (size_t)m * Nn + n;
        float vv = acc[mi][ni][j];
        if (EPI == 0) Cb[idx] = vv;
        else if (EPI == 1) Cb[idx] = siluf(vv);
        else if (EPI == 2) { C2[idx] = vv; Cb[idx] = siluf(vv); }
        else if (EPI == 3) Cb[idx] = vv * dsiluf(Aux[idx]);
        else Cb[idx] = Pw[bz] * Aux[idx] + vv;
      }
    }
  }
}

// ---------------- row-wise RMSNorm in place --------------------------------
__global__ __launch_bounds__(256) void rms_rows_kernel(float* __restrict__ v, const float* __restrict__ w)
{
  const int row = blockIdx.x * 4 + (threadIdx.x >> 6);
  const int lane = threadIdx.x & 63;
  float* p = v + (size_t)row * KD;
  float vals[16]; float ss = 0.f;
  #pragma unroll
  for (int l=0;l<16;l++){ vals[l] = p[lane + (l<<6)]; ss += vals[l]*vals[l]; }
  #pragma unroll
  for (int o=32;o>0;o>>=1) ss += __shfl_xor(ss, o, 64);
  const float inv = rsqrtf(ss * (1.0f/KD) + KEPS);
  #pragma unroll
  for (int l=0;l<16;l++){ const int d = lane + (l<<6); p[d] = vals[l]*inv*w[d]; }
}

// ---------------- per-row backward through rms+MSE -------------------------
__global__ __launch_bounds__(256) void rms_grad_kernel(
    const float* __restrict__ y, const float* __restrict__ kbuf, const float* __restrict__ vbuf,
    const float* __restrict__ lnw, const float* __restrict__ theta,
    float* __restrict__ gy, float* __restrict__ glrow)
{
  const int row = blockIdx.x * 4 + (threadIdx.x >> 6);
  const int lane = threadIdx.x & 63;
  const float th2 = theta[row >> 6] * (2.0f / KD);
  const float* yr = y + (size_t)row * KD;
  const float* kr = kbuf + (size_t)row * KD;
  const float* vr = vbuf + (size_t)row * KD;
  float yv[16]; float ss = 0.f;
  #pragma unroll
  for (int l=0;l<16;l++){ yv[l] = yr[lane + (l<<6)]; ss += yv[l]*yv[l]; }
  #pragma unroll
  for (int o=32;o>0;o>>=1) ss += __shfl_xor(ss, o, 64);
  const float inv = rsqrtf(ss * (1.0f/KD) + KEPS);
  float gzv[16]; float sdot = 0.f;
  #pragma unroll
  for (int l=0;l<16;l++){
    const int d = lane + (l<<6);
    const float gz = th2 * (kr[d] + yv[l]*inv*lnw[d] - vr[d]);
    gzv[l] = gz;
    sdot += gz * lnw[d] * yv[l];
  }
  #pragma unroll
  for (int o=32;o>0;o>>=1) sdot += __shfl_xor(sdot, o, 64);
  const float c3 = inv*inv*inv * (1.0f/KD) * sdot;
  float* gyr = gy + (size_t)row * KD;
  float* glr = glrow + (size_t)row * KD;
  #pragma unroll
  for (int l=0;l<16;l++){
    const int d = lane + (l<<6);
    gyr[d] = inv * lnw[d] * gzv[l] - c3 * yv[l];
    glr[d] = gzv[l] * yv[l] * inv;
  }
}

// ---------------- reduce glrow (64 rows per chunk) -> gl[32][1024] ---------
__global__ __launch_bounds__(256) void glreduce_kernel(
    const float* __restrict__ glrow, float* __restrict__ gl)
{
  const int bn = blockIdx.y, dblk = blockIdx.x;
  const int d = dblk*64 + (threadIdx.x & 63), rg = threadIdx.x >> 6;
  float s = 0.f;
  for (int c = rg; c < KC; c += 4) s += glrow[(size_t)(bn*KC + c)*KD + d];
  __shared__ float L[4][64];
  L[rg][threadIdx.x & 63] = s;
  __syncthreads();
  if (rg == 0)
    gl[(size_t)bn*KD + d] = L[0][threadIdx.x]+L[1][threadIdx.x]+L[2][threadIdx.x]+L[3][threadIdx.x];
}

// ---------------- fp32 transpose (out[C][R] = in[R][C]) --------------------
__global__ __launch_bounds__(256) void transpose_kernel(
    const float* __restrict__ in, float* __restrict__ out, int R, int Cc)
{
  __shared__ float T[64][65];
  const int r0 = blockIdx.y*64, c0 = blockIdx.x*64;
  const int tx = threadIdx.x & 15, ty = threadIdx.x >> 4;
  #pragma unroll
  for (int i=0;i<4;i++){
    const float4 v = *(const float4*)(in + (size_t)(r0+ty+i*16)*Cc + c0 + tx*4);
    T[ty+i*16][tx*4+0]=v.x; T[ty+i*16][tx*4+1]=v.y; T[ty+i*16][tx*4+2]=v.z; T[ty+i*16][tx*4+3]=v.w;
  }
  __syncthreads();
  #pragma unroll
  for (int i=0;i<4;i++){
    float4 v;
    v.x=T[tx*4+0][ty+i*16]; v.y=T[tx*4+1][ty+i*16]; v.z=T[tx*4+2][ty+i*16]; v.w=T[tx*4+3][ty+i*16];
    *(float4*)(out + (size_t)(c0+ty+i*16)*R + r0 + tx*4) = v;
  }
}

// ---------------- scaled dual transpose: outM/outS = cm/cs (per src row chunk) * in^T
__global__ __launch_bounds__(256) void transpose2_kernel(
    const float* __restrict__ in, float* __restrict__ outM, float* __restrict__ outS,
    const float* __restrict__ cm, const float* __restrict__ cs, int R, int Cc)
{
  __shared__ float T[64][65];
  const int r0 = blockIdx.y*64, c0 = blockIdx.x*64;
  const int tx = threadIdx.x & 15, ty = threadIdx.x >> 4;
  #pragma unroll
  for (int i=0;i<4;i++){
    const float4 v = *(const float4*)(in + (size_t)(r0+ty+i*16)*Cc + c0 + tx*4);
    T[ty+i*16][tx*4+0]=v.x; T[ty+i*16][tx*4+1]=v.y; T[ty+i*16][tx*4+2]=v.z; T[ty+i*16][tx*4+3]=v.w;
  }
  __syncthreads();
  const float fm = cm[r0>>6], fs = cs[r0>>6];   // src rows are tokens; 64-aligned chunks
  #pragma unroll
  for (int i=0;i<4;i++){
    float4 v;
    v.x=T[tx*4+0][ty+i*16]; v.y=T[tx*4+1][ty+i*16]; v.z=T[tx*4+2][ty+i*16]; v.w=T[tx*4+3][ty+i*16];
    float4 vm = { v.x*fm, v.y*fm, v.z*fm, v.w*fm };
    float4 vs = { v.x*fs, v.y*fs, v.z*fs, v.w*fs };
    *(float4*)(outM + (size_t)(c0+ty+i*16)*R + r0 + tx*4) = vm;
    *(float4*)(outS + (size_t)(c0+ty+i*16)*R + r0 + tx*4) = vs;
  }
}

// ---------------- nln / nsl ------------------------------------------------
__global__ void glcomb_kernel(const float* __restrict__ gl, const float* __restrict__ lnw,
                              const float* __restrict__ cm, const float* __restrict__ cs,
                              const float* __restrict__ Pw,
                              float* __restrict__ nln, float* __restrict__ nsl)
{
  const int idx = blockIdx.x*256 + threadIdx.x;
  const int b = idx >> 10, d = idx & (KD-1);
  float am=0.f, as=0.f;
  for (int n=0;n<KN;n++){
    const float g = gl[(size_t)(b*KN+n)*KD + d];
    am += cm[b*KN+n]*g; as += cs[b*KN+n]*g;
  }
  nln[idx] = Pw[b]*lnw[d] + am;
  nsl[idx] = as;
}

// ---------------- final out ------------------------------------------------
__global__ __launch_bounds__(256) void final_out_kernel(
    const float* __restrict__ q, const float* __restrict__ yq, const float* __restrict__ nln,
    float* __restrict__ out)
{
  const int row = blockIdx.x * 4 + (threadIdx.x >> 6);
  const int lane = threadIdx.x & 63;
  const int b = row >> 10;
  const float* yr = yq + (size_t)row * KD;
  float yv[16]; float ss = 0.f;
  #pragma unroll
  for (int l=0;l<16;l++){ yv[l] = yr[lane + (l<<6)]; ss += yv[l]*yv[l]; }
  #pragma unroll
  for (int o=32;o>0;o>>=1) ss += __shfl_xor(ss, o, 64);
  const float inv = rsqrtf(ss * (1.0f/KD) + KEPS);
  #pragma unroll
  for (int l=0;l<16;l++){
    const int d = lane + (l<<6);
    out[(size_t)row*KD + d] = q[(size_t)row*KD + d] + yv[l]*inv*nln[b*KD + d];
  }
}

extern "C" void kernel_launch(void* const* d_in, const int* in_sizes, int n_in,
                              void* d_out, int out_size, void* d_ws, size_t ws_size,
                              hipStream_t stream)
{
  const float* x    = (const float*)d_in[0];
  const float* w1   = (const float*)d_in[1];
  const float* w2   = (const float*)d_in[2];
  const float* lnw  = (const float*)d_in[3];
  const float* wq   = (const float*)d_in[4];
  const float* wk   = (const float*)d_in[5];
  const float* wv   = (const float*)d_in[6];
  const float* qnw  = (const float*)d_in[7];
  const float* knw  = (const float*)d_in[8];
  const float* aw   = (const float*)d_in[9];
  const float* tw   = (const float*)d_in[10];
  const float* ew   = (const float*)d_in[11];

  float* out = (float*)d_out;
  float* nw1 = out + (size_t)KB*KS*KD;
  float* nw2 = nw1 + (size_t)KB*KI*KD;
  float* nln = nw2 + (size_t)KB*KD*KI;
  float* ns1 = nln + (size_t)KB*KD;
  float* ns2 = ns1 + (size_t)KB*KI*KD;
  float* nsl = ns2 + (size_t)KB*KD*KI;

  const size_t TD = (size_t)KB*KS*KD;   // 2048x1024
  const size_t TI = (size_t)KB*KS*KI;   // 2048x2048
  float* ws = (float*)d_ws;
  size_t o = 0;
  float* kbuf = ws + o; o += TD;
  float* vbuf = ws + o; o += TD;   // later gyMT
  float* qbuf = ws + o; o += TD;
  float* abuf = ws + o; o += TI;   // later gaMT
  float* hbuf = ws + o; o += TI;   // later gaST
  float* ybuf = ws + o; o += TD;   // later gyST
  float* gybuf= ws + o; o += TD;
  float* gabuf= ws + o; o += TI;   // later hq
  float* glrow= ws + o; o += TD;   // later yq
  float* kT   = ws + o; o += TD;
  float* hT   = ws + o; o += TI;
  float* w2t  = ws + o; o += TD;
  float* gl   = ws + o; o += (size_t)KB*KN*KD;
  float* part = ws + o; o += 1536;
  float* cmb  = ws + o; o += 32;
  float* csb  = ws + o; o += 32;
  float* Pwb  = ws + o; o += 32;
  float* thetab = ws + o; o += 32;

  float* gaMT = abuf;
  float* gaST = hbuf;
  float* gyMT = vbuf;
  float* gyST = ybuf;
  float* hq   = gabuf;
  float* yq   = glrow;

  dim3 blk(256);
  const long BS1 = (long)KI*KD;  // nw1 batch stride
  const long BS2 = (long)KD*KI;

  gates_part_kernel<<<dim3(16,32), blk, 0, stream>>>(x, aw, tw, ew, part);
  scan_coef_kernel<<<1, 64, 0, stream>>>(part, cmb, csb, Pwb, thetab);

  // projections
  mfma_gemm<1><<<dim3(8,16,1), blk, 0, stream>>>(x, wk, kbuf, nullptr, nullptr, nullptr,
                                                 2048, 1024, 1024, 1024, 1024, 0, 0);
  mfma_gemm<1><<<dim3(8,16,1), blk, 0, stream>>>(x, wv, vbuf, nullptr, nullptr, nullptr,
                                                 2048, 1024, 1024, 1024, 1024, 0, 0);
  mfma_gemm<1><<<dim3(8,16,1), blk, 0, stream>>>(x, wq, qbuf, nullptr, nullptr, nullptr,
                                                 2048, 1024, 1024, 1024, 1024, 0, 0);
  rms_rows_kernel<<<512, blk, 0, stream>>>(kbuf, knw);
  rms_rows_kernel<<<512, blk, 0, stream>>>(qbuf, qnw);

  // memory forward at initial weights
  mfma_gemm<2><<<dim3(16,16,1), blk, 0, stream>>>(kbuf, w1, hbuf, abuf, nullptr, nullptr,
                                                  2048, 2048, 1024, 1024, 1024, 0, 0);
  transpose_kernel<<<dim3(32,16), blk, 0, stream>>>(w2, w2t, 1024, 2048);
  mfma_gemm<0><<<dim3(8,16,1), blk, 0, stream>>>(hbuf, w2, ybuf, nullptr, nullptr, nullptr,
                                                 2048, 1024, 2048, 2048, 2048, 0, 0);

  // backward
  rms_grad_kernel<<<512, blk, 0, stream>>>(ybuf, kbuf, vbuf, lnw, thetab, gybuf, glrow);
  glreduce_kernel<<<dim3(16,32), blk, 0, stream>>>(glrow, gl);
  mfma_gemm<3><<<dim3(16,16,1), blk, 0, stream>>>(gybuf, w2t, gabuf, nullptr, abuf, nullptr,
                                                  2048, 2048, 1024, 1024, 1024, 0, 0);

  // transposes for the weighted-gradient GEMMs
  transpose_kernel<<<dim3(16,32), blk, 0, stream>>>(kbuf, kT, 2048, 1024);
  transpose_kernel<<<dim3(32,32), blk, 0, stream>>>(hbuf, hT, 2048, 2048);
  transpose2_kernel<<<dim3(32,32), blk, 0, stream>>>(gabuf, gaMT, gaST, cmb, csb, 2048, 2048);
  transpose2_kernel<<<dim3(16,32), blk, 0, stream>>>(gybuf, gyMT, gyST, cmb, csb, 2048, 1024);

  // scan-weighted gradient GEMMs (z = batch, K-columns offset by z*1024)
  mfma_gemm<4><<<dim3(8,16,2), blk, 0, stream>>>(gaMT, kT, nw1, nullptr, w1, Pwb,
                                                 2048, 1024, 1024, 2048, 2048, 0, 1024);
  mfma_gemm<0><<<dim3(8,16,2), blk, 0, stream>>>(gaST, kT, ns1, nullptr, nullptr, nullptr,
                                                 2048, 1024, 1024, 2048, 2048, 0, 1024);
  mfma_gemm<4><<<dim3(16,8,2), blk, 0, stream>>>(gyMT, hT, nw2, nullptr, w2, Pwb,
                                                 1024, 2048, 1024, 2048, 2048, 0, 1024);
  mfma_gemm<0><<<dim3(16,8,2), blk, 0, stream>>>(gyST, hT, ns2, nullptr, nullptr, nullptr,
                                                 1024, 2048, 1024, 2048, 2048, 0, 1024);
  glcomb_kernel<<<8, blk, 0, stream>>>(gl, lnw, cmb, csb, Pwb, nln, nsl);

  // retrieval with updated weights
  mfma_gemm<1><<<dim3(16,16,1), blk, 0, stream>>>(qbuf, nw1, hq, nullptr, nullptr, nullptr,
                                                  2048, 2048, 1024, 1024, 1024, BS1, 0);
  mfma_gemm<0><<<dim3(8,16,1), blk, 0, stream>>>(hq, nw2, yq, nullptr, nullptr, nullptr,
                                                 2048, 1024, 2048, 2048, 2048, BS2, 0);
  final_out_kernel<<<512, blk, 0, stream>>>(qbuf, yq, nln, out);
}

// Round 3
// 291.603 us; speedup vs baseline: 5.9458x; 1.9904x over previous
//
#include <hip/hip_runtime.h>

#define KD 1024   // D
#define KI 2048   // I
#define KB 2      // B
#define KS 1024   // S
#define KC 64     // C
#define KN 16     // N chunks
#define KEPS 1e-6f

typedef __bf16 bf16x8 __attribute__((ext_vector_type(8)));
typedef __bf16 bf16x4 __attribute__((ext_vector_type(4)));
typedef float f32x4 __attribute__((ext_vector_type(4)));

__device__ __forceinline__ float sigf(float x){ return 1.0f/(1.0f+__expf(-x)); }
__device__ __forceinline__ float siluf(float x){ return x*sigf(x); }
__device__ __forceinline__ float dsiluf(float x){ float s=sigf(x); return s*(1.0f+x*(1.0f-s)); }

// width-16 global->LDS DMA; LDS dest is wave-uniform base + lane*16
__device__ __forceinline__ void gld16(const __bf16* g, __bf16* l) {
  __builtin_amdgcn_global_load_lds(
    (const __attribute__((address_space(1))) unsigned int*)g,
    (__attribute__((address_space(3))) unsigned int*)l, 16, 0, 0);
}

// ---------------- one-shot fp32 -> bf16 conversions ------------------------
// x(2M) wk(1M) wv(1M) wq(1M) w1(2M) w2(2M) elems; processed as float4s
__global__ __launch_bounds__(256) void convert6_kernel(
  const float* __restrict__ x, const float* __restrict__ wk, const float* __restrict__ wv,
  const float* __restrict__ wq, const float* __restrict__ w1, const float* __restrict__ w2,
  __bf16* __restrict__ xb, __bf16* __restrict__ wkb, __bf16* __restrict__ wvb,
  __bf16* __restrict__ wqb, __bf16* __restrict__ w1b, __bf16* __restrict__ w2b)
{
  const long t = (long)blockIdx.x*256 + threadIdx.x;   // float4 index
  const float* s; __bf16* d; long i;
  if (t < 524288)       { s=x;  d=xb;  i=t; }
  else if (t < 786432)  { s=wk; d=wkb; i=t-524288; }
  else if (t < 1048576) { s=wv; d=wvb; i=t-786432; }
  else if (t < 1310720) { s=wq; d=wqb; i=t-1048576; }
  else if (t < 1835008) { s=w1; d=w1b; i=t-1310720; }
  else                  { s=w2; d=w2b; i=t-1835008; }
  const float4 v = *(const float4*)(s + i*4);
  bf16x4 o = { (__bf16)v.x, (__bf16)v.y, (__bf16)v.z, (__bf16)v.w };
  *(bf16x4*)(d + i*4) = o;
}

// ---------------- transpose -> bf16 (SRCF=1: fp32 src, 0: bf16 src) --------
template<int SRCF>
__global__ __launch_bounds__(256) void tconv_kernel(const void* __restrict__ in,
    __bf16* __restrict__ out, int R, int Cc)
{
  __shared__ float T[64][65];
  const int r0 = blockIdx.y*64, c0 = blockIdx.x*64;
  const int tx = threadIdx.x & 15, ty = threadIdx.x >> 4;
  #pragma unroll
  for (int i=0;i<4;i++){
    const int r = r0 + ty + i*16;
    if (SRCF) {
      const float4 v = *(const float4*)((const float*)in + (size_t)r*Cc + c0 + tx*4);
      T[ty+i*16][tx*4+0]=v.x; T[ty+i*16][tx*4+1]=v.y;
      T[ty+i*16][tx*4+2]=v.z; T[ty+i*16][tx*4+3]=v.w;
    } else {
      const bf16x4 v = *(const bf16x4*)((const __bf16*)in + (size_t)r*Cc + c0 + tx*4);
      T[ty+i*16][tx*4+0]=(float)v[0]; T[ty+i*16][tx*4+1]=(float)v[1];
      T[ty+i*16][tx*4+2]=(float)v[2]; T[ty+i*16][tx*4+3]=(float)v[3];
    }
  }
  __syncthreads();
  #pragma unroll
  for (int i=0;i<4;i++){
    bf16x4 o = { (__bf16)T[tx*4+0][ty+i*16], (__bf16)T[tx*4+1][ty+i*16],
                 (__bf16)T[tx*4+2][ty+i*16], (__bf16)T[tx*4+3][ty+i*16] };
    *(bf16x4*)(out + (size_t)(c0+ty+i*16)*R + r0 + tx*4) = o;
  }
}

// ---------------- gates partial dots ---------------------------------------
__global__ __launch_bounds__(256) void gates_part_kernel(
    const float* __restrict__ x, const float* __restrict__ aw,
    const float* __restrict__ tw, const float* __restrict__ ew,
    float* __restrict__ part)
{
  const int seg = blockIdx.x, bn = blockIdx.y;
  const int base = seg*4096;
  float da=0.f, dt=0.f, de=0.f;
  #pragma unroll
  for (int i=0;i<4;i++){
    const int off = base + i*1024 + threadIdx.x*4;
    const float4 xv = *(const float4*)(x + (size_t)bn*65536 + off);
    const float4 av = *(const float4*)(aw + off);
    const float4 tv = *(const float4*)(tw + off);
    const float4 ev = *(const float4*)(ew + off);
    da += xv.x*av.x + xv.y*av.y + xv.z*av.z + xv.w*av.w;
    dt += xv.x*tv.x + xv.y*tv.y + xv.z*tv.z + xv.w*tv.w;
    de += xv.x*ev.x + xv.y*ev.y + xv.z*ev.z + xv.w*ev.w;
  }
  __shared__ float sA[256], sT[256], sE[256];
  sA[threadIdx.x]=da; sT[threadIdx.x]=dt; sE[threadIdx.x]=de;
  __syncthreads();
  for (int s=128;s>0;s>>=1){
    if ((int)threadIdx.x < s){
      sA[threadIdx.x]+=sA[threadIdx.x+s];
      sT[threadIdx.x]+=sT[threadIdx.x+s];
      sE[threadIdx.x]+=sE[threadIdx.x+s];
    }
    __syncthreads();
  }
  if (threadIdx.x==0){
    part[0*512 + bn*16 + seg] = sA[0];
    part[1*512 + bn*16 + seg] = sT[0];
    part[2*512 + bn*16 + seg] = sE[0];
  }
}

// ---------------- scan coefficients (closed form) --------------------------
__global__ void scan_coef_kernel(const float* __restrict__ part,
                                 float* __restrict__ cm, float* __restrict__ cs,
                                 float* __restrict__ Pw, float* __restrict__ theta)
{
  const int b = threadIdx.x;
  if (b >= KB) return;
  float al[KN], et[KN];
  for (int n=0;n<KN;n++){
    float sa=0.f, st=0.f, se=0.f;
    for (int s=0;s<16;s++){
      sa += part[0*512 + (b*KN+n)*16 + s];
      st += part[1*512 + (b*KN+n)*16 + s];
      se += part[2*512 + (b*KN+n)*16 + s];
    }
    al[n] = sigf(sa);
    theta[b*KN+n] = sigf(st)*0.01f;
    et[n] = sigf(se);
  }
  float prodE = 1.f;
  for (int j=KN-1;j>=0;j--){ cs[b*KN+j] = -prodE; prodE *= et[j]; }
  float A[KN]; A[KN-1]=1.f;
  for (int t=KN-2;t>=0;t--) A[t] = A[t+1]*(1.f-al[t+1]);
  for (int j=0;j<KN;j++){
    float inner=0.f, E=1.f;
    for (int t=j;t<KN;t++){ inner += A[t]*E; if (t+1<KN) E *= et[t+1]; }
    cm[b*KN+j] = -inner;
  }
  float pw=1.f;
  for (int n=0;n<KN;n++) pw *= (1.f-al[n]);
  Pw[b]=pw;
}

// ---------------- MFMA bf16 GEMM, glds staging: C = A[M,K] * B[N,K]^T ------
// BM=128, BK=64. BN in {128,64}. LDS linear; source-address XOR pre-swizzle +
// XOR read swizzle (2-way conflicts = free).
// EPI: 0 Cf=acc; 1 Cf=silu (z selects B/C from {Bm,B1,B2}/{Cf,Cf1,Cf2});
//      2 C2f=acc, Cb=bf16(silu); 3 Cb=bf16(acc*dsilu(C2f)); 4 Cb=bf16(silu)
template<int BN, int EPI>
__global__ __launch_bounds__(256) void mgemm(
    const __bf16* __restrict__ A, const __bf16* __restrict__ Bm,
    float* __restrict__ Cf, __bf16* __restrict__ Cb, float* __restrict__ C2f,
    const __bf16* __restrict__ B1, const __bf16* __restrict__ B2,
    float* __restrict__ Cf1, float* __restrict__ Cf2,
    int M, int Nn, int K, int lda, int ldb, long b_bstride)
{
  constexpr int WN = BN/32;
  const int bz = blockIdx.z;
  const int n0 = blockIdx.x * BN;
  const int m0 = blockIdx.y * 128;
  const __bf16* Bp = Bm;
  float* Cfp = Cf;
  if (EPI==1) {
    if (bz==1){ Bp=B1; Cfp=Cf1; } else if (bz==2){ Bp=B2; Cfp=Cf2; }
  }
  Bp += (size_t)(m0 >> 10) * (size_t)b_bstride;
  __shared__ __bf16 As[128*64];
  __shared__ __bf16 Bs[BN*64];
  const int tid = threadIdx.x;
  const int wv = tid >> 6, lane = tid & 63;
  const int wm = (wv >> 1) << 6, wn = (wv & 1) * (BN >> 1);
  const int fr = lane & 15, fg = lane >> 4;
  const int lr = lane >> 3, lc = lane & 7;
  f32x4 acc[4][WN] = {};
  for (int k0 = 0; k0 < K; k0 += 64) {
    #pragma unroll
    for (int i = 0; i < 4; ++i) {
      const int rowbase = (wv*4 + i)*8;
      const int row = rowbase + lr;
      const int sc = (lc ^ (row & 7)) << 3;
      gld16(A + (size_t)(m0 + row)*lda + k0 + sc, As + rowbase*64);
    }
    #pragma unroll
    for (int i = 0; i < BN/32; ++i) {
      const int rowbase = (wv*(BN/32) + i)*8;
      const int row = rowbase + lr;
      const int sc = (lc ^ (row & 7)) << 3;
      gld16(Bp + (size_t)(n0 + row)*ldb + k0 + sc, Bs + rowbase*64);
    }
    __syncthreads();
    #pragma unroll
    for (int ks = 0; ks < 2; ++ks) {
      bf16x8 af[4], bfv[WN];
      #pragma unroll
      for (int mi = 0; mi < 4; ++mi) {
        const int r = wm + mi*16 + fr;
        af[mi] = *(const bf16x8*)(As + r*64 + ((((ks<<2)+fg) ^ (r & 7)) << 3));
      }
      #pragma unroll
      for (int ni = 0; ni < WN; ++ni) {
        const int r = wn + ni*16 + fr;
        bfv[ni] = *(const bf16x8*)(Bs + r*64 + ((((ks<<2)+fg) ^ (r & 7)) << 3));
      }
      #pragma unroll
      for (int mi = 0; mi < 4; ++mi)
        #pragma unroll
        for (int ni = 0; ni < WN; ++ni)
          acc[mi][ni] = __builtin_amdgcn_mfma_f32_16x16x32_bf16(af[mi], bfv[ni], acc[mi][ni], 0,0,0);
    }
    __syncthreads();
  }
  #pragma unroll
  for (int mi = 0; mi < 4; ++mi) {
    #pragma unroll
    for (int ni = 0; ni < WN; ++ni) {
      #pragma unroll
      for (int j = 0; j < 4; ++j) {
        const int m = m0 + wm + mi*16 + fg*4 + j;
        const int n = n0 + wn + ni*16 + fr;
        const size_t idx = (size_t)m * Nn + n;
        const float v = acc[mi][ni][j];
        if (EPI==0) Cfp[idx] = v;
        else if (EPI==1) Cfp[idx] = siluf(v);
        else if (EPI==2) { C2f[idx] = v; Cb[idx] = (__bf16)siluf(v); }
        else if (EPI==3) Cb[idx] = (__bf16)(v * dsiluf(C2f[idx]));
        else if (EPI==4) Cb[idx] = (__bf16)siluf(v);
      }
    }
  }
}

// ---------------- dual scan-weighted GEMM ----------------------------------
// outM = Pw*Winit + sum_chunk cm[chunk] * (A_chunk B_chunk^T), outS with cs.
// A[M][2048] bf16 (param-major, token cols), B[N][2048] bf16. BK=64=chunk.
// tile 128x64, 4 waves (wave 64x32 -> 4x2 frags), 3 acc sets via temp P.
__global__ __launch_bounds__(256) void wacc_dual_kernel(
    const __bf16* __restrict__ A, const __bf16* __restrict__ B,
    const float* __restrict__ Winit,
    const float* __restrict__ cm, const float* __restrict__ cs,
    const float* __restrict__ Pw,
    float* __restrict__ outM, __bf16* __restrict__ outMb, float* __restrict__ outS,
    int M, int Nn, int lda, int ldb)
{
  const int bz = blockIdx.z;
  const int n0 = blockIdx.x * 64;
  const int m0 = blockIdx.y * 128;
  const __bf16* Ap = A + (size_t)bz*1024;
  const __bf16* Bp = B + (size_t)bz*1024;
  __shared__ __bf16 As[128*64];
  __shared__ __bf16 Bs[64*64];
  const int tid = threadIdx.x;
  const int wv = tid >> 6, lane = tid & 63;
  const int wm = (wv >> 1) << 6, wn = (wv & 1) << 5;
  const int fr = lane & 15, fg = lane >> 4;
  const int lr = lane >> 3, lc = lane & 7;
  f32x4 accM[4][2] = {}, accS[4][2] = {};
  for (int k0 = 0; k0 < 1024; k0 += 64) {
    #pragma unroll
    for (int i = 0; i < 4; ++i) {
      const int rowbase = (wv*4 + i)*8;
      const int row = rowbase + lr;
      const int sc = (lc ^ (row & 7)) << 3;
      gld16(Ap + (size_t)(m0 + row)*lda + k0 + sc, As + rowbase*64);
    }
    #pragma unroll
    for (int i = 0; i < 2; ++i) {
      const int rowbase = (wv*2 + i)*8;
      const int row = rowbase + lr;
      const int sc = (lc ^ (row & 7)) << 3;
      gld16(Bp + (size_t)(n0 + row)*ldb + k0 + sc, Bs + rowbase*64);
    }
    __syncthreads();
    const int chunk = bz*KN + (k0 >> 6);
    const float cmc = cm[chunk], csc = cs[chunk];
    bf16x8 a0[4], a1[4], b0[2], b1[2];
    #pragma unroll
    for (int mi = 0; mi < 4; ++mi) {
      const int r = wm + mi*16 + fr;
      a0[mi] = *(const bf16x8*)(As + r*64 + (((0+fg) ^ (r & 7)) << 3));
      a1[mi] = *(const bf16x8*)(As + r*64 + (((4+fg) ^ (r & 7)) << 3));
    }
    #pragma unroll
    for (int ni = 0; ni < 2; ++ni) {
      const int r = wn + ni*16 + fr;
      b0[ni] = *(const bf16x8*)(Bs + r*64 + (((0+fg) ^ (r & 7)) << 3));
      b1[ni] = *(const bf16x8*)(Bs + r*64 + (((4+fg) ^ (r & 7)) << 3));
    }
    #pragma unroll
    for (int mi = 0; mi < 4; ++mi) {
      #pragma unroll
      for (int ni = 0; ni < 2; ++ni) {
        const f32x4 zf = {0.f,0.f,0.f,0.f};
        f32x4 P = __builtin_amdgcn_mfma_f32_16x16x32_bf16(a0[mi], b0[ni], zf, 0,0,0);
        P = __builtin_amdgcn_mfma_f32_16x16x32_bf16(a1[mi], b1[ni], P, 0,0,0);
        accM[mi][ni] += P * cmc;
        accS[mi][ni] += P * csc;
      }
    }
    __syncthreads();
  }
  const float pw = Pw[bz];
  #pragma unroll
  for (int mi = 0; mi < 4; ++mi) {
    #pragma unroll
    for (int ni = 0; ni < 2; ++ni) {
      #pragma unroll
      for (int j = 0; j < 4; ++j) {
        const int m = m0 + wm + mi*16 + fg*4 + j;
        const int n = n0 + wn + ni*16 + fr;
        const size_t widx = (size_t)m * Nn + n;
        const size_t oidx = (size_t)bz * M * Nn + widx;
        const float vm = pw * Winit[widx] + accM[mi][ni][j];
        outM[oidx] = vm;
        outMb[oidx] = (__bf16)vm;
        outS[oidx] = accS[mi][ni][j];
      }
    }
  }
}

// ---------------- fused RMSNorm for k and q (fp32 in place + bf16 copy) ----
__global__ __launch_bounds__(256) void rmsfuse_kernel(
    float* __restrict__ kv, const float* __restrict__ kw, __bf16* __restrict__ k16,
    float* __restrict__ qv, const float* __restrict__ qw, __bf16* __restrict__ q16)
{
  float* v; const float* w; __bf16* o16;
  if (blockIdx.y == 0){ v=kv; w=kw; o16=k16; } else { v=qv; w=qw; o16=q16; }
  const int row = blockIdx.x * 4 + (threadIdx.x >> 6);
  const int lane = threadIdx.x & 63;
  float* p = v + (size_t)row * KD;
  __bf16* p16 = o16 + (size_t)row * KD;
  float vals[16]; float ss = 0.f;
  #pragma unroll
  for (int l=0;l<16;l++){ vals[l] = p[lane + (l<<6)]; ss += vals[l]*vals[l]; }
  #pragma unroll
  for (int o=32;o>0;o>>=1) ss += __shfl_xor(ss, o, 64);
  const float inv = rsqrtf(ss * (1.0f/KD) + KEPS);
  #pragma unroll
  for (int l=0;l<16;l++){
    const int d = lane + (l<<6);
    const float r = vals[l]*inv*w[d];
    p[d] = r; p16[d] = (__bf16)r;
  }
}

// ---------------- per-row backward through rms+MSE -------------------------
__global__ __launch_bounds__(256) void rms_grad_kernel(
    const float* __restrict__ y, const float* __restrict__ kbuf, const float* __restrict__ vbuf,
    const float* __restrict__ lnw, const float* __restrict__ theta,
    __bf16* __restrict__ gy, float* __restrict__ glrow)
{
  const int row = blockIdx.x * 4 + (threadIdx.x >> 6);
  const int lane = threadIdx.x & 63;
  const float th2 = theta[row >> 6] * (2.0f / KD);
  const float* yr = y + (size_t)row * KD;
  const float* kr = kbuf + (size_t)row * KD;
  const float* vr = vbuf + (size_t)row * KD;
  float yv[16]; float ss = 0.f;
  #pragma unroll
  for (int l=0;l<16;l++){ yv[l] = yr[lane + (l<<6)]; ss += yv[l]*yv[l]; }
  #pragma unroll
  for (int o=32;o>0;o>>=1) ss += __shfl_xor(ss, o, 64);
  const float inv = rsqrtf(ss * (1.0f/KD) + KEPS);
  float gzv[16]; float sdot = 0.f;
  #pragma unroll
  for (int l=0;l<16;l++){
    const int d = lane + (l<<6);
    const float gz = th2 * (kr[d] + yv[l]*inv*lnw[d] - vr[d]);
    gzv[l] = gz;
    sdot += gz * lnw[d] * yv[l];
  }
  #pragma unroll
  for (int o=32;o>0;o>>=1) sdot += __shfl_xor(sdot, o, 64);
  const float c3 = inv*inv*inv * (1.0f/KD) * sdot;
  __bf16* gyr = gy + (size_t)row * KD;
  float* glr = glrow + (size_t)row * KD;
  #pragma unroll
  for (int l=0;l<16;l++){
    const int d = lane + (l<<6);
    gyr[d] = (__bf16)(inv * lnw[d] * gzv[l] - c3 * yv[l]);
    glr[d] = gzv[l] * yv[l] * inv;
  }
}

// ---------------- reduce glrow -> gl[32][1024] -----------------------------
__global__ __launch_bounds__(256) void glreduce_kernel(
    const float* __restrict__ glrow, float* __restrict__ gl)
{
  const int bn = blockIdx.y, dblk = blockIdx.x;
  const int d = dblk*64 + (threadIdx.x & 63), rg = threadIdx.x >> 6;
  float s = 0.f;
  for (int c = rg; c < KC; c += 4) s += glrow[(size_t)(bn*KC + c)*KD + d];
  __shared__ float L[4][64];
  L[rg][threadIdx.x & 63] = s;
  __syncthreads();
  if (rg == 0)
    gl[(size_t)bn*KD + d] = L[0][threadIdx.x]+L[1][threadIdx.x]+L[2][threadIdx.x]+L[3][threadIdx.x];
}

// ---------------- nln / nsl ------------------------------------------------
__global__ void glcomb_kernel(const float* __restrict__ gl, const float* __restrict__ lnw,
                              const float* __restrict__ cm, const float* __restrict__ cs,
                              const float* __restrict__ Pw,
                              float* __restrict__ nln, float* __restrict__ nsl)
{
  const int idx = blockIdx.x*256 + threadIdx.x;
  const int b = idx >> 10, d = idx & (KD-1);
  float am=0.f, as=0.f;
  for (int n=0;n<KN;n++){
    const float g = gl[(size_t)(b*KN+n)*KD + d];
    am += cm[b*KN+n]*g; as += cs[b*KN+n]*g;
  }
  nln[idx] = Pw[b]*lnw[d] + am;
  nsl[idx] = as;
}

// ---------------- final out ------------------------------------------------
__global__ __launch_bounds__(256) void final_out_kernel(
    const float* __restrict__ q, const float* __restrict__ yq, const float* __restrict__ nln,
    float* __restrict__ out)
{
  const int row = blockIdx.x * 4 + (threadIdx.x >> 6);
  const int lane = threadIdx.x & 63;
  const int b = row >> 10;
  const float* yr = yq + (size_t)row * KD;
  float yv[16]; float ss = 0.f;
  #pragma unroll
  for (int l=0;l<16;l++){ yv[l] = yr[lane + (l<<6)]; ss += yv[l]*yv[l]; }
  #pragma unroll
  for (int o=32;o>0;o>>=1) ss += __shfl_xor(ss, o, 64);
  const float inv = rsqrtf(ss * (1.0f/KD) + KEPS);
  #pragma unroll
  for (int l=0;l<16;l++){
    const int d = lane + (l<<6);
    out[(size_t)row*KD + d] = q[(size_t)row*KD + d] + yv[l]*inv*nln[b*KD + d];
  }
}

extern "C" void kernel_launch(void* const* d_in, const int* in_sizes, int n_in,
                              void* d_out, int out_size, void* d_ws, size_t ws_size,
                              hipStream_t stream)
{
  const float* x    = (const float*)d_in[0];
  const float* w1   = (const float*)d_in[1];
  const float* w2   = (const float*)d_in[2];
  const float* lnw  = (const float*)d_in[3];
  const float* wq   = (const float*)d_in[4];
  const float* wk   = (const float*)d_in[5];
  const float* wv   = (const float*)d_in[6];
  const float* qnw  = (const float*)d_in[7];
  const float* knw  = (const float*)d_in[8];
  const float* aw   = (const float*)d_in[9];
  const float* tw   = (const float*)d_in[10];
  const float* ew   = (const float*)d_in[11];

  float* out = (float*)d_out;
  float* nw1 = out + (size_t)KB*KS*KD;
  float* nw2 = nw1 + (size_t)KB*KI*KD;
  float* nln = nw2 + (size_t)KB*KD*KI;
  float* ns1 = nln + (size_t)KB*KD;
  float* ns2 = ns1 + (size_t)KB*KI*KD;
  float* nsl = ns2 + (size_t)KB*KD*KI;

  float* ws = (float*)d_ws;
  size_t o = 0;
  float* kbuf = ws+o; o += 2097152;
  float* vbuf = ws+o; o += 2097152;
  float* qbuf = ws+o; o += 2097152;
  float* abuf = ws+o; o += 4194304;
  float* ybuf = ws+o; o += 2097152;   // y, then yq
  float* glrow= ws+o; o += 2097152;
  float* gl   = ws+o; o += 32768;
  float* part = ws+o; o += 1536;
  float* cmb  = ws+o; o += 32;
  float* csb  = ws+o; o += 32;
  float* Pwb  = ws+o; o += 32;
  float* thetab = ws+o; o += 32;
  __bf16* bb = (__bf16*)(ws + o);
  size_t p = 0;
  __bf16* xb   = bb+p; p += 2097152;  // reused as gyT
  __bf16* wkb  = bb+p; p += 1048576;  // wkb+wvb reused as kT
  __bf16* wvb  = bb+p; p += 1048576;
  __bf16* wqb  = bb+p; p += 1048576;
  __bf16* w1b  = bb+p; p += 2097152;  // reused as gyb
  __bf16* w2b  = bb+p; p += 2097152;  // w2b+w2tb reused as gaT
  __bf16* w2tb = bb+p; p += 2097152;
  __bf16* kb16 = bb+p; p += 2097152;
  __bf16* qb16 = bb+p; p += 2097152;
  __bf16* hb16 = bb+p; p += 4194304;
  __bf16* gab  = bb+p; p += 4194304;  // reused as hq16
  __bf16* hT   = bb+p; p += 4194304;
  __bf16* nw1b = bb+p; p += 4194304;
  __bf16* nw2b = bb+p; p += 4194304;
  __bf16* gyT = xb;
  __bf16* kT  = wkb;
  __bf16* gyb = w1b;
  __bf16* gaT = w2b;
  __bf16* hq16= gab;

  dim3 blk(256);

  convert6_kernel<<<9216, blk, 0, stream>>>(x, wk, wv, wq, w1, w2, xb, wkb, wvb, wqb, w1b, w2b);
  tconv_kernel<1><<<dim3(32,16), blk, 0, stream>>>(w2, w2tb, 1024, 2048);
  gates_part_kernel<<<dim3(16,32), blk, 0, stream>>>(x, aw, tw, ew, part);
  scan_coef_kernel<<<1, 64, 0, stream>>>(part, cmb, csb, Pwb, thetab);

  // projections k/v/q = silu(x W^T), z selects weight/output
  mgemm<128,1><<<dim3(8,16,3), blk, 0, stream>>>(xb, wkb, kbuf, nullptr, nullptr,
      wvb, wqb, vbuf, qbuf, 2048, 1024, 1024, 1024, 1024, 0);
  rmsfuse_kernel<<<dim3(512,2), blk, 0, stream>>>(kbuf, knw, kb16, qbuf, qnw, qb16);
  tconv_kernel<0><<<dim3(16,32), blk, 0, stream>>>(kb16, kT, 2048, 1024);

  // memory forward: a = k w1^T (fp32), h = silu(a) (bf16); y = h w2^T (fp32)
  mgemm<128,2><<<dim3(16,16,1), blk, 0, stream>>>(kb16, w1b, nullptr, hb16, abuf,
      nullptr, nullptr, nullptr, nullptr, 2048, 2048, 1024, 1024, 1024, 0);
  mgemm<64,0><<<dim3(16,16,1), blk, 0, stream>>>(hb16, w2b, ybuf, nullptr, nullptr,
      nullptr, nullptr, nullptr, nullptr, 2048, 1024, 2048, 2048, 2048, 0);

  // backward
  rms_grad_kernel<<<512, blk, 0, stream>>>(ybuf, kbuf, vbuf, lnw, thetab, gyb, glrow);
  glreduce_kernel<<<dim3(16,32), blk, 0, stream>>>(glrow, gl);
  mgemm<128,3><<<dim3(16,16,1), blk, 0, stream>>>(gyb, w2tb, nullptr, gab, abuf,
      nullptr, nullptr, nullptr, nullptr, 2048, 2048, 1024, 1024, 1024, 0);

  // transposes (bf16 -> bf16)
  tconv_kernel<0><<<dim3(32,32), blk, 0, stream>>>(hb16, hT, 2048, 2048);
  tconv_kernel<0><<<dim3(16,32), blk, 0, stream>>>(gyb, gyT, 2048, 1024);
  tconv_kernel<0><<<dim3(32,32), blk, 0, stream>>>(gab, gaT, 2048, 2048);

  // dual scan-weighted GEMMs
  wacc_dual_kernel<<<dim3(16,16,2), blk, 0, stream>>>(gaT, kT, w1, cmb, csb, Pwb,
      nw1, nw1b, ns1, 2048, 1024, 2048, 2048);
  wacc_dual_kernel<<<dim3(32,8,2), blk, 0, stream>>>(gyT, hT, w2, cmb, csb, Pwb,
      nw2, nw2b, ns2, 1024, 2048, 2048, 2048);
  glcomb_kernel<<<8, blk, 0, stream>>>(gl, lnw, cmb, csb, Pwb, nln, nsl);

  // retrieval with updated weights
  mgemm<128,4><<<dim3(16,16,1), blk, 0, stream>>>(qb16, nw1b, nullptr, hq16, nullptr,
      nullptr, nullptr, nullptr, nullptr, 2048, 2048, 1024, 1024, 1024, (long)KI*KD);
  mgemm<64,0><<<dim3(16,16,1), blk, 0, stream>>>(hq16, nw2b, ybuf, nullptr, nullptr,
      nullptr, nullptr, nullptr, nullptr, 2048, 1024, 2048, 2048, 2048, (long)KD*KI);
  final_out_kernel<<<512, blk, 0, stream>>>(qbuf, ybuf, nln, out);
}

// Round 4
// 258.318 us; speedup vs baseline: 6.7119x; 1.1289x over previous
//
#include <hip/hip_runtime.h>

#define KD 1024   // D
#define KI 2048   // I
#define KB 2      // B
#define KS 1024   // S
#define KC 64     // C
#define KN 16     // N chunks
#define KEPS 1e-6f

typedef __bf16 bf16x8 __attribute__((ext_vector_type(8)));
typedef __bf16 bf16x4 __attribute__((ext_vector_type(4)));
typedef float f32x4 __attribute__((ext_vector_type(4)));

__device__ __forceinline__ float sigf(float x){ return 1.0f/(1.0f+__expf(-x)); }
__device__ __forceinline__ float siluf(float x){ return x*sigf(x); }
__device__ __forceinline__ float dsiluf(float x){ float s=sigf(x); return s*(1.0f+x*(1.0f-s)); }

// width-16 global->LDS DMA; LDS dest is wave-uniform base + lane*16
__device__ __forceinline__ void gld16(const __bf16* g, __bf16* l) {
  __builtin_amdgcn_global_load_lds(
    (const __attribute__((address_space(1))) unsigned int*)g,
    (__attribute__((address_space(3))) unsigned int*)l, 16, 0, 0);
}

// ---------------- one-shot fp32 -> bf16 conversions ------------------------
__global__ __launch_bounds__(256) void convert6_kernel(
  const float* __restrict__ x, const float* __restrict__ wk, const float* __restrict__ wv,
  const float* __restrict__ wq, const float* __restrict__ w1, const float* __restrict__ w2,
  __bf16* __restrict__ xb, __bf16* __restrict__ wkb, __bf16* __restrict__ wvb,
  __bf16* __restrict__ wqb, __bf16* __restrict__ w1b, __bf16* __restrict__ w2b)
{
  const long t = (long)blockIdx.x*256 + threadIdx.x;   // float4 index
  const float* s; __bf16* d; long i;
  if (t < 524288)       { s=x;  d=xb;  i=t; }
  else if (t < 786432)  { s=wk; d=wkb; i=t-524288; }
  else if (t < 1048576) { s=wv; d=wvb; i=t-786432; }
  else if (t < 1310720) { s=wq; d=wqb; i=t-1048576; }
  else if (t < 1835008) { s=w1; d=w1b; i=t-1310720; }
  else                  { s=w2; d=w2b; i=t-1835008; }
  const float4 v = *(const float4*)(s + i*4);
  bf16x4 o = { (__bf16)v.x, (__bf16)v.y, (__bf16)v.z, (__bf16)v.w };
  *(bf16x4*)(d + i*4) = o;
}

// ---------------- transpose -> bf16 (SRCF=1: fp32 src, 0: bf16 src) --------
template<int SRCF>
__global__ __launch_bounds__(256) void tconv_kernel(const void* __restrict__ in,
    __bf16* __restrict__ out, int R, int Cc)
{
  __shared__ float T[64][65];
  const int r0 = blockIdx.y*64, c0 = blockIdx.x*64;
  const int tx = threadIdx.x & 15, ty = threadIdx.x >> 4;
  #pragma unroll
  for (int i=0;i<4;i++){
    const int r = r0 + ty + i*16;
    if (SRCF) {
      const float4 v = *(const float4*)((const float*)in + (size_t)r*Cc + c0 + tx*4);
      T[ty+i*16][tx*4+0]=v.x; T[ty+i*16][tx*4+1]=v.y;
      T[ty+i*16][tx*4+2]=v.z; T[ty+i*16][tx*4+3]=v.w;
    } else {
      const bf16x4 v = *(const bf16x4*)((const __bf16*)in + (size_t)r*Cc + c0 + tx*4);
      T[ty+i*16][tx*4+0]=(float)v[0]; T[ty+i*16][tx*4+1]=(float)v[1];
      T[ty+i*16][tx*4+2]=(float)v[2]; T[ty+i*16][tx*4+3]=(float)v[3];
    }
  }
  __syncthreads();
  #pragma unroll
  for (int i=0;i<4;i++){
    bf16x4 o = { (__bf16)T[tx*4+0][ty+i*16], (__bf16)T[tx*4+1][ty+i*16],
                 (__bf16)T[tx*4+2][ty+i*16], (__bf16)T[tx*4+3][ty+i*16] };
    *(bf16x4*)(out + (size_t)(c0+ty+i*16)*R + r0 + tx*4) = o;
  }
}

// ---------------- gates partial dots ---------------------------------------
__global__ __launch_bounds__(256) void gates_part_kernel(
    const float* __restrict__ x, const float* __restrict__ aw,
    const float* __restrict__ tw, const float* __restrict__ ew,
    float* __restrict__ part)
{
  const int seg = blockIdx.x, bn = blockIdx.y;
  const int base = seg*4096;
  float da=0.f, dt=0.f, de=0.f;
  #pragma unroll
  for (int i=0;i<4;i++){
    const int off = base + i*1024 + threadIdx.x*4;
    const float4 xv = *(const float4*)(x + (size_t)bn*65536 + off);
    const float4 av = *(const float4*)(aw + off);
    const float4 tv = *(const float4*)(tw + off);
    const float4 ev = *(const float4*)(ew + off);
    da += xv.x*av.x + xv.y*av.y + xv.z*av.z + xv.w*av.w;
    dt += xv.x*tv.x + xv.y*tv.y + xv.z*tv.z + xv.w*tv.w;
    de += xv.x*ev.x + xv.y*ev.y + xv.z*ev.z + xv.w*ev.w;
  }
  __shared__ float sA[256], sT[256], sE[256];
  sA[threadIdx.x]=da; sT[threadIdx.x]=dt; sE[threadIdx.x]=de;
  __syncthreads();
  for (int s=128;s>0;s>>=1){
    if ((int)threadIdx.x < s){
      sA[threadIdx.x]+=sA[threadIdx.x+s];
      sT[threadIdx.x]+=sT[threadIdx.x+s];
      sE[threadIdx.x]+=sE[threadIdx.x+s];
    }
    __syncthreads();
  }
  if (threadIdx.x==0){
    part[0*512 + bn*16 + seg] = sA[0];
    part[1*512 + bn*16 + seg] = sT[0];
    part[2*512 + bn*16 + seg] = sE[0];
  }
}

// ---------------- scan coefficients (closed form) --------------------------
__global__ void scan_coef_kernel(const float* __restrict__ part,
                                 float* __restrict__ cm, float* __restrict__ cs,
                                 float* __restrict__ Pw, float* __restrict__ theta)
{
  const int b = threadIdx.x;
  if (b >= KB) return;
  float al[KN], et[KN];
  for (int n=0;n<KN;n++){
    float sa=0.f, st=0.f, se=0.f;
    for (int s=0;s<16;s++){
      sa += part[0*512 + (b*KN+n)*16 + s];
      st += part[1*512 + (b*KN+n)*16 + s];
      se += part[2*512 + (b*KN+n)*16 + s];
    }
    al[n] = sigf(sa);
    theta[b*KN+n] = sigf(st)*0.01f;
    et[n] = sigf(se);
  }
  float prodE = 1.f;
  for (int j=KN-1;j>=0;j--){ cs[b*KN+j] = -prodE; prodE *= et[j]; }
  float A[KN]; A[KN-1]=1.f;
  for (int t=KN-2;t>=0;t--) A[t] = A[t+1]*(1.f-al[t+1]);
  for (int j=0;j<KN;j++){
    float inner=0.f, E=1.f;
    for (int t=j;t<KN;t++){ inner += A[t]*E; if (t+1<KN) E *= et[t+1]; }
    cm[b*KN+j] = -inner;
  }
  float pw=1.f;
  for (int n=0;n<KN;n++) pw *= (1.f-al[n]);
  Pw[b]=pw;
}

// ---------------- MFMA bf16 GEMM, dbuf + prefetch-1: C = A*B^T -------------
// BM=128, BN=64, BK=64, K=1024 (16 steps). 4 waves, wave tile 64x32.
// MODE: 0 plain, 1 proj mux (z selects B/C), 2 k-split (z = K half, out += z*M*N)
// EPI: 0 Cf=acc; 1 Cf=silu; 2 C2f=acc & Cb=bf16(silu); 3 Cb=bf16(acc*dsilu(C2f));
//      4 Cb=bf16(silu)
template<int EPI, int MODE>
__global__ __launch_bounds__(256) void mgemm2(
    const __bf16* __restrict__ A, const __bf16* __restrict__ Bm,
    float* __restrict__ Cf, __bf16* __restrict__ Cb, float* __restrict__ C2f,
    const __bf16* __restrict__ B1, const __bf16* __restrict__ B2,
    float* __restrict__ Cf1, float* __restrict__ Cf2,
    int M, int Nn, int lda, int ldb, long b_bstride)
{
  const int bz = blockIdx.z;
  const int n0 = blockIdx.x * 64;
  const int m0 = blockIdx.y * 128;
  const __bf16* Ap = A;
  const __bf16* Bp = Bm;
  float* Cfp = Cf;
  if (MODE==1) { if (bz==1){ Bp=B1; Cfp=Cf1; } else if (bz==2){ Bp=B2; Cfp=Cf2; } }
  int koff0 = 0;
  if (MODE==2) { koff0 = bz << 10; Cfp = Cf + (size_t)bz * M * Nn; }
  Bp += (size_t)(m0 >> 10) * (size_t)b_bstride;
  __shared__ __bf16 As[2*128*64];
  __shared__ __bf16 Bs[2*64*64];
  const int tid = threadIdx.x, wv = tid >> 6, lane = tid & 63;
  const int wm = (wv >> 1) << 6, wn = (wv & 1) << 5;
  const int fr = lane & 15, fg = lane >> 4;
  const int lr = lane >> 3, lc = lane & 7;
  const __bf16* asrc[4]; __bf16* adst[4];
  const __bf16* bsrc[2]; __bf16* bdst[2];
  #pragma unroll
  for (int i=0;i<4;i++){
    const int rowbase=(wv*4+i)*8, row=rowbase+lr;
    asrc[i] = Ap + (size_t)(m0+row)*lda + koff0 + ((lc^(row&7))<<3);
    adst[i] = As + rowbase*64;
  }
  #pragma unroll
  for (int i=0;i<2;i++){
    const int rowbase=(wv*2+i)*8, row=rowbase+lr;
    bsrc[i] = Bp + (size_t)(n0+row)*ldb + koff0 + ((lc^(row&7))<<3);
    bdst[i] = Bs + rowbase*64;
  }
  f32x4 acc[4][2] = {};
  #pragma unroll
  for (int i=0;i<4;i++) gld16(asrc[i], adst[i]);
  #pragma unroll
  for (int i=0;i<2;i++) gld16(bsrc[i], bdst[i]);
  __syncthreads();
  #pragma unroll 2
  for (int t=0;t<16;++t){
    const int p = t & 1;
    if (t < 15){
      const int ko = (t+1) << 6;
      const int q = p ^ 1;
      #pragma unroll
      for (int i=0;i<4;i++) gld16(asrc[i]+ko, adst[i]+q*8192);
      #pragma unroll
      for (int i=0;i<2;i++) gld16(bsrc[i]+ko, bdst[i]+q*4096);
    }
    #pragma unroll
    for (int ks=0;ks<2;++ks){
      bf16x8 af[4], bfv[2];
      #pragma unroll
      for (int mi=0;mi<4;++mi){
        const int r = wm + mi*16 + fr;
        af[mi] = *(const bf16x8*)(As + p*8192 + r*64 + ((((ks<<2)+fg)^(r&7))<<3));
      }
      #pragma unroll
      for (int ni=0;ni<2;++ni){
        const int r = wn + ni*16 + fr;
        bfv[ni] = *(const bf16x8*)(Bs + p*4096 + r*64 + ((((ks<<2)+fg)^(r&7))<<3));
      }
      #pragma unroll
      for (int mi=0;mi<4;++mi)
        #pragma unroll
        for (int ni=0;ni<2;++ni)
          acc[mi][ni] = __builtin_amdgcn_mfma_f32_16x16x32_bf16(af[mi], bfv[ni], acc[mi][ni], 0,0,0);
    }
    __syncthreads();
  }
  #pragma unroll
  for (int mi=0;mi<4;++mi){
    #pragma unroll
    for (int ni=0;ni<2;++ni){
      #pragma unroll
      for (int j=0;j<4;++j){
        const int m = m0 + wm + mi*16 + fg*4 + j;
        const int n = n0 + wn + ni*16 + fr;
        const size_t idx = (size_t)m * Nn + n;
        const float v = acc[mi][ni][j];
        if (EPI==0) Cfp[idx] = v;
        else if (EPI==1) Cfp[idx] = siluf(v);
        else if (EPI==2) { C2f[idx] = v; Cb[idx] = (__bf16)siluf(v); }
        else if (EPI==3) Cb[idx] = (__bf16)(v * dsiluf(C2f[idx]));
        else if (EPI==4) Cb[idx] = (__bf16)siluf(v);
      }
    }
  }
}

// ---------------- dual scan-weighted GEMM, dbuf + prefetch-1 ---------------
// outM = Pw*Winit + sum_chunk cm[chunk]*(A_chunk B_chunk^T); outS with cs.
// A[M][2048], B[N][2048] bf16 (param-major, token cols). BK=64=chunk. z=batch.
__global__ __launch_bounds__(256) void wacc2k_kernel(
    const __bf16* __restrict__ A, const __bf16* __restrict__ B,
    const float* __restrict__ Winit,
    const float* __restrict__ cm, const float* __restrict__ cs,
    const float* __restrict__ Pw,
    float* __restrict__ outM, __bf16* __restrict__ outMb, float* __restrict__ outS,
    int M, int Nn, int lda, int ldb)
{
  const int bz = blockIdx.z;
  const int n0 = blockIdx.x * 64;
  const int m0 = blockIdx.y * 128;
  const int koff0 = bz << 10;
  __shared__ __bf16 As[2*128*64];
  __shared__ __bf16 Bs[2*64*64];
  const int tid = threadIdx.x, wv = tid >> 6, lane = tid & 63;
  const int wm = (wv >> 1) << 6, wn = (wv & 1) << 5;
  const int fr = lane & 15, fg = lane >> 4;
  const int lr = lane >> 3, lc = lane & 7;
  const __bf16* asrc[4]; __bf16* adst[4];
  const __bf16* bsrc[2]; __bf16* bdst[2];
  #pragma unroll
  for (int i=0;i<4;i++){
    const int rowbase=(wv*4+i)*8, row=rowbase+lr;
    asrc[i] = A + (size_t)(m0+row)*lda + koff0 + ((lc^(row&7))<<3);
    adst[i] = As + rowbase*64;
  }
  #pragma unroll
  for (int i=0;i<2;i++){
    const int rowbase=(wv*2+i)*8, row=rowbase+lr;
    bsrc[i] = B + (size_t)(n0+row)*ldb + koff0 + ((lc^(row&7))<<3);
    bdst[i] = Bs + rowbase*64;
  }
  f32x4 accM[4][2] = {}, accS[4][2] = {};
  #pragma unroll
  for (int i=0;i<4;i++) gld16(asrc[i], adst[i]);
  #pragma unroll
  for (int i=0;i<2;i++) gld16(bsrc[i], bdst[i]);
  __syncthreads();
  #pragma unroll 2
  for (int t=0;t<16;++t){
    const int p = t & 1;
    const float cmc = cm[bz*KN + t], csc = cs[bz*KN + t];
    if (t < 15){
      const int ko = (t+1) << 6;
      const int q = p ^ 1;
      #pragma unroll
      for (int i=0;i<4;i++) gld16(asrc[i]+ko, adst[i]+q*8192);
      #pragma unroll
      for (int i=0;i<2;i++) gld16(bsrc[i]+ko, bdst[i]+q*4096);
    }
    bf16x8 a0[4], a1[4], b0[2], b1[2];
    #pragma unroll
    for (int mi=0;mi<4;++mi){
      const int r = wm + mi*16 + fr;
      a0[mi] = *(const bf16x8*)(As + p*8192 + r*64 + (((0+fg)^(r&7))<<3));
      a1[mi] = *(const bf16x8*)(As + p*8192 + r*64 + (((4+fg)^(r&7))<<3));
    }
    #pragma unroll
    for (int ni=0;ni<2;++ni){
      const int r = wn + ni*16 + fr;
      b0[ni] = *(const bf16x8*)(Bs + p*4096 + r*64 + (((0+fg)^(r&7))<<3));
      b1[ni] = *(const bf16x8*)(Bs + p*4096 + r*64 + (((4+fg)^(r&7))<<3));
    }
    #pragma unroll
    for (int mi=0;mi<4;++mi){
      #pragma unroll
      for (int ni=0;ni<2;++ni){
        const f32x4 zf = {0.f,0.f,0.f,0.f};
        f32x4 P = __builtin_amdgcn_mfma_f32_16x16x32_bf16(a0[mi], b0[ni], zf, 0,0,0);
        P = __builtin_amdgcn_mfma_f32_16x16x32_bf16(a1[mi], b1[ni], P, 0,0,0);
        accM[mi][ni] += P * cmc;
        accS[mi][ni] += P * csc;
      }
    }
    __syncthreads();
  }
  const float pw = Pw[bz];
  #pragma unroll
  for (int mi=0;mi<4;++mi){
    #pragma unroll
    for (int ni=0;ni<2;++ni){
      #pragma unroll
      for (int j=0;j<4;++j){
        const int m = m0 + wm + mi*16 + fg*4 + j;
        const int n = n0 + wn + ni*16 + fr;
        const size_t widx = (size_t)m * Nn + n;
        const size_t oidx = (size_t)bz * M * Nn + widx;
        const float vm = pw * Winit[widx] + accM[mi][ni][j];
        outM[oidx] = vm;
        outMb[oidx] = (__bf16)vm;
        outS[oidx] = accS[mi][ni][j];
      }
    }
  }
}

// ---------------- fused RMSNorm for k and q (fp32 in place + bf16 copy) ----
__global__ __launch_bounds__(256) void rmsfuse_kernel(
    float* __restrict__ kv, const float* __restrict__ kw, __bf16* __restrict__ k16,
    float* __restrict__ qv, const float* __restrict__ qw, __bf16* __restrict__ q16)
{
  float* v; const float* w; __bf16* o16;
  if (blockIdx.y == 0){ v=kv; w=kw; o16=k16; } else { v=qv; w=qw; o16=q16; }
  const int row = blockIdx.x * 4 + (threadIdx.x >> 6);
  const int lane = threadIdx.x & 63;
  float* p = v + (size_t)row * KD;
  __bf16* p16 = o16 + (size_t)row * KD;
  float vals[16]; float ss = 0.f;
  #pragma unroll
  for (int l=0;l<16;l++){ vals[l] = p[lane + (l<<6)]; ss += vals[l]*vals[l]; }
  #pragma unroll
  for (int o=32;o>0;o>>=1) ss += __shfl_xor(ss, o, 64);
  const float inv = rsqrtf(ss * (1.0f/KD) + KEPS);
  #pragma unroll
  for (int l=0;l<16;l++){
    const int d = lane + (l<<6);
    const float r = vals[l]*inv*w[d];
    p[d] = r; p16[d] = (__bf16)r;
  }
}

// ---------------- per-row backward through rms+MSE (y = y0+y1 split-K) -----
__global__ __launch_bounds__(256) void rms_grad_kernel(
    const float* __restrict__ y0, const float* __restrict__ y1,
    const float* __restrict__ kbuf, const float* __restrict__ vbuf,
    const float* __restrict__ lnw, const float* __restrict__ theta,
    __bf16* __restrict__ gy, float* __restrict__ glrow)
{
  const int row = blockIdx.x * 4 + (threadIdx.x >> 6);
  const int lane = threadIdx.x & 63;
  const float th2 = theta[row >> 6] * (2.0f / KD);
  const float* yr0 = y0 + (size_t)row * KD;
  const float* yr1 = y1 + (size_t)row * KD;
  const float* kr = kbuf + (size_t)row * KD;
  const float* vr = vbuf + (size_t)row * KD;
  float yv[16]; float ss = 0.f;
  #pragma unroll
  for (int l=0;l<16;l++){
    const int d = lane + (l<<6);
    yv[l] = yr0[d] + yr1[d]; ss += yv[l]*yv[l];
  }
  #pragma unroll
  for (int o=32;o>0;o>>=1) ss += __shfl_xor(ss, o, 64);
  const float inv = rsqrtf(ss * (1.0f/KD) + KEPS);
  float gzv[16]; float sdot = 0.f;
  #pragma unroll
  for (int l=0;l<16;l++){
    const int d = lane + (l<<6);
    const float gz = th2 * (kr[d] + yv[l]*inv*lnw[d] - vr[d]);
    gzv[l] = gz;
    sdot += gz * lnw[d] * yv[l];
  }
  #pragma unroll
  for (int o=32;o>0;o>>=1) sdot += __shfl_xor(sdot, o, 64);
  const float c3 = inv*inv*inv * (1.0f/KD) * sdot;
  __bf16* gyr = gy + (size_t)row * KD;
  float* glr = glrow + (size_t)row * KD;
  #pragma unroll
  for (int l=0;l<16;l++){
    const int d = lane + (l<<6);
    gyr[d] = (__bf16)(inv * lnw[d] * gzv[l] - c3 * yv[l]);
    glr[d] = gzv[l] * yv[l] * inv;
  }
}

// ---------------- reduce glrow -> gl[32][1024] -----------------------------
__global__ __launch_bounds__(256) void glreduce_kernel(
    const float* __restrict__ glrow, float* __restrict__ gl)
{
  const int bn = blockIdx.y, dblk = blockIdx.x;
  const int d = dblk*64 + (threadIdx.x & 63), rg = threadIdx.x >> 6;
  float s = 0.f;
  for (int c = rg; c < KC; c += 4) s += glrow[(size_t)(bn*KC + c)*KD + d];
  __shared__ float L[4][64];
  L[rg][threadIdx.x & 63] = s;
  __syncthreads();
  if (rg == 0)
    gl[(size_t)bn*KD + d] = L[0][threadIdx.x]+L[1][threadIdx.x]+L[2][threadIdx.x]+L[3][threadIdx.x];
}

// ---------------- nln / nsl ------------------------------------------------
__global__ void glcomb_kernel(const float* __restrict__ gl, const float* __restrict__ lnw,
                              const float* __restrict__ cm, const float* __restrict__ cs,
                              const float* __restrict__ Pw,
                              float* __restrict__ nln, float* __restrict__ nsl)
{
  const int idx = blockIdx.x*256 + threadIdx.x;
  const int b = idx >> 10, d = idx & (KD-1);
  float am=0.f, as=0.f;
  for (int n=0;n<KN;n++){
    const float g = gl[(size_t)(b*KN+n)*KD + d];
    am += cm[b*KN+n]*g; as += cs[b*KN+n]*g;
  }
  nln[idx] = Pw[b]*lnw[d] + am;
  nsl[idx] = as;
}

// ---------------- final out (yq = yq0+yq1 split-K) -------------------------
__global__ __launch_bounds__(256) void final_out_kernel(
    const float* __restrict__ q, const float* __restrict__ yq0,
    const float* __restrict__ yq1, const float* __restrict__ nln,
    float* __restrict__ out)
{
  const int row = blockIdx.x * 4 + (threadIdx.x >> 6);
  const int lane = threadIdx.x & 63;
  const int b = row >> 10;
  float yv[16]; float ss = 0.f;
  #pragma unroll
  for (int l=0;l<16;l++){
    const int d = lane + (l<<6);
    yv[l] = yq0[(size_t)row*KD + d] + yq1[(size_t)row*KD + d];
    ss += yv[l]*yv[l];
  }
  #pragma unroll
  for (int o=32;o>0;o>>=1) ss += __shfl_xor(ss, o, 64);
  const float inv = rsqrtf(ss * (1.0f/KD) + KEPS);
  #pragma unroll
  for (int l=0;l<16;l++){
    const int d = lane + (l<<6);
    out[(size_t)row*KD + d] = q[(size_t)row*KD + d] + yv[l]*inv*nln[b*KD + d];
  }
}

extern "C" void kernel_launch(void* const* d_in, const int* in_sizes, int n_in,
                              void* d_out, int out_size, void* d_ws, size_t ws_size,
                              hipStream_t stream)
{
  const float* x    = (const float*)d_in[0];
  const float* w1   = (const float*)d_in[1];
  const float* w2   = (const float*)d_in[2];
  const float* lnw  = (const float*)d_in[3];
  const float* wq   = (const float*)d_in[4];
  const float* wk   = (const float*)d_in[5];
  const float* wv   = (const float*)d_in[6];
  const float* qnw  = (const float*)d_in[7];
  const float* knw  = (const float*)d_in[8];
  const float* aw   = (const float*)d_in[9];
  const float* tw   = (const float*)d_in[10];
  const float* ew   = (const float*)d_in[11];

  float* out = (float*)d_out;
  float* nw1 = out + (size_t)KB*KS*KD;
  float* nw2 = nw1 + (size_t)KB*KI*KD;
  float* nln = nw2 + (size_t)KB*KD*KI;
  float* ns1 = nln + (size_t)KB*KD;
  float* ns2 = ns1 + (size_t)KB*KI*KD;
  float* nsl = ns2 + (size_t)KB*KD*KI;

  float* ws = (float*)d_ws;
  size_t o = 0;
  float* kbuf = ws+o; o += 2097152;
  float* vbuf = ws+o; o += 2097152;
  float* qbuf = ws+o; o += 2097152;
  float* abuf = ws+o; o += 4194304;
  float* ybuf = ws+o; o += 2097152;   // y half 0; later yq half 0
  float* ybuf2= ws+o; o += 2097152;   // y half 1; later yq half 1
  float* glrow= ws+o; o += 2097152;
  float* gl   = ws+o; o += 32768;
  float* part = ws+o; o += 1536;
  float* cmb  = ws+o; o += 32;
  float* csb  = ws+o; o += 32;
  float* Pwb  = ws+o; o += 32;
  float* thetab = ws+o; o += 32;
  __bf16* bb = (__bf16*)(ws + o);
  size_t p = 0;
  __bf16* xb   = bb+p; p += 2097152;  // reused as gyT
  __bf16* wkb  = bb+p; p += 1048576;  // wkb+wvb reused as kT
  __bf16* wvb  = bb+p; p += 1048576;
  __bf16* wqb  = bb+p; p += 1048576;
  __bf16* w1b  = bb+p; p += 2097152;  // reused as gyb
  __bf16* w2b  = bb+p; p += 2097152;  // w2b+w2tb reused as gaT
  __bf16* w2tb = bb+p; p += 2097152;
  __bf16* kb16 = bb+p; p += 2097152;
  __bf16* qb16 = bb+p; p += 2097152;
  __bf16* hb16 = bb+p; p += 4194304;
  __bf16* gab  = bb+p; p += 4194304;  // reused as hq16
  __bf16* hT   = bb+p; p += 4194304;
  __bf16* nw1b = bb+p; p += 4194304;
  __bf16* nw2b = bb+p; p += 4194304;
  __bf16* gyT = xb;
  __bf16* kT  = wkb;
  __bf16* gyb = w1b;
  __bf16* gaT = w2b;
  __bf16* hq16= gab;

  dim3 blk(256);

  convert6_kernel<<<9216, blk, 0, stream>>>(x, wk, wv, wq, w1, w2, xb, wkb, wvb, wqb, w1b, w2b);
  tconv_kernel<1><<<dim3(32,16), blk, 0, stream>>>(w2, w2tb, 1024, 2048);
  gates_part_kernel<<<dim3(16,32), blk, 0, stream>>>(x, aw, tw, ew, part);
  scan_coef_kernel<<<1, 64, 0, stream>>>(part, cmb, csb, Pwb, thetab);

  // projections k/v/q = silu(x W^T), z selects weight/output
  mgemm2<1,1><<<dim3(16,16,3), blk, 0, stream>>>(xb, wkb, kbuf, nullptr, nullptr,
      wvb, wqb, vbuf, qbuf, 2048, 1024, 1024, 1024, 0);
  rmsfuse_kernel<<<dim3(512,2), blk, 0, stream>>>(kbuf, knw, kb16, qbuf, qnw, qb16);
  tconv_kernel<0><<<dim3(16,32), blk, 0, stream>>>(kb16, kT, 2048, 1024);

  // memory forward: a = k w1^T (fp32), h = silu(a) (bf16); y = h w2^T (split-K2)
  mgemm2<2,0><<<dim3(32,16,1), blk, 0, stream>>>(kb16, w1b, nullptr, hb16, abuf,
      nullptr, nullptr, nullptr, nullptr, 2048, 2048, 1024, 1024, 0);
  mgemm2<0,2><<<dim3(16,16,2), blk, 0, stream>>>(hb16, w2b, ybuf, nullptr, nullptr,
      nullptr, nullptr, nullptr, nullptr, 2048, 1024, 2048, 2048, 0);

  // backward
  rms_grad_kernel<<<512, blk, 0, stream>>>(ybuf, ybuf2, kbuf, vbuf, lnw, thetab, gyb, glrow);
  glreduce_kernel<<<dim3(16,32), blk, 0, stream>>>(glrow, gl);
  mgemm2<3,0><<<dim3(32,16,1), blk, 0, stream>>>(gyb, w2tb, nullptr, gab, abuf,
      nullptr, nullptr, nullptr, nullptr, 2048, 2048, 1024, 1024, 0);

  // transposes (bf16 -> bf16)
  tconv_kernel<0><<<dim3(32,32), blk, 0, stream>>>(hb16, hT, 2048, 2048);
  tconv_kernel<0><<<dim3(16,32), blk, 0, stream>>>(gyb, gyT, 2048, 1024);
  tconv_kernel<0><<<dim3(32,32), blk, 0, stream>>>(gab, gaT, 2048, 2048);

  // dual scan-weighted GEMMs
  wacc2k_kernel<<<dim3(16,16,2), blk, 0, stream>>>(gaT, kT, w1, cmb, csb, Pwb,
      nw1, nw1b, ns1, 2048, 1024, 2048, 2048);
  wacc2k_kernel<<<dim3(32,8,2), blk, 0, stream>>>(gyT, hT, w2, cmb, csb, Pwb,
      nw2, nw2b, ns2, 1024, 2048, 2048, 2048);
  glcomb_kernel<<<8, blk, 0, stream>>>(gl, lnw, cmb, csb, Pwb, nln, nsl);

  // retrieval with updated weights
  mgemm2<4,0><<<dim3(32,16,1), blk, 0, stream>>>(qb16, nw1b, nullptr, hq16, nullptr,
      nullptr, nullptr, nullptr, nullptr, 2048, 2048, 1024, 1024, (long)KI*KD);
  mgemm2<0,2><<<dim3(16,16,2), blk, 0, stream>>>(hq16, nw2b, ybuf, nullptr, nullptr,
      nullptr, nullptr, nullptr, nullptr, 2048, 1024, 2048, 2048, (long)KD*KI);
  final_out_kernel<<<512, blk, 0, stream>>>(qbuf, ybuf, ybuf2, nln, out);
}

// Round 5
// 230.120 us; speedup vs baseline: 7.5344x; 1.1225x over previous
//
#include <hip/hip_runtime.h>

#define KD 1024   // D
#define KI 2048   // I
#define KB 2      // B
#define KS 1024   // S
#define KC 64     // C
#define KN 16     // N chunks
#define KEPS 1e-6f

typedef __bf16 bf16x8 __attribute__((ext_vector_type(8)));
typedef __bf16 bf16x4 __attribute__((ext_vector_type(4)));
typedef float f32x4 __attribute__((ext_vector_type(4)));

__device__ __forceinline__ float sigf(float x){ return 1.0f/(1.0f+__expf(-x)); }
__device__ __forceinline__ float siluf(float x){ return x*sigf(x); }
__device__ __forceinline__ float dsiluf(float x){ float s=sigf(x); return s*(1.0f+x*(1.0f-s)); }

// width-16 global->LDS DMA; LDS dest is wave-uniform base + lane*16
__device__ __forceinline__ void gld16(const __bf16* g, __bf16* l) {
  __builtin_amdgcn_global_load_lds(
    (const __attribute__((address_space(1))) unsigned int*)g,
    (__attribute__((address_space(3))) unsigned int*)l, 16, 0, 0);
}

// ---------------- shared transpose body (64x64 tile via LDS) ---------------
template<int SRCF>
__device__ __forceinline__ void tconv_body(const void* in, __bf16* out,
                                           int R, int Cc, int bx, int by)
{
  __shared__ float T[64][65];
  const int r0 = by*64, c0 = bx*64;
  const int tx = threadIdx.x & 15, ty = threadIdx.x >> 4;
  #pragma unroll
  for (int i=0;i<4;i++){
    const int r = r0 + ty + i*16;
    if (SRCF) {
      const float4 v = *(const float4*)((const float*)in + (size_t)r*Cc + c0 + tx*4);
      T[ty+i*16][tx*4+0]=v.x; T[ty+i*16][tx*4+1]=v.y;
      T[ty+i*16][tx*4+2]=v.z; T[ty+i*16][tx*4+3]=v.w;
    } else {
      const bf16x4 v = *(const bf16x4*)((const __bf16*)in + (size_t)r*Cc + c0 + tx*4);
      T[ty+i*16][tx*4+0]=(float)v[0]; T[ty+i*16][tx*4+1]=(float)v[1];
      T[ty+i*16][tx*4+2]=(float)v[2]; T[ty+i*16][tx*4+3]=(float)v[3];
    }
  }
  __syncthreads();
  #pragma unroll
  for (int i=0;i<4;i++){
    bf16x4 o = { (__bf16)T[tx*4+0][ty+i*16], (__bf16)T[tx*4+1][ty+i*16],
                 (__bf16)T[tx*4+2][ty+i*16], (__bf16)T[tx*4+3][ty+i*16] };
    *(bf16x4*)(out + (size_t)(c0+ty+i*16)*R + r0 + tx*4) = o;
  }
}

// ---------------- prep: convert6 + gates partials + w2^T + zero gl ---------
__global__ __launch_bounds__(256) void prep_kernel(
  const float* __restrict__ x, const float* __restrict__ wk, const float* __restrict__ wv,
  const float* __restrict__ wq, const float* __restrict__ w1, const float* __restrict__ w2,
  const float* __restrict__ aw, const float* __restrict__ tw, const float* __restrict__ ew,
  __bf16* __restrict__ xb, __bf16* __restrict__ wkb, __bf16* __restrict__ wvb,
  __bf16* __restrict__ wqb, __bf16* __restrict__ w1b, __bf16* __restrict__ w2b,
  __bf16* __restrict__ w2tb, float* __restrict__ part, float* __restrict__ gl)
{
  const int g = blockIdx.x;
  if (g < 9216) {
    const long t = (long)g*256 + threadIdx.x;   // float4 index
    const float* s; __bf16* d; long i;
    if (t < 524288)       { s=x;  d=xb;  i=t; }
    else if (t < 786432)  { s=wk; d=wkb; i=t-524288; }
    else if (t < 1048576) { s=wv; d=wvb; i=t-786432; }
    else if (t < 1310720) { s=wq; d=wqb; i=t-1048576; }
    else if (t < 1835008) { s=w1; d=w1b; i=t-1310720; }
    else                  { s=w2; d=w2b; i=t-1835008; }
    const float4 v = *(const float4*)(s + i*4);
    bf16x4 o = { (__bf16)v.x, (__bf16)v.y, (__bf16)v.z, (__bf16)v.w };
    *(bf16x4*)(d + i*4) = o;
  } else if (g < 9728) {
    const int gg = g - 9216;
    const int seg = gg & 15, bn = gg >> 4;
    const int base = seg*4096;
    float da=0.f, dt=0.f, de=0.f;
    #pragma unroll
    for (int i=0;i<4;i++){
      const int off = base + i*1024 + threadIdx.x*4;
      const float4 xv = *(const float4*)(x + (size_t)bn*65536 + off);
      const float4 av = *(const float4*)(aw + off);
      const float4 tv = *(const float4*)(tw + off);
      const float4 ev = *(const float4*)(ew + off);
      da += xv.x*av.x + xv.y*av.y + xv.z*av.z + xv.w*av.w;
      dt += xv.x*tv.x + xv.y*tv.y + xv.z*tv.z + xv.w*tv.w;
      de += xv.x*ev.x + xv.y*ev.y + xv.z*ev.z + xv.w*ev.w;
    }
    __shared__ float sA[256], sT[256], sE[256];
    sA[threadIdx.x]=da; sT[threadIdx.x]=dt; sE[threadIdx.x]=de;
    __syncthreads();
    for (int s=128;s>0;s>>=1){
      if ((int)threadIdx.x < s){
        sA[threadIdx.x]+=sA[threadIdx.x+s];
        sT[threadIdx.x]+=sT[threadIdx.x+s];
        sE[threadIdx.x]+=sE[threadIdx.x+s];
      }
      __syncthreads();
    }
    if (threadIdx.x==0){
      part[0*512 + bn*16 + seg] = sA[0];
      part[1*512 + bn*16 + seg] = sT[0];
      part[2*512 + bn*16 + seg] = sE[0];
    }
  } else if (g < 10240) {
    const int gg = g - 9728;
    tconv_body<1>(w2, w2tb, 1024, 2048, gg & 31, gg >> 5);
  } else {
    const int gg = g - 10240;
    float4 z = {0.f,0.f,0.f,0.f};
    *(float4*)(gl + (size_t)gg*1024 + threadIdx.x*4) = z;
  }
}

// ---------------- scan coefficients (closed form) --------------------------
__global__ void scan_coef_kernel(const float* __restrict__ part,
                                 float* __restrict__ cm, float* __restrict__ cs,
                                 float* __restrict__ Pw, float* __restrict__ theta)
{
  const int b = threadIdx.x;
  if (b >= KB) return;
  float al[KN], et[KN];
  for (int n=0;n<KN;n++){
    float sa=0.f, st=0.f, se=0.f;
    for (int s=0;s<16;s++){
      sa += part[0*512 + (b*KN+n)*16 + s];
      st += part[1*512 + (b*KN+n)*16 + s];
      se += part[2*512 + (b*KN+n)*16 + s];
    }
    al[n] = sigf(sa);
    theta[b*KN+n] = sigf(st)*0.01f;
    et[n] = sigf(se);
  }
  float prodE = 1.f;
  for (int j=KN-1;j>=0;j--){ cs[b*KN+j] = -prodE; prodE *= et[j]; }
  float A[KN]; A[KN-1]=1.f;
  for (int t=KN-2;t>=0;t--) A[t] = A[t+1]*(1.f-al[t+1]);
  for (int j=0;j<KN;j++){
    float inner=0.f, E=1.f;
    for (int t=j;t<KN;t++){ inner += A[t]*E; if (t+1<KN) E *= et[t+1]; }
    cm[b*KN+j] = -inner;
  }
  float pw=1.f;
  for (int n=0;n<KN;n++) pw *= (1.f-al[n]);
  Pw[b]=pw;
}

// ---------------- MFMA bf16 GEMM, dbuf + prefetch-1: C = A*B^T -------------
// BM=128, BN=64, BK=64, K=1024 (16 steps). 4 waves, wave tile 64x32.
// MODE: 0 plain, 1 proj mux (z selects B), 2 k-split (z = K half)
// EPI: 0 F0[+z*M*N]=acc; 2 Oa=bf16(silu) & Ob=bf16(dsilu);
//      3 Oa=bf16(acc*(float)Aux); 4 Oa=bf16(silu);
//      5 proj: z0 F0=silu, z1 Oa=bf16(silu), z2 F1=silu
template<int EPI, int MODE>
__global__ __launch_bounds__(256) void mgemm2(
    const __bf16* __restrict__ A, const __bf16* __restrict__ B0,
    const __bf16* __restrict__ B1, const __bf16* __restrict__ B2,
    float* __restrict__ F0, float* __restrict__ F1,
    __bf16* __restrict__ Oa, __bf16* __restrict__ Ob, const __bf16* __restrict__ Aux,
    int M, int Nn, int lda, int ldb, long bstr)
{
  const int bz = blockIdx.z;
  const int n0 = blockIdx.x * 64;
  const int m0 = blockIdx.y * 128;
  const __bf16* Bp = B0;
  if (MODE==1) { if (bz==1) Bp=B1; else if (bz==2) Bp=B2; }
  float* F0p = F0;
  int koff0 = 0;
  if (MODE==2) { koff0 = bz << 10; F0p = F0 + (size_t)bz * M * Nn; }
  Bp += (size_t)(m0 >> 10) * (size_t)bstr;
  __shared__ __bf16 As[2*128*64];
  __shared__ __bf16 Bs[2*64*64];
  const int tid = threadIdx.x, wv = tid >> 6, lane = tid & 63;
  const int wm = (wv >> 1) << 6, wn = (wv & 1) << 5;
  const int fr = lane & 15, fg = lane >> 4;
  const int lr = lane >> 3, lc = lane & 7;
  const __bf16* asrc[4]; __bf16* adst[4];
  const __bf16* bsrc[2]; __bf16* bdst[2];
  #pragma unroll
  for (int i=0;i<4;i++){
    const int rowbase=(wv*4+i)*8, row=rowbase+lr;
    asrc[i] = A + (size_t)(m0+row)*lda + koff0 + ((lc^(row&7))<<3);
    adst[i] = As + rowbase*64;
  }
  #pragma unroll
  for (int i=0;i<2;i++){
    const int rowbase=(wv*2+i)*8, row=rowbase+lr;
    bsrc[i] = Bp + (size_t)(n0+row)*ldb + koff0 + ((lc^(row&7))<<3);
    bdst[i] = Bs + rowbase*64;
  }
  f32x4 acc[4][2] = {};
  #pragma unroll
  for (int i=0;i<4;i++) gld16(asrc[i], adst[i]);
  #pragma unroll
  for (int i=0;i<2;i++) gld16(bsrc[i], bdst[i]);
  __syncthreads();
  #pragma unroll 2
  for (int t=0;t<16;++t){
    const int p = t & 1;
    if (t < 15){
      const int ko = (t+1) << 6;
      const int q = p ^ 1;
      #pragma unroll
      for (int i=0;i<4;i++) gld16(asrc[i]+ko, adst[i]+q*8192);
      #pragma unroll
      for (int i=0;i<2;i++) gld16(bsrc[i]+ko, bdst[i]+q*4096);
    }
    #pragma unroll
    for (int ks=0;ks<2;++ks){
      bf16x8 af[4], bfv[2];
      #pragma unroll
      for (int mi=0;mi<4;++mi){
        const int r = wm + mi*16 + fr;
        af[mi] = *(const bf16x8*)(As + p*8192 + r*64 + ((((ks<<2)+fg)^(r&7))<<3));
      }
      #pragma unroll
      for (int ni=0;ni<2;++ni){
        const int r = wn + ni*16 + fr;
        bfv[ni] = *(const bf16x8*)(Bs + p*4096 + r*64 + ((((ks<<2)+fg)^(r&7))<<3));
      }
      #pragma unroll
      for (int mi=0;mi<4;++mi)
        #pragma unroll
        for (int ni=0;ni<2;++ni)
          acc[mi][ni] = __builtin_amdgcn_mfma_f32_16x16x32_bf16(af[mi], bfv[ni], acc[mi][ni], 0,0,0);
    }
    __syncthreads();
  }
  #pragma unroll
  for (int mi=0;mi<4;++mi){
    #pragma unroll
    for (int ni=0;ni<2;++ni){
      #pragma unroll
      for (int j=0;j<4;++j){
        const int m = m0 + wm + mi*16 + fg*4 + j;
        const int n = n0 + wn + ni*16 + fr;
        const size_t idx = (size_t)m * Nn + n;
        const float v = acc[mi][ni][j];
        if (EPI==0) F0p[idx] = v;
        else if (EPI==2) { Oa[idx] = (__bf16)siluf(v); Ob[idx] = (__bf16)dsiluf(v); }
        else if (EPI==3) Oa[idx] = (__bf16)(v * (float)Aux[idx]);
        else if (EPI==4) Oa[idx] = (__bf16)siluf(v);
        else if (EPI==5) {
          if (bz==0) F0[idx] = siluf(v);
          else if (bz==1) Oa[idx] = (__bf16)siluf(v);
          else F1[idx] = siluf(v);
        }
      }
    }
  }
}

// ---------------- dual scan-weighted GEMM, dbuf + prefetch-1 ---------------
__global__ __launch_bounds__(256) void wacc2k_kernel(
    const __bf16* __restrict__ A, const __bf16* __restrict__ B,
    const float* __restrict__ Winit,
    const float* __restrict__ cm, const float* __restrict__ cs,
    const float* __restrict__ Pw,
    float* __restrict__ outM, __bf16* __restrict__ outMb, float* __restrict__ outS,
    int M, int Nn, int lda, int ldb)
{
  const int bz = blockIdx.z;
  const int n0 = blockIdx.x * 64;
  const int m0 = blockIdx.y * 128;
  const int koff0 = bz << 10;
  __shared__ __bf16 As[2*128*64];
  __shared__ __bf16 Bs[2*64*64];
  const int tid = threadIdx.x, wv = tid >> 6, lane = tid & 63;
  const int wm = (wv >> 1) << 6, wn = (wv & 1) << 5;
  const int fr = lane & 15, fg = lane >> 4;
  const int lr = lane >> 3, lc = lane & 7;
  const __bf16* asrc[4]; __bf16* adst[4];
  const __bf16* bsrc[2]; __bf16* bdst[2];
  #pragma unroll
  for (int i=0;i<4;i++){
    const int rowbase=(wv*4+i)*8, row=rowbase+lr;
    asrc[i] = A + (size_t)(m0+row)*lda + koff0 + ((lc^(row&7))<<3);
    adst[i] = As + rowbase*64;
  }
  #pragma unroll
  for (int i=0;i<2;i++){
    const int rowbase=(wv*2+i)*8, row=rowbase+lr;
    bsrc[i] = B + (size_t)(n0+row)*ldb + koff0 + ((lc^(row&7))<<3);
    bdst[i] = Bs + rowbase*64;
  }
  f32x4 accM[4][2] = {}, accS[4][2] = {};
  #pragma unroll
  for (int i=0;i<4;i++) gld16(asrc[i], adst[i]);
  #pragma unroll
  for (int i=0;i<2;i++) gld16(bsrc[i], bdst[i]);
  __syncthreads();
  #pragma unroll 2
  for (int t=0;t<16;++t){
    const int p = t & 1;
    const float cmc = cm[bz*KN + t], csc = cs[bz*KN + t];
    if (t < 15){
      const int ko = (t+1) << 6;
      const int q = p ^ 1;
      #pragma unroll
      for (int i=0;i<4;i++) gld16(asrc[i]+ko, adst[i]+q*8192);
      #pragma unroll
      for (int i=0;i<2;i++) gld16(bsrc[i]+ko, bdst[i]+q*4096);
    }
    bf16x8 a0[4], a1[4], b0[2], b1[2];
    #pragma unroll
    for (int mi=0;mi<4;++mi){
      const int r = wm + mi*16 + fr;
      a0[mi] = *(const bf16x8*)(As + p*8192 + r*64 + (((0+fg)^(r&7))<<3));
      a1[mi] = *(const bf16x8*)(As + p*8192 + r*64 + (((4+fg)^(r&7))<<3));
    }
    #pragma unroll
    for (int ni=0;ni<2;++ni){
      const int r = wn + ni*16 + fr;
      b0[ni] = *(const bf16x8*)(Bs + p*4096 + r*64 + (((0+fg)^(r&7))<<3));
      b1[ni] = *(const bf16x8*)(Bs + p*4096 + r*64 + (((4+fg)^(r&7))<<3));
    }
    #pragma unroll
    for (int mi=0;mi<4;++mi){
      #pragma unroll
      for (int ni=0;ni<2;++ni){
        const f32x4 zf = {0.f,0.f,0.f,0.f};
        f32x4 P = __builtin_amdgcn_mfma_f32_16x16x32_bf16(a0[mi], b0[ni], zf, 0,0,0);
        P = __builtin_amdgcn_mfma_f32_16x16x32_bf16(a1[mi], b1[ni], P, 0,0,0);
        accM[mi][ni] += P * cmc;
        accS[mi][ni] += P * csc;
      }
    }
    __syncthreads();
  }
  const float pw = Pw[bz];
  #pragma unroll
  for (int mi=0;mi<4;++mi){
    #pragma unroll
    for (int ni=0;ni<2;++ni){
      #pragma unroll
      for (int j=0;j<4;++j){
        const int m = m0 + wm + mi*16 + fg*4 + j;
        const int n = n0 + wn + ni*16 + fr;
        const size_t widx = (size_t)m * Nn + n;
        const size_t oidx = (size_t)bz * M * Nn + widx;
        const float vm = pw * Winit[widx] + accM[mi][ni][j];
        outM[oidx] = vm;
        outMb[oidx] = (__bf16)vm;
        outS[oidx] = accS[mi][ni][j];
      }
    }
  }
}

// ---------------- fused RMSNorm for k and q (bf16 out only) ----------------
__global__ __launch_bounds__(256) void rmsfuse_kernel(
    const float* __restrict__ kv, const float* __restrict__ kw, __bf16* __restrict__ k16,
    const float* __restrict__ qv, const float* __restrict__ qw, __bf16* __restrict__ q16)
{
  const float* v; const float* w; __bf16* o16;
  if (blockIdx.y == 0){ v=kv; w=kw; o16=k16; } else { v=qv; w=qw; o16=q16; }
  const int row = blockIdx.x * 4 + (threadIdx.x >> 6);
  const int lane = threadIdx.x & 63;
  const float* p = v + (size_t)row * KD;
  __bf16* p16 = o16 + (size_t)row * KD;
  float vals[16]; float ss = 0.f;
  #pragma unroll
  for (int l=0;l<16;l++){ vals[l] = p[lane + (l<<6)]; ss += vals[l]*vals[l]; }
  #pragma unroll
  for (int o=32;o>0;o>>=1) ss += __shfl_xor(ss, o, 64);
  const float inv = rsqrtf(ss * (1.0f/KD) + KEPS);
  #pragma unroll
  for (int l=0;l<16;l++){
    const int d = lane + (l<<6);
    p16[d] = (__bf16)(vals[l]*inv*w[d]);
  }
}

// ---------------- per-row backward (y=y0+y1), gl via block atomics ---------
__global__ __launch_bounds__(256) void rms_grad_kernel(
    const float* __restrict__ y0, const float* __restrict__ y1,
    const __bf16* __restrict__ k16, const __bf16* __restrict__ v16,
    const float* __restrict__ lnw, const float* __restrict__ theta,
    __bf16* __restrict__ gy, float* __restrict__ gl)
{
  const int wv = threadIdx.x >> 6;
  const int row = blockIdx.x * 4 + wv;
  const int lane = threadIdx.x & 63;
  const int chunk = blockIdx.x >> 4;
  const float th2 = theta[chunk] * (2.0f / KD);
  const float* yr0 = y0 + (size_t)row * KD;
  const float* yr1 = y1 + (size_t)row * KD;
  const __bf16* kr = k16 + (size_t)row * KD;
  const __bf16* vr = v16 + (size_t)row * KD;
  float yv[16]; float ss = 0.f;
  #pragma unroll
  for (int l=0;l<16;l++){
    const int d = lane + (l<<6);
    yv[l] = yr0[d] + yr1[d]; ss += yv[l]*yv[l];
  }
  #pragma unroll
  for (int o=32;o>0;o>>=1) ss += __shfl_xor(ss, o, 64);
  const float inv = rsqrtf(ss * (1.0f/KD) + KEPS);
  float gzv[16]; float sdot = 0.f;
  #pragma unroll
  for (int l=0;l<16;l++){
    const int d = lane + (l<<6);
    const float gz = th2 * ((float)kr[d] + yv[l]*inv*lnw[d] - (float)vr[d]);
    gzv[l] = gz;
    sdot += gz * lnw[d] * yv[l];
  }
  #pragma unroll
  for (int o=32;o>0;o>>=1) sdot += __shfl_xor(sdot, o, 64);
  const float c3 = inv*inv*inv * (1.0f/KD) * sdot;
  __bf16* gyr = gy + (size_t)row * KD;
  __shared__ float L[4][KD];
  #pragma unroll
  for (int l=0;l<16;l++){
    const int d = lane + (l<<6);
    gyr[d] = (__bf16)(inv * lnw[d] * gzv[l] - c3 * yv[l]);
    L[wv][d] = gzv[l] * yv[l] * inv;
  }
  __syncthreads();
  if (wv == 0){
    float* glc = gl + (size_t)chunk * KD;
    #pragma unroll
    for (int l=0;l<16;l++){
      const int d = lane + (l<<6);
      atomicAdd(&glc[d], L[0][d]+L[1][d]+L[2][d]+L[3][d]);
    }
  }
}

// ---------------- merged transposes: kT, hT, gyT, gaT ----------------------
__global__ __launch_bounds__(256) void tconv4_kernel(
    const __bf16* __restrict__ kb16, __bf16* __restrict__ kT,
    const __bf16* __restrict__ hb16, __bf16* __restrict__ hT,
    const __bf16* __restrict__ gyb,  __bf16* __restrict__ gyT,
    const __bf16* __restrict__ gab,  __bf16* __restrict__ gaT)
{
  const int g = blockIdx.x;
  if (g < 512)        tconv_body<0>(kb16, kT, 2048, 1024, g & 15, g >> 4);
  else if (g < 1536){ const int t = g - 512;  tconv_body<0>(hb16, hT, 2048, 2048, t & 31, t >> 5); }
  else if (g < 2048){ const int t = g - 1536; tconv_body<0>(gyb, gyT, 2048, 1024, t & 15, t >> 4); }
  else              { const int t = g - 2048; tconv_body<0>(gab, gaT, 2048, 2048, t & 31, t >> 5); }
}

// ---------------- nln / nsl ------------------------------------------------
__global__ void glcomb_kernel(const float* __restrict__ gl, const float* __restrict__ lnw,
                              const float* __restrict__ cm, const float* __restrict__ cs,
                              const float* __restrict__ Pw,
                              float* __restrict__ nln, float* __restrict__ nsl)
{
  const int idx = blockIdx.x*256 + threadIdx.x;
  const int b = idx >> 10, d = idx & (KD-1);
  float am=0.f, as=0.f;
  for (int n=0;n<KN;n++){
    const float g = gl[(size_t)(b*KN+n)*KD + d];
    am += cm[b*KN+n]*g; as += cs[b*KN+n]*g;
  }
  nln[idx] = Pw[b]*lnw[d] + am;
  nsl[idx] = as;
}

// ---------------- final out (yq = yq0+yq1, q from bf16) --------------------
__global__ __launch_bounds__(256) void final_out_kernel(
    const __bf16* __restrict__ q16, const float* __restrict__ yq0,
    const float* __restrict__ yq1, const float* __restrict__ nln,
    float* __restrict__ out)
{
  const int row = blockIdx.x * 4 + (threadIdx.x >> 6);
  const int lane = threadIdx.x & 63;
  const int b = row >> 10;
  float yv[16]; float ss = 0.f;
  #pragma unroll
  for (int l=0;l<16;l++){
    const int d = lane + (l<<6);
    yv[l] = yq0[(size_t)row*KD + d] + yq1[(size_t)row*KD + d];
    ss += yv[l]*yv[l];
  }
  #pragma unroll
  for (int o=32;o>0;o>>=1) ss += __shfl_xor(ss, o, 64);
  const float inv = rsqrtf(ss * (1.0f/KD) + KEPS);
  #pragma unroll
  for (int l=0;l<16;l++){
    const int d = lane + (l<<6);
    out[(size_t)row*KD + d] = (float)q16[(size_t)row*KD + d] + yv[l]*inv*nln[b*KD + d];
  }
}

extern "C" void kernel_launch(void* const* d_in, const int* in_sizes, int n_in,
                              void* d_out, int out_size, void* d_ws, size_t ws_size,
                              hipStream_t stream)
{
  const float* x    = (const float*)d_in[0];
  const float* w1   = (const float*)d_in[1];
  const float* w2   = (const float*)d_in[2];
  const float* lnw  = (const float*)d_in[3];
  const float* wq   = (const float*)d_in[4];
  const float* wk   = (const float*)d_in[5];
  const float* wv   = (const float*)d_in[6];
  const float* qnw  = (const float*)d_in[7];
  const float* knw  = (const float*)d_in[8];
  const float* aw   = (const float*)d_in[9];
  const float* tw   = (const float*)d_in[10];
  const float* ew   = (const float*)d_in[11];

  float* out = (float*)d_out;
  float* nw1 = out + (size_t)KB*KS*KD;
  float* nw2 = nw1 + (size_t)KB*KI*KD;
  float* nln = nw2 + (size_t)KB*KD*KI;
  float* ns1 = nln + (size_t)KB*KD;
  float* ns2 = ns1 + (size_t)KB*KI*KD;
  float* nsl = ns2 + (size_t)KB*KD*KI;

  float* ws = (float*)d_ws;
  size_t o = 0;
  float* kbuf = ws+o; o += 2097152;   // fp32 silu(x wk^T) pre-rms
  float* qbuf = ws+o; o += 2097152;   // fp32 silu(x wq^T) pre-rms
  float* ybuf = ws+o; o += 2097152;   // y half 0; later yq half 0
  float* ybuf2= ws+o; o += 2097152;   // y half 1; later yq half 1
  float* gl   = ws+o; o += 32768;
  float* part = ws+o; o += 1536;
  float* cmb  = ws+o; o += 32;
  float* csb  = ws+o; o += 32;
  float* Pwb  = ws+o; o += 32;
  float* thetab = ws+o; o += 32;
  __bf16* bb = (__bf16*)(ws + o);
  size_t p = 0;
  __bf16* xb   = bb+p; p += 2097152;  // reused as gyT
  __bf16* wkb  = bb+p; p += 1048576;  // wkb+wvb reused as kT
  __bf16* wvb  = bb+p; p += 1048576;
  __bf16* wqb  = bb+p; p += 1048576;
  __bf16* w1b  = bb+p; p += 2097152;  // reused as gyb
  __bf16* w2b  = bb+p; p += 2097152;  // w2b+w2tb reused as gaT
  __bf16* w2tb = bb+p; p += 2097152;
  __bf16* kb16 = bb+p; p += 2097152;
  __bf16* qb16 = bb+p; p += 2097152;
  __bf16* vb16 = bb+p; p += 2097152;
  __bf16* hb16 = bb+p; p += 4194304;
  __bf16* db16 = bb+p; p += 4194304;  // dsilu(a) bf16
  __bf16* gab  = bb+p; p += 4194304;  // reused as hq16
  __bf16* hT   = bb+p; p += 4194304;
  __bf16* nw1b = bb+p; p += 4194304;
  __bf16* nw2b = bb+p; p += 4194304;
  __bf16* gyT = xb;
  __bf16* kT  = wkb;
  __bf16* gyb = w1b;
  __bf16* gaT = w2b;
  __bf16* hq16= gab;

  dim3 blk(256);

  // 1. prep: convert to bf16 + gate partials + w2^T + zero gl
  prep_kernel<<<10272, blk, 0, stream>>>(x, wk, wv, wq, w1, w2, aw, tw, ew,
      xb, wkb, wvb, wqb, w1b, w2b, w2tb, part, gl);
  // 2. scan coefficients
  scan_coef_kernel<<<1, 64, 0, stream>>>(part, cmb, csb, Pwb, thetab);

  // 3. projections: z0 k->fp32, z1 v->bf16, z2 q->fp32
  mgemm2<5,1><<<dim3(16,16,3), blk, 0, stream>>>(xb, wkb, wvb, wqb,
      kbuf, qbuf, vb16, nullptr, nullptr, 2048, 1024, 1024, 1024, 0);
  // 4. rms for k and q -> bf16
  rmsfuse_kernel<<<dim3(512,2), blk, 0, stream>>>(kbuf, knw, kb16, qbuf, qnw, qb16);

  // 5. a = k w1^T: h=silu bf16, d=dsilu bf16
  mgemm2<2,0><<<dim3(32,16,1), blk, 0, stream>>>(kb16, w1b, nullptr, nullptr,
      nullptr, nullptr, hb16, db16, nullptr, 2048, 2048, 1024, 1024, 0);
  // 6. y = h w2^T (split-K 2)
  mgemm2<0,2><<<dim3(16,16,2), blk, 0, stream>>>(hb16, w2b, nullptr, nullptr,
      ybuf, nullptr, nullptr, nullptr, nullptr, 2048, 1024, 2048, 2048, 0);
  // 7. backward through rms+MSE (gl via atomics)
  rms_grad_kernel<<<512, blk, 0, stream>>>(ybuf, ybuf2, kb16, vb16, lnw, thetab, gyb, gl);
  // 8. ga = (gy w2tb^T) * dsilu
  mgemm2<3,0><<<dim3(32,16,1), blk, 0, stream>>>(gyb, w2tb, nullptr, nullptr,
      nullptr, nullptr, gab, nullptr, db16, 2048, 2048, 1024, 1024, 0);
  // 9. all transposes in one launch
  tconv4_kernel<<<3072, blk, 0, stream>>>(kb16, kT, hb16, hT, gyb, gyT, gab, gaT);

  // 10/11. dual scan-weighted GEMMs
  wacc2k_kernel<<<dim3(16,16,2), blk, 0, stream>>>(gaT, kT, w1, cmb, csb, Pwb,
      nw1, nw1b, ns1, 2048, 1024, 2048, 2048);
  wacc2k_kernel<<<dim3(32,8,2), blk, 0, stream>>>(gyT, hT, w2, cmb, csb, Pwb,
      nw2, nw2b, ns2, 1024, 2048, 2048, 2048);
  // 12. nln / nsl
  glcomb_kernel<<<8, blk, 0, stream>>>(gl, lnw, cmb, csb, Pwb, nln, nsl);

  // 13. hq = silu(q nw1^T) bf16
  mgemm2<4,0><<<dim3(32,16,1), blk, 0, stream>>>(qb16, nw1b, nullptr, nullptr,
      nullptr, nullptr, hq16, nullptr, nullptr, 2048, 2048, 1024, 1024, (long)KI*KD);
  // 14. yq = hq nw2^T (split-K 2)
  mgemm2<0,2><<<dim3(16,16,2), blk, 0, stream>>>(hq16, nw2b, nullptr, nullptr,
      ybuf, nullptr, nullptr, nullptr, nullptr, 2048, 1024, 2048, 2048, (long)KD*KI);
  // 15. out = q + rms(yq)*nln
  final_out_kernel<<<512, blk, 0, stream>>>(qb16, ybuf, ybuf2, nln, out);
}

// Round 6
// 211.417 us; speedup vs baseline: 8.2009x; 1.0885x over previous
//
#include <hip/hip_runtime.h>

#define KD 1024   // D
#define KI 2048   // I
#define KB 2      // B
#define KS 1024   // S
#define KC 64     // C
#define KN 16     // N chunks
#define KEPS 1e-6f

typedef __bf16 bf16x8 __attribute__((ext_vector_type(8)));
typedef __bf16 bf16x4 __attribute__((ext_vector_type(4)));
typedef float f32x4 __attribute__((ext_vector_type(4)));

__device__ __forceinline__ float sigf(float x){ return 1.0f/(1.0f+__expf(-x)); }
__device__ __forceinline__ float siluf(float x){ return x*sigf(x); }
__device__ __forceinline__ float dsiluf(float x){ float s=sigf(x); return s*(1.0f+x*(1.0f-s)); }

// width-16 global->LDS DMA; LDS dest is wave-uniform base + lane*16
__device__ __forceinline__ void gld16(const __bf16* g, __bf16* l) {
  __builtin_amdgcn_global_load_lds(
    (const __attribute__((address_space(1))) unsigned int*)g,
    (__attribute__((address_space(3))) unsigned int*)l, 16, 0, 0);
}

// ---------------- shared transpose body (64x64 tile via LDS) ---------------
template<int SRCF>
__device__ __forceinline__ void tconv_body(const void* in, __bf16* out,
                                           int R, int Cc, int bx, int by)
{
  __shared__ float T[64][65];
  const int r0 = by*64, c0 = bx*64;
  const int tx = threadIdx.x & 15, ty = threadIdx.x >> 4;
  #pragma unroll
  for (int i=0;i<4;i++){
    const int r = r0 + ty + i*16;
    if (SRCF) {
      const float4 v = *(const float4*)((const float*)in + (size_t)r*Cc + c0 + tx*4);
      T[ty+i*16][tx*4+0]=v.x; T[ty+i*16][tx*4+1]=v.y;
      T[ty+i*16][tx*4+2]=v.z; T[ty+i*16][tx*4+3]=v.w;
    } else {
      const bf16x4 v = *(const bf16x4*)((const __bf16*)in + (size_t)r*Cc + c0 + tx*4);
      T[ty+i*16][tx*4+0]=(float)v[0]; T[ty+i*16][tx*4+1]=(float)v[1];
      T[ty+i*16][tx*4+2]=(float)v[2]; T[ty+i*16][tx*4+3]=(float)v[3];
    }
  }
  __syncthreads();
  #pragma unroll
  for (int i=0;i<4;i++){
    bf16x4 o = { (__bf16)T[tx*4+0][ty+i*16], (__bf16)T[tx*4+1][ty+i*16],
                 (__bf16)T[tx*4+2][ty+i*16], (__bf16)T[tx*4+3][ty+i*16] };
    *(bf16x4*)(out + (size_t)(c0+ty+i*16)*R + r0 + tx*4) = o;
  }
}

// ---------------- prep: convert (x-blocks also gate partials) + w2^T + gl=0
__global__ __launch_bounds__(256) void prep_kernel(
  const float* __restrict__ x, const float* __restrict__ wk, const float* __restrict__ wv,
  const float* __restrict__ wq, const float* __restrict__ w1, const float* __restrict__ w2,
  const float* __restrict__ aw, const float* __restrict__ tw, const float* __restrict__ ew,
  __bf16* __restrict__ xb, __bf16* __restrict__ wkb, __bf16* __restrict__ wvb,
  __bf16* __restrict__ wqb, __bf16* __restrict__ w1b, __bf16* __restrict__ w2b,
  __bf16* __restrict__ w2tb, float* __restrict__ part, float* __restrict__ gl)
{
  const int g = blockIdx.x;
  if (g < 2048) {
    // x convert + gate partial dots (one float4 per thread)
    const int i = g*256 + threadIdx.x;          // float4 index into x
    const float4 xv = *(const float4*)(x + (size_t)i*4);
    bf16x4 o = { (__bf16)xv.x, (__bf16)xv.y, (__bf16)xv.z, (__bf16)xv.w };
    *(bf16x4*)(xb + (size_t)i*4) = o;
    const size_t co = (size_t)(i & 16383) * 4;  // chunk-local element offset
    const float4 av = *(const float4*)(aw + co);
    const float4 tv = *(const float4*)(tw + co);
    const float4 ev = *(const float4*)(ew + co);
    float da = xv.x*av.x + xv.y*av.y + xv.z*av.z + xv.w*av.w;
    float dt = xv.x*tv.x + xv.y*tv.y + xv.z*tv.z + xv.w*tv.w;
    float de = xv.x*ev.x + xv.y*ev.y + xv.z*ev.z + xv.w*ev.w;
    __shared__ float sA[256], sT[256], sE[256];
    sA[threadIdx.x]=da; sT[threadIdx.x]=dt; sE[threadIdx.x]=de;
    __syncthreads();
    for (int s=128;s>0;s>>=1){
      if ((int)threadIdx.x < s){
        sA[threadIdx.x]+=sA[threadIdx.x+s];
        sT[threadIdx.x]+=sT[threadIdx.x+s];
        sE[threadIdx.x]+=sE[threadIdx.x+s];
      }
      __syncthreads();
    }
    if (threadIdx.x==0){
      part[g] = sA[0]; part[2048+g] = sT[0]; part[4096+g] = sE[0];
    }
  } else if (g < 9216) {
    const long t = (long)g*256 + threadIdx.x;   // float4 index
    const float* s; __bf16* d; long i;
    if (t < 786432)       { s=wk; d=wkb; i=t-524288; }
    else if (t < 1048576) { s=wv; d=wvb; i=t-786432; }
    else if (t < 1310720) { s=wq; d=wqb; i=t-1048576; }
    else if (t < 1835008) { s=w1; d=w1b; i=t-1310720; }
    else                  { s=w2; d=w2b; i=t-1835008; }
    const float4 v = *(const float4*)(s + i*4);
    bf16x4 o = { (__bf16)v.x, (__bf16)v.y, (__bf16)v.z, (__bf16)v.w };
    *(bf16x4*)(d + i*4) = o;
  } else if (g < 9728) {
    const int gg = g - 9216;
    tconv_body<1>(w2, w2tb, 1024, 2048, gg & 31, gg >> 5);
  } else {
    const int gg = g - 9728;                    // 32 blocks zero gl
    float4 z = {0.f,0.f,0.f,0.f};
    *(float4*)(gl + (size_t)gg*1024 + threadIdx.x*4) = z;
  }
}

// ---------------- MFMA bf16 GEMM, dbuf + prefetch-1: C = A*B^T -------------
// BM=128, BN=64, BK=64, K=1024 (16 steps). 4 waves, wave tile 64x32.
// MODE: 0 plain, 1 proj mux (z selects B), 2 k-split (z = K half)
// EPI: 0 F0=acc; 2 Oa=silu & Ob=dsilu (+WT: OT=silu^T);
//      3 (WT) OT=(acc*Aux)^T only; 4 Oa=silu; 5 proj mux; 6 Oa[z*M*N]=bf16(acc)
// WT: epilogue LDS re-transpose writes OT[n0+n][m0+m], leading dim ldt.
template<int EPI, int MODE, int WT>
__global__ __launch_bounds__(256) void mgemm2(
    const __bf16* __restrict__ A, const __bf16* __restrict__ B0,
    const __bf16* __restrict__ B1, const __bf16* __restrict__ B2,
    float* __restrict__ F0, float* __restrict__ F1,
    __bf16* __restrict__ Oa, __bf16* __restrict__ Ob, const __bf16* __restrict__ Aux,
    __bf16* __restrict__ OT, int ldt,
    int M, int Nn, int lda, int ldb, long bstr)
{
  const int bz = blockIdx.z;
  const int n0 = blockIdx.x * 64;
  const int m0 = blockIdx.y * 128;
  const __bf16* Bp = B0;
  if (MODE==1) { if (bz==1) Bp=B1; else if (bz==2) Bp=B2; }
  float* F0p = F0;
  int koff0 = 0;
  if (MODE==2) { koff0 = bz << 10; }
  Bp += (size_t)(m0 >> 10) * (size_t)bstr;
  __shared__ __bf16 As[2*128*64];
  __shared__ __bf16 Bs[2*64*64];
  const int tid = threadIdx.x, wv = tid >> 6, lane = tid & 63;
  const int wm = (wv >> 1) << 6, wn = (wv & 1) << 5;
  const int fr = lane & 15, fg = lane >> 4;
  const int lr = lane >> 3, lc = lane & 7;
  const __bf16* asrc[4]; __bf16* adst[4];
  const __bf16* bsrc[2]; __bf16* bdst[2];
  #pragma unroll
  for (int i=0;i<4;i++){
    const int rowbase=(wv*4+i)*8, row=rowbase+lr;
    asrc[i] = A + (size_t)(m0+row)*lda + koff0 + ((lc^(row&7))<<3);
    adst[i] = As + rowbase*64;
  }
  #pragma unroll
  for (int i=0;i<2;i++){
    const int rowbase=(wv*2+i)*8, row=rowbase+lr;
    bsrc[i] = Bp + (size_t)(n0+row)*ldb + koff0 + ((lc^(row&7))<<3);
    bdst[i] = Bs + rowbase*64;
  }
  f32x4 acc[4][2] = {};
  #pragma unroll
  for (int i=0;i<4;i++) gld16(asrc[i], adst[i]);
  #pragma unroll
  for (int i=0;i<2;i++) gld16(bsrc[i], bdst[i]);
  __syncthreads();
  #pragma unroll 2
  for (int t=0;t<16;++t){
    const int p = t & 1;
    if (t < 15){
      const int ko = (t+1) << 6;
      const int q = p ^ 1;
      #pragma unroll
      for (int i=0;i<4;i++) gld16(asrc[i]+ko, adst[i]+q*8192);
      #pragma unroll
      for (int i=0;i<2;i++) gld16(bsrc[i]+ko, bdst[i]+q*4096);
    }
    #pragma unroll
    for (int ks=0;ks<2;++ks){
      bf16x8 af[4], bfv[2];
      #pragma unroll
      for (int mi=0;mi<4;++mi){
        const int r = wm + mi*16 + fr;
        af[mi] = *(const bf16x8*)(As + p*8192 + r*64 + ((((ks<<2)+fg)^(r&7))<<3));
      }
      #pragma unroll
      for (int ni=0;ni<2;++ni){
        const int r = wn + ni*16 + fr;
        bfv[ni] = *(const bf16x8*)(Bs + p*4096 + r*64 + ((((ks<<2)+fg)^(r&7))<<3));
      }
      #pragma unroll
      for (int mi=0;mi<4;++mi)
        #pragma unroll
        for (int ni=0;ni<2;++ni)
          acc[mi][ni] = __builtin_amdgcn_mfma_f32_16x16x32_bf16(af[mi], bfv[ni], acc[mi][ni], 0,0,0);
    }
    __syncthreads();
  }
  __bf16* T = As;   // reuse staging LDS for transpose epilogue
  #pragma unroll
  for (int mi=0;mi<4;++mi){
    #pragma unroll
    for (int ni=0;ni<2;++ni){
      bf16x4 tv;
      #pragma unroll
      for (int j=0;j<4;++j){
        const int m = m0 + wm + mi*16 + fg*4 + j;
        const int n = n0 + wn + ni*16 + fr;
        const size_t idx = (size_t)m * Nn + n;
        const float v = acc[mi][ni][j];
        float tval = 0.f;
        if (EPI==0) F0p[idx] = v;
        else if (EPI==2) { const float sv = siluf(v); Oa[idx]=(__bf16)sv; Ob[idx]=(__bf16)dsiluf(v); tval=sv; }
        else if (EPI==3) tval = v * (float)Aux[idx];
        else if (EPI==4) Oa[idx] = (__bf16)siluf(v);
        else if (EPI==5) {
          if (bz==0) F0[idx] = siluf(v);
          else if (bz==1) Oa[idx] = (__bf16)siluf(v);
          else F1[idx] = siluf(v);
        }
        else if (EPI==6) Oa[(size_t)bz*M*Nn + idx] = (__bf16)v;
        if (WT) tv[j] = (__bf16)tval;
      }
      if (WT){
        const int nl = wn + ni*16 + fr;
        const int ml = wm + mi*16 + fg*4;
        *(bf16x4*)(T + nl*128 + (ml ^ ((nl&7)<<3))) = tv;
      }
    }
  }
  if (WT){
    __syncthreads();
    const int tn = tid >> 2, tc = tid & 3;
    #pragma unroll
    for (int u=0;u<4;++u){
      const int m8 = tc*32 + u*8;
      const bf16x8 v = *(const bf16x8*)(T + tn*128 + (m8 ^ ((tn&7)<<3)));
      *(bf16x8*)(OT + (size_t)(n0+tn)*ldt + m0 + m8) = v;
    }
  }
}

// ---------------- dual scan-weighted GEMM body -----------------------------
__device__ __forceinline__ void wacc_body(
    __bf16* As, __bf16* Bs,
    const __bf16* __restrict__ A, const __bf16* __restrict__ B,
    const float* __restrict__ Winit,
    const float* __restrict__ cm, const float* __restrict__ cs,
    const float* __restrict__ Pw,
    float* __restrict__ outM, __bf16* __restrict__ outMb, float* __restrict__ outS,
    int M, int Nn, int lda, int ldb, int n0, int m0, int bz)
{
  const int koff0 = bz << 10;
  const int tid = threadIdx.x, wv = tid >> 6, lane = tid & 63;
  const int wm = (wv >> 1) << 6, wn = (wv & 1) << 5;
  const int fr = lane & 15, fg = lane >> 4;
  const int lr = lane >> 3, lc = lane & 7;
  const __bf16* asrc[4]; __bf16* adst[4];
  const __bf16* bsrc[2]; __bf16* bdst[2];
  #pragma unroll
  for (int i=0;i<4;i++){
    const int rowbase=(wv*4+i)*8, row=rowbase+lr;
    asrc[i] = A + (size_t)(m0+row)*lda + koff0 + ((lc^(row&7))<<3);
    adst[i] = As + rowbase*64;
  }
  #pragma unroll
  for (int i=0;i<2;i++){
    const int rowbase=(wv*2+i)*8, row=rowbase+lr;
    bsrc[i] = B + (size_t)(n0+row)*ldb + koff0 + ((lc^(row&7))<<3);
    bdst[i] = Bs + rowbase*64;
  }
  f32x4 accM[4][2] = {}, accS[4][2] = {};
  #pragma unroll
  for (int i=0;i<4;i++) gld16(asrc[i], adst[i]);
  #pragma unroll
  for (int i=0;i<2;i++) gld16(bsrc[i], bdst[i]);
  __syncthreads();
  #pragma unroll 2
  for (int t=0;t<16;++t){
    const int p = t & 1;
    const float cmc = cm[bz*KN + t], csc = cs[bz*KN + t];
    if (t < 15){
      const int ko = (t+1) << 6;
      const int q = p ^ 1;
      #pragma unroll
      for (int i=0;i<4;i++) gld16(asrc[i]+ko, adst[i]+q*8192);
      #pragma unroll
      for (int i=0;i<2;i++) gld16(bsrc[i]+ko, bdst[i]+q*4096);
    }
    bf16x8 a0[4], a1[4], b0[2], b1[2];
    #pragma unroll
    for (int mi=0;mi<4;++mi){
      const int r = wm + mi*16 + fr;
      a0[mi] = *(const bf16x8*)(As + p*8192 + r*64 + (((0+fg)^(r&7))<<3));
      a1[mi] = *(const bf16x8*)(As + p*8192 + r*64 + (((4+fg)^(r&7))<<3));
    }
    #pragma unroll
    for (int ni=0;ni<2;++ni){
      const int r = wn + ni*16 + fr;
      b0[ni] = *(const bf16x8*)(Bs + p*4096 + r*64 + (((0+fg)^(r&7))<<3));
      b1[ni] = *(const bf16x8*)(Bs + p*4096 + r*64 + (((4+fg)^(r&7))<<3));
    }
    #pragma unroll
    for (int mi=0;mi<4;++mi){
      #pragma unroll
      for (int ni=0;ni<2;++ni){
        const f32x4 zf = {0.f,0.f,0.f,0.f};
        f32x4 P = __builtin_amdgcn_mfma_f32_16x16x32_bf16(a0[mi], b0[ni], zf, 0,0,0);
        P = __builtin_amdgcn_mfma_f32_16x16x32_bf16(a1[mi], b1[ni], P, 0,0,0);
        accM[mi][ni] += P * cmc;
        accS[mi][ni] += P * csc;
      }
    }
    __syncthreads();
  }
  const float pw = Pw[bz];
  #pragma unroll
  for (int mi=0;mi<4;++mi){
    #pragma unroll
    for (int ni=0;ni<2;++ni){
      #pragma unroll
      for (int j=0;j<4;++j){
        const int m = m0 + wm + mi*16 + fg*4 + j;
        const int n = n0 + wn + ni*16 + fr;
        const size_t widx = (size_t)m * Nn + n;
        const size_t oidx = (size_t)bz * M * Nn + widx;
        const float vm = pw * Winit[widx] + accM[mi][ni][j];
        outM[oidx] = vm;
        outMb[oidx] = (__bf16)vm;
        outS[oidx] = accS[mi][ni][j];
      }
    }
  }
}

// ---------------- merged wacc1 + wacc2 + glcomb ----------------------------
__global__ __launch_bounds__(256) void waccall_kernel(
    const __bf16* __restrict__ gaT, const __bf16* __restrict__ kT, const float* __restrict__ w1,
    const __bf16* __restrict__ gyT, const __bf16* __restrict__ hT, const float* __restrict__ w2,
    const float* __restrict__ gl, const float* __restrict__ lnw,
    const float* __restrict__ cm, const float* __restrict__ cs, const float* __restrict__ Pw,
    float* __restrict__ nw1, __bf16* __restrict__ nw1b, float* __restrict__ ns1,
    float* __restrict__ nw2, __bf16* __restrict__ nw2b, float* __restrict__ ns2,
    float* __restrict__ nln, float* __restrict__ nsl)
{
  __shared__ __bf16 As[2*128*64];
  __shared__ __bf16 Bs[2*64*64];
  const int g = blockIdx.x;
  if (g < 512){
    const int bz = g >> 8, rem = g & 255;
    wacc_body(As, Bs, gaT, kT, w1, cm, cs, Pw, nw1, nw1b, ns1,
              2048, 1024, 2048, 2048, (rem & 15)*64, (rem >> 4)*128, bz);
  } else if (g < 1024){
    const int t = g - 512;
    const int bz = t >> 8, rem = t & 255;
    wacc_body(As, Bs, gyT, hT, w2, cm, cs, Pw, nw2, nw2b, ns2,
              1024, 2048, 2048, 2048, (rem & 31)*64, (rem >> 5)*128, bz);
  } else {
    const int idx = (g - 1024)*256 + threadIdx.x;
    const int b = idx >> 10, d = idx & (KD-1);
    float am=0.f, as=0.f;
    for (int n=0;n<KN;n++){
      const float gv = gl[(size_t)(b*KN+n)*KD + d];
      am += cm[b*KN+n]*gv; as += cs[b*KN+n]*gv;
    }
    nln[idx] = Pw[b]*lnw[d] + am;
    nsl[idx] = as;
  }
}

// ---------------- rmsnorm for k,q (+ scan coefficients at y==2) ------------
__global__ __launch_bounds__(256) void rmsfuse_kernel(
    const float* __restrict__ kv, const float* __restrict__ kw, __bf16* __restrict__ k16,
    const float* __restrict__ qv, const float* __restrict__ qw, __bf16* __restrict__ q16,
    const float* __restrict__ part, float* __restrict__ cm, float* __restrict__ cs,
    float* __restrict__ Pw, float* __restrict__ theta)
{
  if (blockIdx.y == 2){
    if (blockIdx.x != 0) return;
    __shared__ float P[32][8][3];
    const int bn = threadIdx.x >> 3, sg = threadIdx.x & 7;
    float s0=0.f, s1=0.f, s2=0.f;
    #pragma unroll
    for (int u=0;u<8;u++){
      const int seg = bn*64 + sg*8 + u;
      s0 += part[seg]; s1 += part[2048+seg]; s2 += part[4096+seg];
    }
    P[bn][sg][0]=s0; P[bn][sg][1]=s1; P[bn][sg][2]=s2;
    __syncthreads();
    if ((int)threadIdx.x < KB){
      const int b = threadIdx.x;
      float al[KN], et[KN];
      for (int n=0;n<KN;n++){
        const int c = b*KN+n;
        float sa=0.f, st=0.f, se=0.f;
        #pragma unroll
        for (int k=0;k<8;k++){ sa+=P[c][k][0]; st+=P[c][k][1]; se+=P[c][k][2]; }
        al[n]=sigf(sa); theta[c]=sigf(st)*0.01f; et[n]=sigf(se);
      }
      float prodE = 1.f;
      for (int j=KN-1;j>=0;j--){ cs[b*KN+j] = -prodE; prodE *= et[j]; }
      float Ac[KN]; Ac[KN-1]=1.f;
      for (int t=KN-2;t>=0;t--) Ac[t] = Ac[t+1]*(1.f-al[t+1]);
      for (int j=0;j<KN;j++){
        float inner=0.f, E=1.f;
        for (int t=j;t<KN;t++){ inner += Ac[t]*E; if (t+1<KN) E *= et[t+1]; }
        cm[b*KN+j] = -inner;
      }
      float pw=1.f;
      for (int n=0;n<KN;n++) pw *= (1.f-al[n]);
      Pw[b]=pw;
    }
    return;
  }
  const float* v; const float* w; __bf16* o16;
  if (blockIdx.y == 0){ v=kv; w=kw; o16=k16; } else { v=qv; w=qw; o16=q16; }
  const int row = blockIdx.x * 4 + (threadIdx.x >> 6);
  const int lane = threadIdx.x & 63;
  const float* p = v + (size_t)row * KD;
  __bf16* p16 = o16 + (size_t)row * KD;
  float vals[16]; float ss = 0.f;
  #pragma unroll
  for (int l=0;l<16;l++){ vals[l] = p[lane + (l<<6)]; ss += vals[l]*vals[l]; }
  #pragma unroll
  for (int o=32;o>0;o>>=1) ss += __shfl_xor(ss, o, 64);
  const float inv = rsqrtf(ss * (1.0f/KD) + KEPS);
  #pragma unroll
  for (int l=0;l<16;l++){
    const int d = lane + (l<<6);
    p16[d] = (__bf16)(vals[l]*inv*w[d]);
  }
}

// ---------------- per-row backward (y = bf16 halves), gl via atomics -------
__global__ __launch_bounds__(256) void rms_grad_kernel(
    const __bf16* __restrict__ y16,
    const __bf16* __restrict__ k16, const __bf16* __restrict__ v16,
    const float* __restrict__ lnw, const float* __restrict__ theta,
    __bf16* __restrict__ gy, float* __restrict__ gl)
{
  const int wv = threadIdx.x >> 6;
  const int row = blockIdx.x * 4 + wv;
  const int lane = threadIdx.x & 63;
  const int chunk = blockIdx.x >> 4;
  const float th2 = theta[chunk] * (2.0f / KD);
  const __bf16* yr0 = y16 + (size_t)row * KD;
  const __bf16* yr1 = y16 + 2097152 + (size_t)row * KD;
  const __bf16* kr = k16 + (size_t)row * KD;
  const __bf16* vr = v16 + (size_t)row * KD;
  float yv[16]; float ss = 0.f;
  #pragma unroll
  for (int l=0;l<16;l++){
    const int d = lane + (l<<6);
    yv[l] = (float)yr0[d] + (float)yr1[d]; ss += yv[l]*yv[l];
  }
  #pragma unroll
  for (int o=32;o>0;o>>=1) ss += __shfl_xor(ss, o, 64);
  const float inv = rsqrtf(ss * (1.0f/KD) + KEPS);
  float gzv[16]; float sdot = 0.f;
  #pragma unroll
  for (int l=0;l<16;l++){
    const int d = lane + (l<<6);
    const float gz = th2 * ((float)kr[d] + yv[l]*inv*lnw[d] - (float)vr[d]);
    gzv[l] = gz;
    sdot += gz * lnw[d] * yv[l];
  }
  #pragma unroll
  for (int o=32;o>0;o>>=1) sdot += __shfl_xor(sdot, o, 64);
  const float c3 = inv*inv*inv * (1.0f/KD) * sdot;
  __bf16* gyr = gy + (size_t)row * KD;
  __shared__ float L[4][KD];
  #pragma unroll
  for (int l=0;l<16;l++){
    const int d = lane + (l<<6);
    gyr[d] = (__bf16)(inv * lnw[d] * gzv[l] - c3 * yv[l]);
    L[wv][d] = gzv[l] * yv[l] * inv;
  }
  __syncthreads();
  if (wv == 0){
    float* glc = gl + (size_t)chunk * KD;
    #pragma unroll
    for (int l=0;l<16;l++){
      const int d = lane + (l<<6);
      atomicAdd(&glc[d], L[0][d]+L[1][d]+L[2][d]+L[3][d]);
    }
  }
}

// ---------------- remaining transposes: kT + gyT ---------------------------
__global__ __launch_bounds__(256) void tconv2_kernel(
    const __bf16* __restrict__ kb16, __bf16* __restrict__ kT,
    const __bf16* __restrict__ gyb,  __bf16* __restrict__ gyT)
{
  const int g = blockIdx.x;
  if (g < 512)  tconv_body<0>(kb16, kT, 2048, 1024, g & 15, g >> 4);
  else        { const int t = g - 512; tconv_body<0>(gyb, gyT, 2048, 1024, t & 15, t >> 4); }
}

// ---------------- final out (yq = bf16 halves, q from bf16) ----------------
__global__ __launch_bounds__(256) void final_out_kernel(
    const __bf16* __restrict__ q16, const __bf16* __restrict__ yq16,
    const float* __restrict__ nln, float* __restrict__ out)
{
  const int row = blockIdx.x * 4 + (threadIdx.x >> 6);
  const int lane = threadIdx.x & 63;
  const int b = row >> 10;
  float yv[16]; float ss = 0.f;
  #pragma unroll
  for (int l=0;l<16;l++){
    const int d = lane + (l<<6);
    yv[l] = (float)yq16[(size_t)row*KD + d] + (float)yq16[2097152 + (size_t)row*KD + d];
    ss += yv[l]*yv[l];
  }
  #pragma unroll
  for (int o=32;o>0;o>>=1) ss += __shfl_xor(ss, o, 64);
  const float inv = rsqrtf(ss * (1.0f/KD) + KEPS);
  #pragma unroll
  for (int l=0;l<16;l++){
    const int d = lane + (l<<6);
    out[(size_t)row*KD + d] = (float)q16[(size_t)row*KD + d] + yv[l]*inv*nln[b*KD + d];
  }
}

extern "C" void kernel_launch(void* const* d_in, const int* in_sizes, int n_in,
                              void* d_out, int out_size, void* d_ws, size_t ws_size,
                              hipStream_t stream)
{
  const float* x    = (const float*)d_in[0];
  const float* w1   = (const float*)d_in[1];
  const float* w2   = (const float*)d_in[2];
  const float* lnw  = (const float*)d_in[3];
  const float* wq   = (const float*)d_in[4];
  const float* wk   = (const float*)d_in[5];
  const float* wv   = (const float*)d_in[6];
  const float* qnw  = (const float*)d_in[7];
  const float* knw  = (const float*)d_in[8];
  const float* aw   = (const float*)d_in[9];
  const float* tw   = (const float*)d_in[10];
  const float* ew   = (const float*)d_in[11];

  float* out = (float*)d_out;
  float* nw1 = out + (size_t)KB*KS*KD;
  float* nw2 = nw1 + (size_t)KB*KI*KD;
  float* nln = nw2 + (size_t)KB*KD*KI;
  float* ns1 = nln + (size_t)KB*KD;
  float* ns2 = ns1 + (size_t)KB*KI*KD;
  float* nsl = ns2 + (size_t)KB*KD*KI;

  float* ws = (float*)d_ws;
  size_t o = 0;
  float* kbuf = ws+o; o += 2097152;   // fp32 silu(x wk^T) pre-rms
  float* qbuf = ws+o; o += 2097152;   // fp32 silu(x wq^T) pre-rms
  float* gl   = ws+o; o += 32768;
  float* part = ws+o; o += 6144;
  float* cmb  = ws+o; o += 32;
  float* csb  = ws+o; o += 32;
  float* Pwb  = ws+o; o += 32;
  float* thetab = ws+o; o += 32;
  __bf16* bb = (__bf16*)(ws + o);
  size_t p = 0;
  __bf16* xb   = bb+p; p += 2097152;  // reused as gyT
  __bf16* wkb  = bb+p; p += 1048576;  // wkb+wvb reused as kT
  __bf16* wvb  = bb+p; p += 1048576;
  __bf16* wqb  = bb+p; p += 1048576;
  __bf16* w1b  = bb+p; p += 2097152;  // reused as gyb
  __bf16* w2b  = bb+p; p += 2097152;  // w2b+w2tb reused as hq16
  __bf16* w2tb = bb+p; p += 2097152;
  __bf16* kb16 = bb+p; p += 2097152;
  __bf16* qb16 = bb+p; p += 2097152;
  __bf16* vb16 = bb+p; p += 2097152;
  __bf16* hb16 = bb+p; p += 4194304;
  __bf16* db16 = bb+p; p += 4194304;  // dsilu(a)
  __bf16* hT   = bb+p; p += 4194304;
  __bf16* gaT  = bb+p; p += 4194304;
  __bf16* nw1b = bb+p; p += 4194304;
  __bf16* nw2b = bb+p; p += 4194304;
  __bf16* y16  = bb+p; p += 4194304;  // y halves; later yq halves
  __bf16* gyT = xb;
  __bf16* kT  = wkb;
  __bf16* gyb = w1b;
  __bf16* hq16= w2b;

  dim3 blk(256);

  // 1. prep: convert + gate partials + w2^T + zero gl
  prep_kernel<<<9760, blk, 0, stream>>>(x, wk, wv, wq, w1, w2, aw, tw, ew,
      xb, wkb, wvb, wqb, w1b, w2b, w2tb, part, gl);
  // 2. projections: z0 k->fp32, z1 v->bf16, z2 q->fp32
  mgemm2<5,1,0><<<dim3(16,16,3), blk, 0, stream>>>(xb, wkb, wvb, wqb,
      kbuf, qbuf, vb16, nullptr, nullptr, nullptr, 0, 2048, 1024, 1024, 1024, 0);
  // 3. rms k,q -> bf16 (+ scan coefficients at y==2)
  rmsfuse_kernel<<<dim3(512,3), blk, 0, stream>>>(kbuf, knw, kb16, qbuf, qnw, qb16,
      part, cmb, csb, Pwb, thetab);
  // 4. a = k w1^T: h=silu, d=dsilu, hT via epilogue transpose
  mgemm2<2,0,1><<<dim3(32,16,1), blk, 0, stream>>>(kb16, w1b, nullptr, nullptr,
      nullptr, nullptr, hb16, db16, nullptr, hT, 2048, 2048, 2048, 1024, 1024, 0);
  // 5. y = h w2^T (split-K 2, bf16 halves)
  mgemm2<6,2,0><<<dim3(16,16,2), blk, 0, stream>>>(hb16, w2b, nullptr, nullptr,
      nullptr, nullptr, y16, nullptr, nullptr, nullptr, 0, 2048, 1024, 2048, 2048, 0);
  // 6. backward through rms+MSE (gy bf16, gl atomics)
  rms_grad_kernel<<<512, blk, 0, stream>>>(y16, kb16, vb16, lnw, thetab, gyb, gl);
  // 7. kT + gyT transposes
  tconv2_kernel<<<1024, blk, 0, stream>>>(kb16, kT, gyb, gyT);
  // 8. gaT = ((gy w2tb^T) * dsilu)^T via epilogue transpose (no normal write)
  mgemm2<3,0,1><<<dim3(32,16,1), blk, 0, stream>>>(gyb, w2tb, nullptr, nullptr,
      nullptr, nullptr, nullptr, nullptr, db16, gaT, 2048, 2048, 2048, 1024, 1024, 0);
  // 9. wacc1 + wacc2 + glcomb in one launch
  waccall_kernel<<<1032, blk, 0, stream>>>(gaT, kT, w1, gyT, hT, w2, gl, lnw,
      cmb, csb, Pwb, nw1, nw1b, ns1, nw2, nw2b, ns2, nln, nsl);
  // 10. hq = silu(q nw1^T) bf16
  mgemm2<4,0,0><<<dim3(32,16,1), blk, 0, stream>>>(qb16, nw1b, nullptr, nullptr,
      nullptr, nullptr, hq16, nullptr, nullptr, nullptr, 0, 2048, 2048, 1024, 1024, (long)KI*KD);
  // 11. yq = hq nw2^T (split-K 2, bf16 halves)
  mgemm2<6,2,0><<<dim3(16,16,2), blk, 0, stream>>>(hq16, nw2b, nullptr, nullptr,
      nullptr, nullptr, y16, nullptr, nullptr, nullptr, 0, 2048, 1024, 2048, 2048, (long)KD*KI);
  // 12. out = q + rms(yq)*nln
  final_out_kernel<<<512, blk, 0, stream>>>(qb16, y16, nln, out);
}

// Round 7
// 200.085 us; speedup vs baseline: 8.6654x; 1.0566x over previous
//
#include <hip/hip_runtime.h>

#define KD 1024   // D
#define KI 2048   // I
#define KB 2      // B
#define KS 1024   // S
#define KC 64     // C
#define KN 16     // N chunks
#define KEPS 1e-6f

typedef __bf16 bf16x8 __attribute__((ext_vector_type(8)));
typedef __bf16 bf16x4 __attribute__((ext_vector_type(4)));
typedef float f32x4 __attribute__((ext_vector_type(4)));

__device__ __forceinline__ float sigf(float x){ return 1.0f/(1.0f+__expf(-x)); }
__device__ __forceinline__ float siluf(float x){ return x*sigf(x); }
__device__ __forceinline__ float dsiluf(float x){ float s=sigf(x); return s*(1.0f+x*(1.0f-s)); }

// width-16 global->LDS DMA; LDS dest is wave-uniform base + lane*16
__device__ __forceinline__ void gld16(const __bf16* g, __bf16* l) {
  __builtin_amdgcn_global_load_lds(
    (const __attribute__((address_space(1))) unsigned int*)g,
    (__attribute__((address_space(3))) unsigned int*)l, 16, 0, 0);
}

#define WAIT_VM6()  asm volatile("s_waitcnt vmcnt(6)" ::: "memory")
#define WAIT_VM0()  asm volatile("s_waitcnt vmcnt(0)" ::: "memory")
#define WAIT_LGKM() asm volatile("s_waitcnt lgkmcnt(0)" ::: "memory")
#define BAR()       __builtin_amdgcn_s_barrier()

// ---------------- shared transpose body (64x64 tile via LDS) ---------------
template<int SRCF>
__device__ __forceinline__ void tconv_body(const void* in, __bf16* out,
                                           int R, int Cc, int bx, int by)
{
  __shared__ float T[64][65];
  const int r0 = by*64, c0 = bx*64;
  const int tx = threadIdx.x & 15, ty = threadIdx.x >> 4;
  #pragma unroll
  for (int i=0;i<4;i++){
    const int r = r0 + ty + i*16;
    if (SRCF) {
      const float4 v = *(const float4*)((const float*)in + (size_t)r*Cc + c0 + tx*4);
      T[ty+i*16][tx*4+0]=v.x; T[ty+i*16][tx*4+1]=v.y;
      T[ty+i*16][tx*4+2]=v.z; T[ty+i*16][tx*4+3]=v.w;
    } else {
      const bf16x4 v = *(const bf16x4*)((const __bf16*)in + (size_t)r*Cc + c0 + tx*4);
      T[ty+i*16][tx*4+0]=(float)v[0]; T[ty+i*16][tx*4+1]=(float)v[1];
      T[ty+i*16][tx*4+2]=(float)v[2]; T[ty+i*16][tx*4+3]=(float)v[3];
    }
  }
  __syncthreads();
  #pragma unroll
  for (int i=0;i<4;i++){
    bf16x4 o = { (__bf16)T[tx*4+0][ty+i*16], (__bf16)T[tx*4+1][ty+i*16],
                 (__bf16)T[tx*4+2][ty+i*16], (__bf16)T[tx*4+3][ty+i*16] };
    *(bf16x4*)(out + (size_t)(c0+ty+i*16)*R + r0 + tx*4) = o;
  }
}

// ---------------- prep: convert (x-blocks also gate partials) + w2^T + gl=0
__global__ __launch_bounds__(256) void prep_kernel(
  const float* __restrict__ x, const float* __restrict__ wk, const float* __restrict__ wv,
  const float* __restrict__ wq, const float* __restrict__ w1, const float* __restrict__ w2,
  const float* __restrict__ aw, const float* __restrict__ tw, const float* __restrict__ ew,
  __bf16* __restrict__ xb, __bf16* __restrict__ wkb, __bf16* __restrict__ wvb,
  __bf16* __restrict__ wqb, __bf16* __restrict__ w1b, __bf16* __restrict__ w2b,
  __bf16* __restrict__ w2tb, float* __restrict__ part, float* __restrict__ gl)
{
  const int g = blockIdx.x;
  if (g < 2048) {
    // x convert + gate partial dots (one float4 per thread)
    const int i = g*256 + threadIdx.x;          // float4 index into x
    const float4 xv = *(const float4*)(x + (size_t)i*4);
    bf16x4 o = { (__bf16)xv.x, (__bf16)xv.y, (__bf16)xv.z, (__bf16)xv.w };
    *(bf16x4*)(xb + (size_t)i*4) = o;
    const size_t co = (size_t)(i & 16383) * 4;  // chunk-local element offset
    const float4 av = *(const float4*)(aw + co);
    const float4 tv = *(const float4*)(tw + co);
    const float4 ev = *(const float4*)(ew + co);
    float da = xv.x*av.x + xv.y*av.y + xv.z*av.z + xv.w*av.w;
    float dt = xv.x*tv.x + xv.y*tv.y + xv.z*tv.z + xv.w*tv.w;
    float de = xv.x*ev.x + xv.y*ev.y + xv.z*ev.z + xv.w*ev.w;
    __shared__ float sA[256], sT[256], sE[256];
    sA[threadIdx.x]=da; sT[threadIdx.x]=dt; sE[threadIdx.x]=de;
    __syncthreads();
    for (int s=128;s>0;s>>=1){
      if ((int)threadIdx.x < s){
        sA[threadIdx.x]+=sA[threadIdx.x+s];
        sT[threadIdx.x]+=sT[threadIdx.x+s];
        sE[threadIdx.x]+=sE[threadIdx.x+s];
      }
      __syncthreads();
    }
    if (threadIdx.x==0){
      part[g] = sA[0]; part[2048+g] = sT[0]; part[4096+g] = sE[0];
    }
  } else if (g < 9216) {
    const long t = (long)g*256 + threadIdx.x;   // float4 index
    const float* s; __bf16* d; long i;
    if (t < 786432)       { s=wk; d=wkb; i=t-524288; }
    else if (t < 1048576) { s=wv; d=wvb; i=t-786432; }
    else if (t < 1310720) { s=wq; d=wqb; i=t-1048576; }
    else if (t < 1835008) { s=w1; d=w1b; i=t-1310720; }
    else                  { s=w2; d=w2b; i=t-1835008; }
    const float4 v = *(const float4*)(s + i*4);
    bf16x4 o = { (__bf16)v.x, (__bf16)v.y, (__bf16)v.z, (__bf16)v.w };
    *(bf16x4*)(d + i*4) = o;
  } else if (g < 9728) {
    const int gg = g - 9216;
    tconv_body<1>(w2, w2tb, 1024, 2048, gg & 31, gg >> 5);
  } else {
    const int gg = g - 9728;                    // 32 blocks zero gl
    float4 z = {0.f,0.f,0.f,0.f};
    *(float4*)(gl + (size_t)gg*1024 + threadIdx.x*4) = z;
  }
}

// ---------------- MFMA bf16 GEMM, counted-vmcnt pipeline: C = A*B^T --------
// BM=128, BN=64, BK=64, K=1024 (16 steps). 4 waves, wave tile 64x32.
// Prefetch loads for t+1 stay IN FLIGHT across the barriers (vmcnt(6), not 0).
// MODE: 0 plain, 1 proj mux (z selects B), 2 k-split (z = K half)
// EPI: 0 F0=acc; 2 Oa=silu & Ob=dsilu (+WT: OT=silu^T);
//      3 (WT) OT=(acc*Aux)^T only; 4 Oa=silu; 5 proj mux; 6 Oa[z*M*N]=bf16(acc)
template<int EPI, int MODE, int WT>
__global__ __launch_bounds__(256) void mgemm2(
    const __bf16* __restrict__ A, const __bf16* __restrict__ B0,
    const __bf16* __restrict__ B1, const __bf16* __restrict__ B2,
    float* __restrict__ F0, float* __restrict__ F1,
    __bf16* __restrict__ Oa, __bf16* __restrict__ Ob, const __bf16* __restrict__ Aux,
    __bf16* __restrict__ OT, int ldt,
    int M, int Nn, int lda, int ldb, long bstr)
{
  const int bz = blockIdx.z;
  const int n0 = blockIdx.x * 64;
  const int m0 = blockIdx.y * 128;
  const __bf16* Bp = B0;
  if (MODE==1) { if (bz==1) Bp=B1; else if (bz==2) Bp=B2; }
  float* F0p = F0;
  int koff0 = 0;
  if (MODE==2) { koff0 = bz << 10; }
  Bp += (size_t)(m0 >> 10) * (size_t)bstr;
  __shared__ __bf16 As[2*128*64];
  __shared__ __bf16 Bs[2*64*64];
  const int tid = threadIdx.x, wv = tid >> 6, lane = tid & 63;
  const int wm = (wv >> 1) << 6, wn = (wv & 1) << 5;
  const int fr = lane & 15, fg = lane >> 4;
  const int lr = lane >> 3, lc = lane & 7;
  const __bf16* asrc[4]; __bf16* adst[4];
  const __bf16* bsrc[2]; __bf16* bdst[2];
  #pragma unroll
  for (int i=0;i<4;i++){
    const int rowbase=(wv*4+i)*8, row=rowbase+lr;
    asrc[i] = A + (size_t)(m0+row)*lda + koff0 + ((lc^(row&7))<<3);
    adst[i] = As + rowbase*64;
  }
  #pragma unroll
  for (int i=0;i<2;i++){
    const int rowbase=(wv*2+i)*8, row=rowbase+lr;
    bsrc[i] = Bp + (size_t)(n0+row)*ldb + koff0 + ((lc^(row&7))<<3);
    bdst[i] = Bs + rowbase*64;
  }
  f32x4 acc[4][2] = {};
  #pragma unroll
  for (int i=0;i<4;i++) gld16(asrc[i], adst[i]);
  #pragma unroll
  for (int i=0;i<2;i++) gld16(bsrc[i], bdst[i]);
  WAIT_VM0();
  BAR();
  #pragma unroll 2
  for (int t=0;t<16;++t){
    const int p = t & 1;
    if (t < 15){
      const int ko = (t+1) << 6;
      const int q = p ^ 1;
      #pragma unroll
      for (int i=0;i<4;i++) gld16(asrc[i]+ko, adst[i]+q*8192);
      #pragma unroll
      for (int i=0;i<2;i++) gld16(bsrc[i]+ko, bdst[i]+q*4096);
      WAIT_VM6();            // loads(t) done; loads(t+1) stay in flight
    } else {
      WAIT_VM0();
    }
    BAR();
    #pragma unroll
    for (int ks=0;ks<2;++ks){
      bf16x8 af[4], bfv[2];
      #pragma unroll
      for (int mi=0;mi<4;++mi){
        const int r = wm + mi*16 + fr;
        af[mi] = *(const bf16x8*)(As + p*8192 + r*64 + ((((ks<<2)+fg)^(r&7))<<3));
      }
      #pragma unroll
      for (int ni=0;ni<2;++ni){
        const int r = wn + ni*16 + fr;
        bfv[ni] = *(const bf16x8*)(Bs + p*4096 + r*64 + ((((ks<<2)+fg)^(r&7))<<3));
      }
      #pragma unroll
      for (int mi=0;mi<4;++mi)
        #pragma unroll
        for (int ni=0;ni<2;++ni)
          acc[mi][ni] = __builtin_amdgcn_mfma_f32_16x16x32_bf16(af[mi], bfv[ni], acc[mi][ni], 0,0,0);
    }
    WAIT_LGKM();             // all LDS reads landed in regs before buffer reuse
    BAR();
  }
  __bf16* T = As;   // reuse staging LDS for transpose epilogue
  #pragma unroll
  for (int mi=0;mi<4;++mi){
    #pragma unroll
    for (int ni=0;ni<2;++ni){
      bf16x4 tv;
      #pragma unroll
      for (int j=0;j<4;++j){
        const int m = m0 + wm + mi*16 + fg*4 + j;
        const int n = n0 + wn + ni*16 + fr;
        const size_t idx = (size_t)m * Nn + n;
        const float v = acc[mi][ni][j];
        float tval = 0.f;
        if (EPI==0) F0p[idx] = v;
        else if (EPI==2) { const float sv = siluf(v); Oa[idx]=(__bf16)sv; Ob[idx]=(__bf16)dsiluf(v); tval=sv; }
        else if (EPI==3) tval = v * (float)Aux[idx];
        else if (EPI==4) Oa[idx] = (__bf16)siluf(v);
        else if (EPI==5) {
          if (bz==0) F0[idx] = siluf(v);
          else if (bz==1) Oa[idx] = (__bf16)siluf(v);
          else F1[idx] = siluf(v);
        }
        else if (EPI==6) Oa[(size_t)bz*M*Nn + idx] = (__bf16)v;
        if (WT) tv[j] = (__bf16)tval;
      }
      if (WT){
        const int nl = wn + ni*16 + fr;
        const int ml = wm + mi*16 + fg*4;
        *(bf16x4*)(T + nl*128 + (ml ^ ((nl&7)<<3))) = tv;
      }
    }
  }
  if (WT){
    __syncthreads();
    const int tn = tid >> 2, tc = tid & 3;
    #pragma unroll
    for (int u=0;u<4;++u){
      const int m8 = tc*32 + u*8;
      const bf16x8 v = *(const bf16x8*)(T + tn*128 + (m8 ^ ((tn&7)<<3)));
      *(bf16x8*)(OT + (size_t)(n0+tn)*ldt + m0 + m8) = v;
    }
  }
}

// ---------------- dual scan-weighted GEMM body (counted-vmcnt) -------------
__device__ __forceinline__ void wacc_body(
    __bf16* As, __bf16* Bs,
    const __bf16* __restrict__ A, const __bf16* __restrict__ B,
    const float* __restrict__ Winit,
    const float* __restrict__ cm, const float* __restrict__ cs,
    const float* __restrict__ Pw,
    float* __restrict__ outM, __bf16* __restrict__ outMb, float* __restrict__ outS,
    int M, int Nn, int lda, int ldb, int n0, int m0, int bz)
{
  const int koff0 = bz << 10;
  const int tid = threadIdx.x, wv = tid >> 6, lane = tid & 63;
  const int wm = (wv >> 1) << 6, wn = (wv & 1) << 5;
  const int fr = lane & 15, fg = lane >> 4;
  const int lr = lane >> 3, lc = lane & 7;
  // preload scan coefficients BEFORE any staging so no VMEM op pollutes the
  // in-loop vmcnt count
  float cmr[KN], csr[KN];
  #pragma unroll
  for (int n=0;n<KN;n++){ cmr[n]=cm[bz*KN+n]; csr[n]=cs[bz*KN+n]; }
  const __bf16* asrc[4]; __bf16* adst[4];
  const __bf16* bsrc[2]; __bf16* bdst[2];
  #pragma unroll
  for (int i=0;i<4;i++){
    const int rowbase=(wv*4+i)*8, row=rowbase+lr;
    asrc[i] = A + (size_t)(m0+row)*lda + koff0 + ((lc^(row&7))<<3);
    adst[i] = As + rowbase*64;
  }
  #pragma unroll
  for (int i=0;i<2;i++){
    const int rowbase=(wv*2+i)*8, row=rowbase+lr;
    bsrc[i] = B + (size_t)(n0+row)*ldb + koff0 + ((lc^(row&7))<<3);
    bdst[i] = Bs + rowbase*64;
  }
  f32x4 accM[4][2] = {}, accS[4][2] = {};
  asm volatile("s_waitcnt vmcnt(0) lgkmcnt(0)" ::: "memory");  // fence preloads
  #pragma unroll
  for (int i=0;i<4;i++) gld16(asrc[i], adst[i]);
  #pragma unroll
  for (int i=0;i<2;i++) gld16(bsrc[i], bdst[i]);
  WAIT_VM0();
  BAR();
  #pragma unroll 2
  for (int t=0;t<16;++t){
    const int p = t & 1;
    const float cmc = cmr[t], csc = csr[t];
    if (t < 15){
      const int ko = (t+1) << 6;
      const int q = p ^ 1;
      #pragma unroll
      for (int i=0;i<4;i++) gld16(asrc[i]+ko, adst[i]+q*8192);
      #pragma unroll
      for (int i=0;i<2;i++) gld16(bsrc[i]+ko, bdst[i]+q*4096);
      WAIT_VM6();
    } else {
      WAIT_VM0();
    }
    BAR();
    bf16x8 a0[4], a1[4], b0[2], b1[2];
    #pragma unroll
    for (int mi=0;mi<4;++mi){
      const int r = wm + mi*16 + fr;
      a0[mi] = *(const bf16x8*)(As + p*8192 + r*64 + (((0+fg)^(r&7))<<3));
      a1[mi] = *(const bf16x8*)(As + p*8192 + r*64 + (((4+fg)^(r&7))<<3));
    }
    #pragma unroll
    for (int ni=0;ni<2;++ni){
      const int r = wn + ni*16 + fr;
      b0[ni] = *(const bf16x8*)(Bs + p*4096 + r*64 + (((0+fg)^(r&7))<<3));
      b1[ni] = *(const bf16x8*)(Bs + p*4096 + r*64 + (((4+fg)^(r&7))<<3));
    }
    #pragma unroll
    for (int mi=0;mi<4;++mi){
      #pragma unroll
      for (int ni=0;ni<2;++ni){
        const f32x4 zf = {0.f,0.f,0.f,0.f};
        f32x4 P = __builtin_amdgcn_mfma_f32_16x16x32_bf16(a0[mi], b0[ni], zf, 0,0,0);
        P = __builtin_amdgcn_mfma_f32_16x16x32_bf16(a1[mi], b1[ni], P, 0,0,0);
        accM[mi][ni] += P * cmc;
        accS[mi][ni] += P * csc;
      }
    }
    WAIT_LGKM();
    BAR();
  }
  const float pw = Pw[bz];
  #pragma unroll
  for (int mi=0;mi<4;++mi){
    #pragma unroll
    for (int ni=0;ni<2;++ni){
      #pragma unroll
      for (int j=0;j<4;++j){
        const int m = m0 + wm + mi*16 + fg*4 + j;
        const int n = n0 + wn + ni*16 + fr;
        const size_t widx = (size_t)m * Nn + n;
        const size_t oidx = (size_t)bz * M * Nn + widx;
        const float vm = pw * Winit[widx] + accM[mi][ni][j];
        outM[oidx] = vm;
        outMb[oidx] = (__bf16)vm;
        outS[oidx] = accS[mi][ni][j];
      }
    }
  }
}

// ---------------- merged wacc1 + wacc2 + glcomb ----------------------------
__global__ __launch_bounds__(256) void waccall_kernel(
    const __bf16* __restrict__ gaT, const __bf16* __restrict__ kT, const float* __restrict__ w1,
    const __bf16* __restrict__ gyT, const __bf16* __restrict__ hT, const float* __restrict__ w2,
    const float* __restrict__ gl, const float* __restrict__ lnw,
    const float* __restrict__ cm, const float* __restrict__ cs, const float* __restrict__ Pw,
    float* __restrict__ nw1, __bf16* __restrict__ nw1b, float* __restrict__ ns1,
    float* __restrict__ nw2, __bf16* __restrict__ nw2b, float* __restrict__ ns2,
    float* __restrict__ nln, float* __restrict__ nsl)
{
  __shared__ __bf16 As[2*128*64];
  __shared__ __bf16 Bs[2*64*64];
  const int g = blockIdx.x;
  if (g < 512){
    const int bz = g >> 8, rem = g & 255;
    wacc_body(As, Bs, gaT, kT, w1, cm, cs, Pw, nw1, nw1b, ns1,
              2048, 1024, 2048, 2048, (rem & 15)*64, (rem >> 4)*128, bz);
  } else if (g < 1024){
    const int t = g - 512;
    const int bz = t >> 8, rem = t & 255;
    wacc_body(As, Bs, gyT, hT, w2, cm, cs, Pw, nw2, nw2b, ns2,
              1024, 2048, 2048, 2048, (rem & 31)*64, (rem >> 5)*128, bz);
  } else {
    const int idx = (g - 1024)*256 + threadIdx.x;
    const int b = idx >> 10, d = idx & (KD-1);
    float am=0.f, as=0.f;
    for (int n=0;n<KN;n++){
      const float gv = gl[(size_t)(b*KN+n)*KD + d];
      am += cm[b*KN+n]*gv; as += cs[b*KN+n]*gv;
    }
    nln[idx] = Pw[b]*lnw[d] + am;
    nsl[idx] = as;
  }
}

// ---------------- rmsnorm for k,q (+ scan coefficients at y==2) ------------
__global__ __launch_bounds__(256) void rmsfuse_kernel(
    const float* __restrict__ kv, const float* __restrict__ kw, __bf16* __restrict__ k16,
    const float* __restrict__ qv, const float* __restrict__ qw, __bf16* __restrict__ q16,
    const float* __restrict__ part, float* __restrict__ cm, float* __restrict__ cs,
    float* __restrict__ Pw, float* __restrict__ theta)
{
  if (blockIdx.y == 2){
    if (blockIdx.x != 0) return;
    __shared__ float P[32][8][3];
    const int bn = threadIdx.x >> 3, sg = threadIdx.x & 7;
    float s0=0.f, s1=0.f, s2=0.f;
    #pragma unroll
    for (int u=0;u<8;u++){
      const int seg = bn*64 + sg*8 + u;
      s0 += part[seg]; s1 += part[2048+seg]; s2 += part[4096+seg];
    }
    P[bn][sg][0]=s0; P[bn][sg][1]=s1; P[bn][sg][2]=s2;
    __syncthreads();
    if ((int)threadIdx.x < KB){
      const int b = threadIdx.x;
      float al[KN], et[KN];
      for (int n=0;n<KN;n++){
        const int c = b*KN+n;
        float sa=0.f, st=0.f, se=0.f;
        #pragma unroll
        for (int k=0;k<8;k++){ sa+=P[c][k][0]; st+=P[c][k][1]; se+=P[c][k][2]; }
        al[n]=sigf(sa); theta[c]=sigf(st)*0.01f; et[n]=sigf(se);
      }
      float prodE = 1.f;
      for (int j=KN-1;j>=0;j--){ cs[b*KN+j] = -prodE; prodE *= et[j]; }
      float Ac[KN]; Ac[KN-1]=1.f;
      for (int t=KN-2;t>=0;t--) Ac[t] = Ac[t+1]*(1.f-al[t+1]);
      for (int j=0;j<KN;j++){
        float inner=0.f, E=1.f;
        for (int t=j;t<KN;t++){ inner += Ac[t]*E; if (t+1<KN) E *= et[t+1]; }
        cm[b*KN+j] = -inner;
      }
      float pw=1.f;
      for (int n=0;n<KN;n++) pw *= (1.f-al[n]);
      Pw[b]=pw;
    }
    return;
  }
  const float* v; const float* w; __bf16* o16;
  if (blockIdx.y == 0){ v=kv; w=kw; o16=k16; } else { v=qv; w=qw; o16=q16; }
  const int row = blockIdx.x * 4 + (threadIdx.x >> 6);
  const int lane = threadIdx.x & 63;
  const float* p = v + (size_t)row * KD;
  __bf16* p16 = o16 + (size_t)row * KD;
  float vals[16]; float ss = 0.f;
  #pragma unroll
  for (int l=0;l<16;l++){ vals[l] = p[lane + (l<<6)]; ss += vals[l]*vals[l]; }
  #pragma unroll
  for (int o=32;o>0;o>>=1) ss += __shfl_xor(ss, o, 64);
  const float inv = rsqrtf(ss * (1.0f/KD) + KEPS);
  #pragma unroll
  for (int l=0;l<16;l++){
    const int d = lane + (l<<6);
    p16[d] = (__bf16)(vals[l]*inv*w[d]);
  }
}

// ---------------- per-row backward (y = bf16 halves), gl via atomics -------
__global__ __launch_bounds__(256) void rms_grad_kernel(
    const __bf16* __restrict__ y16,
    const __bf16* __restrict__ k16, const __bf16* __restrict__ v16,
    const float* __restrict__ lnw, const float* __restrict__ theta,
    __bf16* __restrict__ gy, float* __restrict__ gl)
{
  const int wv = threadIdx.x >> 6;
  const int row = blockIdx.x * 4 + wv;
  const int lane = threadIdx.x & 63;
  const int chunk = blockIdx.x >> 4;
  const float th2 = theta[chunk] * (2.0f / KD);
  const __bf16* yr0 = y16 + (size_t)row * KD;
  const __bf16* yr1 = y16 + 2097152 + (size_t)row * KD;
  const __bf16* kr = k16 + (size_t)row * KD;
  const __bf16* vr = v16 + (size_t)row * KD;
  float yv[16]; float ss = 0.f;
  #pragma unroll
  for (int l=0;l<16;l++){
    const int d = lane + (l<<6);
    yv[l] = (float)yr0[d] + (float)yr1[d]; ss += yv[l]*yv[l];
  }
  #pragma unroll
  for (int o=32;o>0;o>>=1) ss += __shfl_xor(ss, o, 64);
  const float inv = rsqrtf(ss * (1.0f/KD) + KEPS);
  float gzv[16]; float sdot = 0.f;
  #pragma unroll
  for (int l=0;l<16;l++){
    const int d = lane + (l<<6);
    const float gz = th2 * ((float)kr[d] + yv[l]*inv*lnw[d] - (float)vr[d]);
    gzv[l] = gz;
    sdot += gz * lnw[d] * yv[l];
  }
  #pragma unroll
  for (int o=32;o>0;o>>=1) sdot += __shfl_xor(sdot, o, 64);
  const float c3 = inv*inv*inv * (1.0f/KD) * sdot;
  __bf16* gyr = gy + (size_t)row * KD;
  __shared__ float L[4][KD];
  #pragma unroll
  for (int l=0;l<16;l++){
    const int d = lane + (l<<6);
    gyr[d] = (__bf16)(inv * lnw[d] * gzv[l] - c3 * yv[l]);
    L[wv][d] = gzv[l] * yv[l] * inv;
  }
  __syncthreads();
  if (wv == 0){
    float* glc = gl + (size_t)chunk * KD;
    #pragma unroll
    for (int l=0;l<16;l++){
      const int d = lane + (l<<6);
      atomicAdd(&glc[d], L[0][d]+L[1][d]+L[2][d]+L[3][d]);
    }
  }
}

// ---------------- remaining transposes: kT + gyT ---------------------------
__global__ __launch_bounds__(256) void tconv2_kernel(
    const __bf16* __restrict__ kb16, __bf16* __restrict__ kT,
    const __bf16* __restrict__ gyb,  __bf16* __restrict__ gyT)
{
  const int g = blockIdx.x;
  if (g < 512)  tconv_body<0>(kb16, kT, 2048, 1024, g & 15, g >> 4);
  else        { const int t = g - 512; tconv_body<0>(gyb, gyT, 2048, 1024, t & 15, t >> 4); }
}

// ---------------- final out (yq = bf16 halves, q from bf16) ----------------
__global__ __launch_bounds__(256) void final_out_kernel(
    const __bf16* __restrict__ q16, const __bf16* __restrict__ yq16,
    const float* __restrict__ nln, float* __restrict__ out)
{
  const int row = blockIdx.x * 4 + (threadIdx.x >> 6);
  const int lane = threadIdx.x & 63;
  const int b = row >> 10;
  float yv[16]; float ss = 0.f;
  #pragma unroll
  for (int l=0;l<16;l++){
    const int d = lane + (l<<6);
    yv[l] = (float)yq16[(size_t)row*KD + d] + (float)yq16[2097152 + (size_t)row*KD + d];
    ss += yv[l]*yv[l];
  }
  #pragma unroll
  for (int o=32;o>0;o>>=1) ss += __shfl_xor(ss, o, 64);
  const float inv = rsqrtf(ss * (1.0f/KD) + KEPS);
  #pragma unroll
  for (int l=0;l<16;l++){
    const int d = lane + (l<<6);
    out[(size_t)row*KD + d] = (float)q16[(size_t)row*KD + d] + yv[l]*inv*nln[b*KD + d];
  }
}

extern "C" void kernel_launch(void* const* d_in, const int* in_sizes, int n_in,
                              void* d_out, int out_size, void* d_ws, size_t ws_size,
                              hipStream_t stream)
{
  const float* x    = (const float*)d_in[0];
  const float* w1   = (const float*)d_in[1];
  const float* w2   = (const float*)d_in[2];
  const float* lnw  = (const float*)d_in[3];
  const float* wq   = (const float*)d_in[4];
  const float* wk   = (const float*)d_in[5];
  const float* wv   = (const float*)d_in[6];
  const float* qnw  = (const float*)d_in[7];
  const float* knw  = (const float*)d_in[8];
  const float* aw   = (const float*)d_in[9];
  const float* tw   = (const float*)d_in[10];
  const float* ew   = (const float*)d_in[11];

  float* out = (float*)d_out;
  float* nw1 = out + (size_t)KB*KS*KD;
  float* nw2 = nw1 + (size_t)KB*KI*KD;
  float* nln = nw2 + (size_t)KB*KD*KI;
  float* ns1 = nln + (size_t)KB*KD;
  float* ns2 = ns1 + (size_t)KB*KI*KD;
  float* nsl = ns2 + (size_t)KB*KD*KI;

  float* ws = (float*)d_ws;
  size_t o = 0;
  float* kbuf = ws+o; o += 2097152;   // fp32 silu(x wk^T) pre-rms
  float* qbuf = ws+o; o += 2097152;   // fp32 silu(x wq^T) pre-rms
  float* gl   = ws+o; o += 32768;
  float* part = ws+o; o += 6144;
  float* cmb  = ws+o; o += 32;
  float* csb  = ws+o; o += 32;
  float* Pwb  = ws+o; o += 32;
  float* thetab = ws+o; o += 32;
  __bf16* bb = (__bf16*)(ws + o);
  size_t p = 0;
  __bf16* xb   = bb+p; p += 2097152;  // reused as gyT
  __bf16* wkb  = bb+p; p += 1048576;  // wkb+wvb reused as kT
  __bf16* wvb  = bb+p; p += 1048576;
  __bf16* wqb  = bb+p; p += 1048576;
  __bf16* w1b  = bb+p; p += 2097152;  // reused as gyb
  __bf16* w2b  = bb+p; p += 2097152;  // w2b+w2tb reused as hq16
  __bf16* w2tb = bb+p; p += 2097152;
  __bf16* kb16 = bb+p; p += 2097152;
  __bf16* qb16 = bb+p; p += 2097152;
  __bf16* vb16 = bb+p; p += 2097152;
  __bf16* hb16 = bb+p; p += 4194304;
  __bf16* db16 = bb+p; p += 4194304;  // dsilu(a)
  __bf16* hT   = bb+p; p += 4194304;
  __bf16* gaT  = bb+p; p += 4194304;
  __bf16* nw1b = bb+p; p += 4194304;
  __bf16* nw2b = bb+p; p += 4194304;
  __bf16* y16  = bb+p; p += 4194304;  // y halves; later yq halves
  __bf16* gyT = xb;
  __bf16* kT  = wkb;
  __bf16* gyb = w1b;
  __bf16* hq16= w2b;

  dim3 blk(256);

  // 1. prep: convert + gate partials + w2^T + zero gl
  prep_kernel<<<9760, blk, 0, stream>>>(x, wk, wv, wq, w1, w2, aw, tw, ew,
      xb, wkb, wvb, wqb, w1b, w2b, w2tb, part, gl);
  // 2. projections: z0 k->fp32, z1 v->bf16, z2 q->fp32
  mgemm2<5,1,0><<<dim3(16,16,3), blk, 0, stream>>>(xb, wkb, wvb, wqb,
      kbuf, qbuf, vb16, nullptr, nullptr, nullptr, 0, 2048, 1024, 1024, 1024, 0);
  // 3. rms k,q -> bf16 (+ scan coefficients at y==2)
  rmsfuse_kernel<<<dim3(512,3), blk, 0, stream>>>(kbuf, knw, kb16, qbuf, qnw, qb16,
      part, cmb, csb, Pwb, thetab);
  // 4. a = k w1^T: h=silu, d=dsilu, hT via epilogue transpose
  mgemm2<2,0,1><<<dim3(32,16,1), blk, 0, stream>>>(kb16, w1b, nullptr, nullptr,
      nullptr, nullptr, hb16, db16, nullptr, hT, 2048, 2048, 2048, 1024, 1024, 0);
  // 5. y = h w2^T (split-K 2, bf16 halves)
  mgemm2<6,2,0><<<dim3(16,16,2), blk, 0, stream>>>(hb16, w2b, nullptr, nullptr,
      nullptr, nullptr, y16, nullptr, nullptr, nullptr, 0, 2048, 1024, 2048, 2048, 0);
  // 6. backward through rms+MSE (gy bf16, gl atomics)
  rms_grad_kernel<<<512, blk, 0, stream>>>(y16, kb16, vb16, lnw, thetab, gyb, gl);
  // 7. kT + gyT transposes
  tconv2_kernel<<<1024, blk, 0, stream>>>(kb16, kT, gyb, gyT);
  // 8. gaT = ((gy w2tb^T) * dsilu)^T via epilogue transpose (no normal write)
  mgemm2<3,0,1><<<dim3(32,16,1), blk, 0, stream>>>(gyb, w2tb, nullptr, nullptr,
      nullptr, nullptr, nullptr, nullptr, db16, gaT, 2048, 2048, 2048, 1024, 1024, 0);
  // 9. wacc1 + wacc2 + glcomb in one launch
  waccall_kernel<<<1032, blk, 0, stream>>>(gaT, kT, w1, gyT, hT, w2, gl, lnw,
      cmb, csb, Pwb, nw1, nw1b, ns1, nw2, nw2b, ns2, nln, nsl);
  // 10. hq = silu(q nw1^T) bf16
  mgemm2<4,0,0><<<dim3(32,16,1), blk, 0, stream>>>(qb16, nw1b, nullptr, nullptr,
      nullptr, nullptr, hq16, nullptr, nullptr, nullptr, 0, 2048, 2048, 1024, 1024, (long)KI*KD);
  // 11. yq = hq nw2^T (split-K 2, bf16 halves)
  mgemm2<6,2,0><<<dim3(16,16,2), blk, 0, stream>>>(hq16, nw2b, nullptr, nullptr,
      nullptr, nullptr, y16, nullptr, nullptr, nullptr, 0, 2048, 1024, 2048, 2048, (long)KD*KI);
  // 12. out = q + rms(yq)*nln
  final_out_kernel<<<512, blk, 0, stream>>>(qb16, y16, nln, out);
}